// Round 8
// baseline (559.046 us; speedup 1.0000x reference)
//
#include <hip/hip_runtime.h>
#include <hip/hip_bf16.h>
#include <math.h>

#define BB 2
#define SS 1024
#define DD 1024
#define HH 16
#define HDIM 64
#define KK 31
#define GG 4
#define EE 2
#define HIDN 2048
#define NTOK (BB*SS)
#define D3 (3*DD)

typedef unsigned short u16;
typedef __attribute__((ext_vector_type(8))) short s16x8;
typedef __attribute__((ext_vector_type(8))) unsigned short u16x8;
typedef __attribute__((ext_vector_type(4))) unsigned short u16x4;
typedef __attribute__((ext_vector_type(4))) float f32x4;
typedef __attribute__((ext_vector_type(2))) unsigned int u32x2;

__device__ __forceinline__ float gelu_f(float x) {
  return 0.5f * x * (1.0f + erff(x * 0.7071067811865475f));
}
__device__ __forceinline__ u16 f2bf(float f) {
  unsigned u = __builtin_bit_cast(unsigned, f);
  u = (u + 0x7fffu + ((u >> 16) & 1u)) >> 16;
  return (u16)u;
}
__device__ __forceinline__ float bf2f(u16 u) {
  return __builtin_bit_cast(float, ((unsigned)u) << 16);
}
__device__ __forceinline__ f32x4 MFMA16(s16x8 a, s16x8 b, f32x4 c) {
  return __builtin_amdgcn_mfma_f32_16x16x32_bf16(a, b, c, 0, 0, 0);
}
#define GLOAD16(gp, lp) __builtin_amdgcn_global_load_lds( \
    (const __attribute__((address_space(1))) void*)(gp),  \
    (__attribute__((address_space(3))) void*)(lp), 16, 0, 0)

// ---------------- LayerNorm: fp32 in -> bf16 out, one block per row ----------------
__global__ void ln_kernel(const float* __restrict__ x, const float* __restrict__ g,
                          const float* __restrict__ b, u16* __restrict__ out) {
  const int row = blockIdx.x;
  const int tid = threadIdx.x;
  __shared__ float red[4];
  const float4 v = reinterpret_cast<const float4*>(x + (size_t)row * DD)[tid];
  float s = v.x + v.y + v.z + v.w;
  s += __shfl_down(s, 32); s += __shfl_down(s, 16); s += __shfl_down(s, 8);
  s += __shfl_down(s, 4);  s += __shfl_down(s, 2);  s += __shfl_down(s, 1);
  if ((tid & 63) == 0) red[tid >> 6] = s;
  __syncthreads();
  const float mean = (red[0] + red[1] + red[2] + red[3]) * (1.0f / DD);
  __syncthreads();
  const float4 d = make_float4(v.x - mean, v.y - mean, v.z - mean, v.w - mean);
  float sq = d.x*d.x + d.y*d.y + d.z*d.z + d.w*d.w;
  sq += __shfl_down(sq, 32); sq += __shfl_down(sq, 16); sq += __shfl_down(sq, 8);
  sq += __shfl_down(sq, 4);  sq += __shfl_down(sq, 2);  sq += __shfl_down(sq, 1);
  if ((tid & 63) == 0) red[tid >> 6] = sq;
  __syncthreads();
  const float var = (red[0] + red[1] + red[2] + red[3]) * (1.0f / DD);
  const float rstd = rsqrtf(var + 1e-5f);
  const float4 gv = reinterpret_cast<const float4*>(g)[tid];
  const float4 bv = reinterpret_cast<const float4*>(b)[tid];
  u16x4 o;
  o[0] = f2bf(d.x * rstd * gv.x + bv.x);
  o[1] = f2bf(d.y * rstd * gv.y + bv.y);
  o[2] = f2bf(d.z * rstd * gv.z + bv.z);
  o[3] = f2bf(d.w * rstd * gv.w + bv.w);
  *reinterpret_cast<u16x4*>(out + (size_t)row * DD + tid * 4) = o;
}

// ---------------- conv weight reorder: conv_w[o][i][k] f32 -> Wb[k][o][i] bf16 ----------------
__global__ void prep_convw(const float* __restrict__ cw, u16* __restrict__ Wb) {
  const int o = blockIdx.x;
#pragma unroll
  for (int rep = 0; rep < 4; ++rep) {
    const int i = rep * 256 + threadIdx.x;
    const float* src = cw + ((size_t)o * DD + i) * KK;
    float wv[KK];
#pragma unroll
    for (int k = 0; k < KK; ++k) wv[k] = src[k];
#pragma unroll
    for (int k = 0; k < KK; ++k)
      Wb[((size_t)k * DD + o) * DD + i] = f2bf(wv[k]);
  }
}

// ---------------- plain f32 -> bf16 convert ----------------
__global__ void cvt_kernel(const float* __restrict__ in, u16* __restrict__ outp, int n4) {
  const int i = blockIdx.x * 256 + threadIdx.x;
  if (i < n4) {
    const float4 v = reinterpret_cast<const float4*>(in)[i];
    u16x4 o; o[0] = f2bf(v.x); o[1] = f2bf(v.y); o[2] = f2bf(v.z); o[3] = f2bf(v.w);
    reinterpret_cast<u16x4*>(outp)[i] = o;
  }
}

// ---------------- transpose-convert: src[z][R][C] f32 -> dst[z][C][R] bf16 ----------------
__global__ void tr_kernel(const float* __restrict__ src, u16* __restrict__ dst, int R, int C) {
  __shared__ float tile[32][33];
  const int c0 = blockIdx.x * 32, r0 = blockIdx.y * 32;
  const size_t base = (size_t)blockIdx.z * R * C;
  const int tx = threadIdx.x & 31, ty = threadIdx.x >> 5;  // ty 0..7
#pragma unroll
  for (int i = 0; i < 4; ++i)
    tile[ty + i * 8][tx] = src[base + (size_t)(r0 + ty + i * 8) * C + c0 + tx];
  __syncthreads();
#pragma unroll
  for (int i = 0; i < 4; ++i)
    dst[base + (size_t)(c0 + ty + i * 8) * R + r0 + tx] = f2bf(tile[tx][ty + i * 8]);
}

// ---------------- V transpose: qkvb V-part -> Vt[b][h][d][k] bf16 ----------------
__global__ void vtr_kernel(const u16* __restrict__ qkvb, u16* __restrict__ Vt) {
  __shared__ u16 tile[32][40];
  const int k0 = blockIdx.x * 32, d0 = blockIdx.y * 32, bh = blockIdx.z;
  const int b = bh >> 4, h = bh & 15;
  const int tx = threadIdx.x & 31, ty = threadIdx.x >> 5;  // ty 0..7
#pragma unroll
  for (int i = 0; i < 4; ++i)
    tile[ty + i * 8][tx] =
        qkvb[(size_t)(b * SS + k0 + ty + i * 8) * D3 + 2 * DD + h * HDIM + d0 + tx];
  __syncthreads();
#pragma unroll
  for (int i = 0; i < 4; ++i)
    Vt[((size_t)(b * HH + h) * HDIM + d0 + ty + i * 8) * SS + k0 + tx] = tile[tx][ty + i * 8];
}

// ---------------- conv via MFMA v6: barrier-free taps, wave-private B ring-3, LINEAR frag read ----------------
// v5 post-mortem: barrier removal worked but the B-read XOR (ported from 128B-row geometry)
// created 8.2M bank-conflict cycles (63x) in the 64B-row private layout. v6: chunk-within-o-major
// slot layout so each B-frag read is lane-LINEAR (lane l reads region + l*16 -> zero conflicts,
// same pattern as the DMA writes). Store: instr q(=nf) writes r=q*16+(lane&15), c16=lane>>4.
// stageA issued AFTER the counted vmcnt so it never gets over-drained. LDS 136KB unchanged.
__global__ __launch_bounds__(512) void conv_kernel(const u16* __restrict__ hb,
                                                   const u16* __restrict__ Wb,
                                                   u16* __restrict__ P) {
  const int L = blockIdx.x;            // 0..255
  const int o_t = L & 7;               // o-tile pinned per XCD (B L2 reuse)
  const int rest = L >> 3;
  const int s_t = rest >> 1;           // 0..15
  const int z = rest & 1;              // i-half
  const int b = s_t >> 3, sloc = s_t & 7;
  const int s0l = sloc * 128;
  const int o0 = o_t * 128;
  const int ibase = z * 512;
  const int tid = threadIdx.x, lane = tid & 63, w = tid >> 6;
  const int wm = (w >> 2) & 1, wn = (w >> 1) & 1, ksid = w & 1;
  const int q15 = lane & 15, g = lane >> 4;
  __shared__ __align__(16) u16 Ad[2][160 * 64];   // 40 KB, dbuf over i-slices
  __shared__ __align__(16) u16 Bp[8][3][2048];    // 96 KB, wave-private ring-3 (4KB slots)
  const int rlo = (sloc == 0) ? 15 : 0;
  const int rhi = (sloc == 7) ? 143 : 158;
  if (sloc == 0)
    for (int i = tid; i < 15 * 64; i += 512) { Ad[0][i] = 0; Ad[1][i] = 0; }
  if (sloc == 7)
    for (int i = tid; i < 17 * 64; i += 512) { Ad[0][143 * 64 + i] = 0; Ad[1][143 * 64 + i] = 0; }
  auto stageA = [&](int buf, int i0) {
    for (int q = w; q < 20; q += 8) {
      const int r = q * 8 + (lane >> 3);
      const int c = (lane & 7) ^ (r & 7);
      if (r >= rlo && r < rhi)
        GLOAD16(hb + (size_t)(b * SS + s0l - 15 + r) * DD + i0 + c * 8, &Ad[buf][q * 512]);
    }
  };
  // private: this wave's 64o x 32i quarter for tap k at absolute i-base i0w.
  // Slot layout: region nf (1KB) = instr q; within region, byte l*16 holds
  // (o = nf*16 + (l&15), i-chunk = l>>4). Frag read is then lane-linear (conflict-free).
  auto stageBp = [&](int slot, int k, int i0w) {
#pragma unroll
    for (int q = 0; q < 4; ++q) {
      const int r = q * 16 + (lane & 15);           // o-row local 0..63
      const int c16 = lane >> 4;                    // i-chunk 0..3
      GLOAD16(Wb + ((size_t)k * DD + o0 + wn * 64 + r) * DD + i0w + c16 * 8,
              &Bp[w][slot][q * 512]);
    }
  };
  f32x4 acc[4][4];
#pragma unroll
  for (int i = 0; i < 4; ++i)
#pragma unroll
    for (int j = 0; j < 4; ++j) acc[i][j] = f32x4{0.f, 0.f, 0.f, 0.f};
  const int ib0 = ibase + ksid * 32;
  stageA(0, ibase);
  stageBp(0, 0, ib0);
  stageBp(1, 1, ib0);
  asm volatile("s_waitcnt vmcnt(0)" ::: "memory");
  __syncthreads();
  const int T = 8 * KK;  // 248 taps
  const int kx = ksid * 64;  // byte XOR selecting this wave's K=32 half in Ad rows
  int t = 0;
  for (int i0i = 0; i0i < 8; ++i0i) {
    const u16* Ab = Ad[i0i & 1];
    for (int k = 0; k < KK; ++k, ++t) {
      {  // prefetch own B(t+2) into private ring
        const int tn = t + 2;
        if (tn < T) stageBp(tn % 3, tn % KK, ibase + (tn / KK) * 64 + ksid * 32);
      }
      // A frags from shared Ad (slice-stable)
      s16x8 af[4];
      const int rk0 = wm * 64 + q15 + k;
#pragma unroll
      for (int mf = 0; mf < 4; ++mf) {
        const int rr = rk0 + mf * 16;
        const char* p = (const char*)Ab + rr * 128;
        af[mf] = *(const s16x8*)(p + (((g ^ (rr & 7)) * 16) ^ kx));
      }
      // own B(t) landed when <= 2 taps' worth of own loads outstanding
      if (t + 2 < T)      asm volatile("s_waitcnt vmcnt(8)" ::: "memory");
      else if (t + 1 < T) asm volatile("s_waitcnt vmcnt(4)" ::: "memory");
      else                asm volatile("s_waitcnt vmcnt(0)" ::: "memory");
      // A prefetch AFTER the counted wait (issue-only; consumed after slice barrier)
      if (k == 5 && i0i < 7) stageA((i0i + 1) & 1, ibase + (i0i + 1) * 64);
      const char* Bb = (const char*)&Bp[w][t % 3][0];
      s16x8 bfr[4];
#pragma unroll
      for (int nf = 0; nf < 4; ++nf)
        bfr[nf] = *(const s16x8*)(Bb + nf * 1024 + lane * 16);   // lane-linear, 0-conflict
      __builtin_amdgcn_s_setprio(1);
#pragma unroll
      for (int mf = 0; mf < 4; ++mf)
#pragma unroll
        for (int nf = 0; nf < 4; ++nf)
          acc[mf][nf] = MFMA16(af[mf], bfr[nf], acc[mf][nf]);
      __builtin_amdgcn_s_setprio(0);
    }
    if (i0i < 7) {                       // slice boundary: Ad swap (cross-wave A visibility)
      asm volatile("s_waitcnt vmcnt(0)" ::: "memory");
      __syncthreads();
    }
  }
  // ---- ks-pair reduction: ks1 waves stash f32 acc in LDS (reuse Bp), ks0 sums+writes ----
  __syncthreads();
  float* scr = (float*)(&Bp[0][0][0]) + (wm * 2 + wn) * 4096;
  if (ksid == 1) {
#pragma unroll
    for (int mf = 0; mf < 4; ++mf)
#pragma unroll
      for (int nf = 0; nf < 4; ++nf) {
        const int col = nf * 16 + q15;
        *(f32x4*)&scr[col * 64 + ((mf * 16 + g * 4) ^ ((col & 7) << 3))] = acc[mf][nf];
      }
  }
  __syncthreads();
  if (ksid == 0) {
    u16* Pz = P + (size_t)z * NTOK * DD;
#pragma unroll
    for (int mf = 0; mf < 4; ++mf) {
      f32x4 sum[4];
#pragma unroll
      for (int nf = 0; nf < 4; ++nf) {
        const int col = nf * 16 + q15;
        const f32x4 o = *(const f32x4*)&scr[col * 64 + ((mf * 16 + g * 4) ^ ((col & 7) << 3))];
        sum[nf] = acc[mf][nf] + o;
      }
#pragma unroll
      for (int r = 0; r < 4; ++r) {
        const int srow = s0l + wm * 64 + mf * 16 + g * 4 + r;
        u16* orow = Pz + (size_t)(b * SS + srow) * DD + o0 + wn * 64;
#pragma unroll
        for (int nf = 0; nf < 4; ++nf)
          orow[nf * 16 + q15] = f2bf(sum[nf][r]);
      }
    }
  }
}

// ---------------- combine: x1 = gelu(P0+P1+cb) + x ----------------
__global__ void combine_kernel(const u16* __restrict__ P, const float* __restrict__ cb,
                               const float* __restrict__ x, float* __restrict__ x1) {
  const int idx = blockIdx.x * 256 + threadIdx.x;
  const size_t base = (size_t)idx * 4;
  const int col = (int)(base & (DD - 1));
  const u16x4 p0 = *(const u16x4*)(P + base);
  const u16x4 p1 = *(const u16x4*)(P + (size_t)NTOK * DD + base);
  const float4 xv = *(const float4*)(x + base);
  const float4 cbv = *(const float4*)(cb + col);
  float4 o;
  o.x = gelu_f(bf2f(p0[0]) + bf2f(p1[0]) + cbv.x) + xv.x;
  o.y = gelu_f(bf2f(p0[1]) + bf2f(p1[1]) + cbv.y) + xv.y;
  o.z = gelu_f(bf2f(p0[2]) + bf2f(p1[2]) + cbv.z) + xv.z;
  o.w = gelu_f(bf2f(p0[3]) + bf2f(p1[3]) + cbv.w) + xv.w;
  *(float4*)(x1 + base) = o;
}

// ---------------- qkv GEMM: qkvb[2048][3072] = hb @ inwb^T + in_b (bf16 out) ----------------
__global__ __launch_bounds__(256) void qkv_kernel(const u16* __restrict__ A, const u16* __restrict__ B,
                           const float* __restrict__ bias, u16* __restrict__ C) {
  const int n0 = blockIdx.x * 64, m0 = blockIdx.y * 128;
  const int tid = threadIdx.x, lane = tid & 63, w = tid >> 6;
  const int wm = w >> 1, wn = w & 1;
  __shared__ u16 As[2][128 * 64];
  __shared__ u16 Bs[2][64 * 64];
  f32x4 acc[4][2];
#pragma unroll
  for (int i = 0; i < 4; ++i)
#pragma unroll
    for (int j = 0; j < 2; ++j) acc[i][j] = f32x4{0.f, 0.f, 0.f, 0.f};
  auto stage = [&](int t, int buf) {
    const int k0 = t * 64;
#pragma unroll
    for (int q = 0; q < 4; ++q) {
      const int idx = w * 4 + q, r = idx * 8 + (lane >> 3), c = (lane & 7) ^ (r & 7);
      GLOAD16(A + (size_t)(m0 + r) * DD + k0 + c * 8, &As[buf][idx * 512]);
    }
#pragma unroll
    for (int q = 0; q < 2; ++q) {
      const int idx = w * 2 + q, r = idx * 8 + (lane >> 3), c = (lane & 7) ^ (r & 7);
      GLOAD16(B + (size_t)(n0 + r) * DD + k0 + c * 8, &Bs[buf][idx * 512]);
    }
  };
  stage(0, 0);
  asm volatile("s_waitcnt vmcnt(0)" ::: "memory");
  __syncthreads();
  const int T = DD / 64;
  for (int t = 0; t < T; ++t) {
    if (t + 1 < T) stage(t + 1, (t + 1) & 1);
    const u16* Ab = As[t & 1];
    const u16* Bb = Bs[t & 1];
    const int xb = (((lane >> 4) ^ (lane & 7)) * 16);
    s16x8 af[4][2], bfr[2][2];
#pragma unroll
    for (int mf = 0; mf < 4; ++mf) {
      const char* p = (const char*)Ab + (wm * 64 + mf * 16 + (lane & 15)) * 128;
      af[mf][0] = *(const s16x8*)(p + xb);
      af[mf][1] = *(const s16x8*)(p + (xb ^ 64));
    }
#pragma unroll
    for (int nf = 0; nf < 2; ++nf) {
      const char* p = (const char*)Bb + (wn * 32 + nf * 16 + (lane & 15)) * 128;
      bfr[nf][0] = *(const s16x8*)(p + xb);
      bfr[nf][1] = *(const s16x8*)(p + (xb ^ 64));
    }
#pragma unroll
    for (int ks = 0; ks < 2; ++ks)
#pragma unroll
      for (int mf = 0; mf < 4; ++mf)
#pragma unroll
        for (int nf = 0; nf < 2; ++nf)
          acc[mf][nf] = MFMA16(af[mf][ks], bfr[nf][ks], acc[mf][nf]);
    asm volatile("s_waitcnt vmcnt(0)" ::: "memory");
    __syncthreads();
  }
#pragma unroll
  for (int mf = 0; mf < 4; ++mf)
#pragma unroll
    for (int rr = 0; rr < 4; ++rr) {
      const int row = m0 + wm * 64 + mf * 16 + (lane >> 4) * 4 + rr;
#pragma unroll
      for (int nf = 0; nf < 2; ++nf) {
        const int col = n0 + wn * 32 + nf * 16 + (lane & 15);
        C[(size_t)row * D3 + col] = f2bf(acc[mf][nf][rr] + bias[col]);
      }
    }
}

// ---------------- out proj: x2 = ctxb @ outwb^T + out_b + x1 (f32 out + bf16 scatter to x2g) ----------------
__global__ __launch_bounds__(256) void out_kernel(const u16* __restrict__ A, const u16* __restrict__ B,
                           const float* __restrict__ bias, const float* __restrict__ resid,
                           float* __restrict__ C, u16* __restrict__ x2g,
                           const int* __restrict__ inv) {
  const int n0 = blockIdx.x * 64, m0 = blockIdx.y * 128;
  const int tid = threadIdx.x, lane = tid & 63, w = tid >> 6;
  const int wm = w >> 1, wn = w & 1;
  __shared__ u16 As[2][128 * 64];
  __shared__ u16 Bs[2][64 * 64];
  f32x4 acc[4][2];
#pragma unroll
  for (int i = 0; i < 4; ++i)
#pragma unroll
    for (int j = 0; j < 2; ++j) acc[i][j] = f32x4{0.f, 0.f, 0.f, 0.f};
  auto stage = [&](int t, int buf) {
    const int k0 = t * 64;
#pragma unroll
    for (int q = 0; q < 4; ++q) {
      const int idx = w * 4 + q, r = idx * 8 + (lane >> 3), c = (lane & 7) ^ (r & 7);
      GLOAD16(A + (size_t)(m0 + r) * DD + k0 + c * 8, &As[buf][idx * 512]);
    }
#pragma unroll
    for (int q = 0; q < 2; ++q) {
      const int idx = w * 2 + q, r = idx * 8 + (lane >> 3), c = (lane & 7) ^ (r & 7);
      GLOAD16(B + (size_t)(n0 + r) * DD + k0 + c * 8, &Bs[buf][idx * 512]);
    }
  };
  stage(0, 0);
  asm volatile("s_waitcnt vmcnt(0)" ::: "memory");
  __syncthreads();
  const int T = DD / 64;
  for (int t = 0; t < T; ++t) {
    if (t + 1 < T) stage(t + 1, (t + 1) & 1);
    const u16* Ab = As[t & 1];
    const u16* Bb = Bs[t & 1];
    const int xb = (((lane >> 4) ^ (lane & 7)) * 16);
    s16x8 af[4][2], bfr[2][2];
#pragma unroll
    for (int mf = 0; mf < 4; ++mf) {
      const char* p = (const char*)Ab + (wm * 64 + mf * 16 + (lane & 15)) * 128;
      af[mf][0] = *(const s16x8*)(p + xb);
      af[mf][1] = *(const s16x8*)(p + (xb ^ 64));
    }
#pragma unroll
    for (int nf = 0; nf < 2; ++nf) {
      const char* p = (const char*)Bb + (wn * 32 + nf * 16 + (lane & 15)) * 128;
      bfr[nf][0] = *(const s16x8*)(p + xb);
      bfr[nf][1] = *(const s16x8*)(p + (xb ^ 64));
    }
#pragma unroll
    for (int ks = 0; ks < 2; ++ks)
#pragma unroll
      for (int mf = 0; mf < 4; ++mf)
#pragma unroll
        for (int nf = 0; nf < 2; ++nf)
          acc[mf][nf] = MFMA16(af[mf][ks], bfr[nf][ks], acc[mf][nf]);
    asm volatile("s_waitcnt vmcnt(0)" ::: "memory");
    __syncthreads();
  }
#pragma unroll
  for (int mf = 0; mf < 4; ++mf)
#pragma unroll
    for (int rr = 0; rr < 4; ++rr) {
      const int row = m0 + wm * 64 + mf * 16 + (lane >> 4) * 4 + rr;
      const int slot = inv[row];
#pragma unroll
      for (int nf = 0; nf < 2; ++nf) {
        const int col = n0 + wn * 32 + nf * 16 + (lane & 15);
        const float v = acc[mf][nf][rr] + bias[col] + resid[(size_t)row * DD + col];
        C[(size_t)row * DD + col] = v;
        x2g[(size_t)slot * DD + col] = f2bf(v);
      }
    }
}

// ---------------- MFMA flash attention: 128 q x (b,h) per block, 8 waves x 16 q ----------------
__global__ __launch_bounds__(512) void attn_kernel(const u16* __restrict__ qkv,
                                                   const u16* __restrict__ Vt,
                                                   u16* __restrict__ ctx) {
  const int q0 = blockIdx.x * 128, h = blockIdx.y, b = blockIdx.z;
  const int tid = threadIdx.x, lane = tid & 63, w = tid >> 6;
  const int q15 = lane & 15, g = lane >> 4, l7 = lane & 7;
  __shared__ u16 Q_lds[128 * 64];
  __shared__ u16 K_lds[2][64 * 64];
  __shared__ u16 V_lds[2][64 * 64];
  __shared__ u16 P_lds[8][16 * 72];
  __shared__ float s_lds[8][16];

#pragma unroll
  for (int q2 = 0; q2 < 2; ++q2) {
    const int idx = w * 2 + q2;
    const int r = idx * 8 + (lane >> 3);
    const int c = l7 ^ (r & 7);
    GLOAD16(qkv + (size_t)(b * SS + q0 + r) * D3 + h * HDIM + c * 8, &Q_lds[idx * 512]);
  }
  auto stageK = [&](int buf, int kt) {
    const int r = w * 8 + (lane >> 3);
    const int c = l7 ^ (r & 7);
    GLOAD16(qkv + (size_t)(b * SS + kt * 64 + r) * D3 + DD + h * HDIM + c * 8,
            &K_lds[buf][w * 512]);
  };
  auto stageV = [&](int buf, int kt) {
    const int r = w * 8 + (lane >> 3);
    const int c = l7 ^ (r & 7);
    GLOAD16(Vt + ((size_t)(b * HH + h) * HDIM + r) * SS + kt * 64 + c * 8,
            &V_lds[buf][w * 512]);
  };
  stageK(0, 0);
  stageV(0, 0);
  asm volatile("s_waitcnt vmcnt(0)" ::: "memory");
  __syncthreads();
  s16x8 bq[2];
#pragma unroll
  for (int ks = 0; ks < 2; ++ks)
    bq[ks] = *(const s16x8*)((const char*)Q_lds + (w * 16 + q15) * 128 + ((4 * ks + g) ^ l7) * 16);
  f32x4 oacc[4];
#pragma unroll
  for (int nf = 0; nf < 4; ++nf) oacc[nf] = f32x4{0.f, 0.f, 0.f, 0.f};
  float mrun = -3.0e38f, lrun = 0.0f;
  int buf = 0;
  for (int kt = 0; kt < 16; ++kt) {
    if (kt < 15) { stageK(buf ^ 1, kt + 1); stageV(buf ^ 1, kt + 1); }
    f32x4 st[4];
#pragma unroll
    for (int mf = 0; mf < 4; ++mf) st[mf] = f32x4{0.f, 0.f, 0.f, 0.f};
#pragma unroll
    for (int ks = 0; ks < 2; ++ks) {
#pragma unroll
      for (int mf = 0; mf < 4; ++mf) {
        const s16x8 ka = *(const s16x8*)((const char*)K_lds[buf] + (mf * 16 + q15) * 128 +
                                         ((4 * ks + g) ^ l7) * 16);
        st[mf] = MFMA16(ka, bq[ks], st[mf]);
      }
    }
    float t0[4][4];
    float cmax = -3.0e38f;
#pragma unroll
    for (int mf = 0; mf < 4; ++mf)
#pragma unroll
      for (int r = 0; r < 4; ++r) {
        const float v = st[mf][r] * 0.125f;
        t0[mf][r] = v;
        cmax = fmaxf(cmax, v);
      }
    cmax = fmaxf(cmax, __shfl_xor(cmax, 16));
    cmax = fmaxf(cmax, __shfl_xor(cmax, 32));
    const float mnew = fmaxf(mrun, cmax);
    const float scf = __expf(mrun - mnew);
    float psum = 0.f;
#pragma unroll
    for (int mf = 0; mf < 4; ++mf)
#pragma unroll
      for (int r = 0; r < 4; ++r) {
        const float p = __expf(t0[mf][r] - mnew);
        t0[mf][r] = p;
        psum += p;
      }
    psum += __shfl_xor(psum, 16);
    psum += __shfl_xor(psum, 32);
    lrun = lrun * scf + psum;
    mrun = mnew;
    s_lds[w][q15] = scf;
    u16* pw = &P_lds[w][0];
#pragma unroll
    for (int mf = 0; mf < 4; ++mf) {
      u32x2 pk;
      pk[0] = (unsigned)f2bf(t0[mf][0]) | ((unsigned)f2bf(t0[mf][1]) << 16);
      pk[1] = (unsigned)f2bf(t0[mf][2]) | ((unsigned)f2bf(t0[mf][3]) << 16);
      *(u32x2*)(pw + q15 * 72 + mf * 16 + g * 4) = pk;
    }
    asm volatile("s_waitcnt lgkmcnt(0)" ::: "memory");
    const f32x4 scv = *(const f32x4*)&s_lds[w][g * 4];
#pragma unroll
    for (int nf = 0; nf < 4; ++nf)
#pragma unroll
      for (int r = 0; r < 4; ++r) oacc[nf][r] *= scv[r];
#pragma unroll
    for (int ks = 0; ks < 2; ++ks) {
      const s16x8 pa = *(const s16x8*)(pw + q15 * 72 + ks * 32 + g * 8);
#pragma unroll
      for (int nf = 0; nf < 4; ++nf) {
        const s16x8 bv = *(const s16x8*)((const char*)V_lds[buf] + (nf * 16 + q15) * 128 +
                                         ((4 * ks + g) ^ l7) * 16);
        oacc[nf] = MFMA16(pa, bv, oacc[nf]);
      }
    }
    asm volatile("s_waitcnt vmcnt(0)" ::: "memory");
    __syncthreads();
    buf ^= 1;
  }
  const float linv = 1.0f / lrun;
  s_lds[w][q15] = linv;
  asm volatile("s_waitcnt lgkmcnt(0)" ::: "memory");
  const f32x4 lv = *(const f32x4*)&s_lds[w][g * 4];
#pragma unroll
  for (int nf = 0; nf < 4; ++nf)
#pragma unroll
    for (int r = 0; r < 4; ++r) {
      const int qg = q0 + w * 16 + g * 4 + r;
      ctx[(size_t)(b * SS + qg) * DD + h * HDIM + nf * 16 + q15] = f2bf(oacc[nf][r] * lv[r]);
    }
}

// ---------------- MoE routing ----------------
__global__ void zero_counts_kernel(int* c) { if (threadIdx.x < GG) c[threadIdx.x] = 0; }

__global__ void gather_kernel(const int* __restrict__ gid, int* __restrict__ counts,
                              int* __restrict__ gather) {
  const int n = blockIdx.x * 256 + threadIdx.x;
  if (n < NTOK) {
    const int g = gid[n];
    const int slot = atomicAdd(&counts[g], 1);
    gather[g * NTOK + slot] = n;
  }
}

// off[g] = exclusive prefix sum of counts; off[GG] = NTOK
__global__ void scan_kernel(const int* __restrict__ cnts, int* __restrict__ off) {
  if (threadIdx.x == 0) {
    int s = 0;
#pragma unroll
    for (int g = 0; g < GG; ++g) { off[g] = s; s += cnts[g]; }
    off[GG] = s;
  }
}

// gidx[off[g]+slot] = tok ; inv[tok] = off[g]+slot
__global__ void pack_kernel(const int* __restrict__ gat, const int* __restrict__ cnts,
                            const int* __restrict__ off, int* __restrict__ gidx,
                            int* __restrict__ inv) {
  const int g = blockIdx.y;
  const int slot = blockIdx.x * 256 + threadIdx.x;
  if (slot < cnts[g]) {
    const int tok = gat[g * NTOK + slot];
    const int sg = off[g] + slot;
    gidx[sg] = tok;
    inv[tok] = sg;
  }
}

// ---------------- MoE GEMM1: h1[e][base+slot] = gelu(x2g[base+slot] @ w1t[g,e]^T + b1) ----------------
// grid x = n-tile (dense -> all XCD residues active), y = m-tile (sparse early-exit).
__global__ __launch_bounds__(256) void moe1_kernel(const u16* __restrict__ x2g, const u16* __restrict__ w1t,
                            const float* __restrict__ e_b1, const int* __restrict__ off,
                            const int* __restrict__ cnts, u16* __restrict__ h1) {
  const int ge = blockIdx.z, g = ge >> 1, e = ge & 1;
  const int cnt = cnts[g];
  const int m0 = blockIdx.y * 128;
  if (m0 >= cnt) return;
  const int base = off[g];
  const int n0 = blockIdx.x * 64;
  const u16* A = x2g + (size_t)base * DD;       // contiguous rows of this group
  const u16* B = w1t + (size_t)ge * HIDN * DD;  // [HID][D]
  const int tid = threadIdx.x, lane = tid & 63, w = tid >> 6;
  const int wm = w >> 1, wn = w & 1;
  __shared__ u16 As[2][128 * 64];
  __shared__ u16 Bs[2][64 * 64];
  f32x4 acc[4][2];
#pragma unroll
  for (int i = 0; i < 4; ++i)
#pragma unroll
    for (int j = 0; j < 2; ++j) acc[i][j] = f32x4{0.f, 0.f, 0.f, 0.f};
  auto stage = [&](int t, int buf) {
    const int k0 = t * 64;
#pragma unroll
    for (int q = 0; q < 4; ++q) {
      const int idx = w * 4 + q, r = idx * 8 + (lane >> 3), c = (lane & 7) ^ (r & 7);
      int rg = m0 + r; if (rg > cnt - 1) rg = cnt - 1;
      GLOAD16(A + (size_t)rg * DD + k0 + c * 8, &As[buf][idx * 512]);
    }
#pragma unroll
    for (int q = 0; q < 2; ++q) {
      const int idx = w * 2 + q, r = idx * 8 + (lane >> 3), c = (lane & 7) ^ (r & 7);
      GLOAD16(B + (size_t)(n0 + r) * DD + k0 + c * 8, &Bs[buf][idx * 512]);
    }
  };
  stage(0, 0);
  asm volatile("s_waitcnt vmcnt(0)" ::: "memory");
  __syncthreads();
  const int T = DD / 64;
  for (int t = 0; t < T; ++t) {
    if (t + 1 < T) stage(t + 1, (t + 1) & 1);
    const u16* Ab = As[t & 1];
    const u16* Bb = Bs[t & 1];
    const int xb = (((lane >> 4) ^ (lane & 7)) * 16);
    s16x8 af[4][2], bfr[2][2];
#pragma unroll
    for (int mf = 0; mf < 4; ++mf) {
      const char* p = (const char*)Ab + (wm * 64 + mf * 16 + (lane & 15)) * 128;
      af[mf][0] = *(const s16x8*)(p + xb);
      af[mf][1] = *(const s16x8*)(p + (xb ^ 64));
    }
#pragma unroll
    for (int nf = 0; nf < 2; ++nf) {
      const char* p = (const char*)Bb + (wn * 32 + nf * 16 + (lane & 15)) * 128;
      bfr[nf][0] = *(const s16x8*)(p + xb);
      bfr[nf][1] = *(const s16x8*)(p + (xb ^ 64));
    }
#pragma unroll
    for (int ks = 0; ks < 2; ++ks)
#pragma unroll
      for (int mf = 0; mf < 4; ++mf)
#pragma unroll
        for (int nf = 0; nf < 2; ++nf)
          acc[mf][nf] = MFMA16(af[mf][ks], bfr[nf][ks], acc[mf][nf]);
    asm volatile("s_waitcnt vmcnt(0)" ::: "memory");
    __syncthreads();
  }
  const float* b1 = e_b1 + (size_t)ge * HIDN;
#pragma unroll
  for (int mf = 0; mf < 4; ++mf)
#pragma unroll
    for (int rr = 0; rr < 4; ++rr) {
      const int rowg = m0 + wm * 64 + mf * 16 + (lane >> 4) * 4 + rr;
      if (rowg < cnt) {
        u16* orow = h1 + ((size_t)e * NTOK + base + rowg) * HIDN;  // slot-ordered
#pragma unroll
        for (int nf = 0; nf < 2; ++nf) {
          const int col = n0 + wn * 32 + nf * 16 + (lane & 15);
          orow[col] = f2bf(gelu_f(acc[mf][nf][rr] + b1[col]));
        }
      }
    }
}

// ---------------- MoE GEMM2: out[tok] = 0.5*sum_e h1[e][slot] @ w2t[g,e]^T + 0.5*(b2_0+b2_1) + x2 ----------------
// grid x = n-tile (dense), y = m-tile (sparse early-exit); scatter only in the epilogue.
__global__ __launch_bounds__(256) void moe2_kernel(const u16* __restrict__ h1, const u16* __restrict__ w2t,
                            const float* __restrict__ e_b2, const int* __restrict__ off,
                            const int* __restrict__ cnts, const int* __restrict__ gidx,
                            const float* __restrict__ x2, float* __restrict__ outp) {
  const int g = blockIdx.z;
  const int cnt = cnts[g];
  const int m0 = blockIdx.y * 128;
  if (m0 >= cnt) return;
  const int base = off[g];
  const int n0 = blockIdx.x * 64;
  const int tid = threadIdx.x, lane = tid & 63, w = tid >> 6;
  const int wm = w >> 1, wn = w & 1;
  __shared__ u16 As[2][128 * 64];
  __shared__ u16 Bs[2][64 * 64];
  f32x4 acc[4][2];
#pragma unroll
  for (int i = 0; i < 4; ++i)
#pragma unroll
    for (int j = 0; j < 2; ++j) acc[i][j] = f32x4{0.f, 0.f, 0.f, 0.f};
  auto stage = [&](int t, int buf) {
    const int e = t >> 5;
    const int k0 = (t & 31) * 64;
#pragma unroll
    for (int q = 0; q < 4; ++q) {
      const int idx = w * 4 + q, r = idx * 8 + (lane >> 3), c = (lane & 7) ^ (r & 7);
      int rg = m0 + r; if (rg > cnt - 1) rg = cnt - 1;
      GLOAD16(h1 + ((size_t)e * NTOK + base + rg) * HIDN + k0 + c * 8, &As[buf][idx * 512]);
    }
#pragma unroll
    for (int q = 0; q < 2; ++q) {
      const int idx = w * 2 + q, r = idx * 8 + (lane >> 3), c = (lane & 7) ^ (r & 7);
      GLOAD16(w2t + ((size_t)(g * EE + e) * DD + n0 + r) * HIDN + k0 + c * 8, &Bs[buf][idx * 512]);
    }
  };
  stage(0, 0);
  asm volatile("s_waitcnt vmcnt(0)" ::: "memory");
  __syncthreads();
  const int T = 64;
  for (int t = 0; t < T; ++t) {
    if (t + 1 < T) stage(t + 1, (t + 1) & 1);
    const u16* Ab = As[t & 1];
    const u16* Bb = Bs[t & 1];
    const int xb = (((lane >> 4) ^ (lane & 7)) * 16);
    s16x8 af[4][2], bfr[2][2];
#pragma unroll
    for (int mf = 0; mf < 4; ++mf) {
      const char* p = (const char*)Ab + (wm * 64 + mf * 16 + (lane & 15)) * 128;
      af[mf][0] = *(const s16x8*)(p + xb);
      af[mf][1] = *(const s16x8*)(p + (xb ^ 64));
    }
#pragma unroll
    for (int nf = 0; nf < 2; ++nf) {
      const char* p = (const char*)Bb + (wn * 32 + nf * 16 + (lane & 15)) * 128;
      bfr[nf][0] = *(const s16x8*)(p + xb);
      bfr[nf][1] = *(const s16x8*)(p + (xb ^ 64));
    }
#pragma unroll
    for (int ks = 0; ks < 2; ++ks)
#pragma unroll
      for (int mf = 0; mf < 4; ++mf)
#pragma unroll
        for (int nf = 0; nf < 2; ++nf)
          acc[mf][nf] = MFMA16(af[mf][ks], bfr[nf][ks], acc[mf][nf]);
    asm volatile("s_waitcnt vmcnt(0)" ::: "memory");
    __syncthreads();
  }
  const float* b20 = e_b2 + (size_t)(g * EE + 0) * DD;
  const float* b21 = e_b2 + (size_t)(g * EE + 1) * DD;
#pragma unroll
  for (int mf = 0; mf < 4; ++mf)
#pragma unroll
    for (int rr = 0; rr < 4; ++rr) {
      const int rowg = m0 + wm * 64 + mf * 16 + (lane >> 4) * 4 + rr;
      if (rowg < cnt) {
        const int tok = gidx[base + rowg];
#pragma unroll
        for (int nf = 0; nf < 2; ++nf) {
          const int col = n0 + wn * 32 + nf * 16 + (lane & 15);
          outp[(size_t)tok * DD + col] =
              0.5f * acc[mf][nf][rr] + 0.5f * (b20[col] + b21[col]) + x2[(size_t)tok * DD + col];
        }
      }
    }
}

extern "C" void kernel_launch(void* const* d_in, const int* in_sizes, int n_in,
                              void* d_out, int out_size, void* d_ws, size_t ws_size,
                              hipStream_t stream) {
  (void)in_sizes; (void)n_in; (void)out_size; (void)ws_size;
  const float* x      = (const float*)d_in[0];
  const int*   gid    = (const int*)d_in[1];
  const float* cn_g   = (const float*)d_in[2];
  const float* cn_b   = (const float*)d_in[3];
  const float* conv_w = (const float*)d_in[4];
  const float* conv_b = (const float*)d_in[5];
  const float* an_g   = (const float*)d_in[6];
  const float* an_b   = (const float*)d_in[7];
  const float* in_w   = (const float*)d_in[8];
  const float* in_b   = (const float*)d_in[9];
  const float* out_w  = (const float*)d_in[10];
  const float* out_b  = (const float*)d_in[11];
  const float* e_w1   = (const float*)d_in[12];
  const float* e_b1   = (const float*)d_in[13];
  const float* e_w2   = (const float*)d_in[14];
  const float* e_b2   = (const float*)d_in[15];
  float* outp = (float*)d_out;

  // ---- workspace map (high-water 74MB + ~41KB, identical to r5-r7 pass) ----
  // conv phase: hb 0..4 | Pc 4..12 | Wb 12..74 (dead after conv_kernel)
  // post-conv:  x1 12..20 | qkvb 24..36 | inwb 40..46 | outwb 40..42 | Vt 46..50
  //             x2 52..60 | inv 60..60.008 (in dead-Wb hole) | x2g 64..68
  // MoE phase:  wgt 4..36 | h1 36..52 | tail at 74M: gat/cnts/offp/gidx
  // ROUTING RUNS AFTER CONV (r4 lesson: prep_convw clobbers anything inside Wb's span).
  char* wsp = (char*)d_ws;
  u16*   hb    = (u16*)(wsp);                         // 0..4M  (ln out; ctxb reuse)
  u16*   Pc    = (u16*)(wsp + (4ull << 20));          // 4..12M (conv partials x2, conv phase)
  float* x1    = (float*)(wsp + (12ull << 20));       // 12..20M (combine out)
  u16*   Wb    = (u16*)(wsp + (12ull << 20));         // 12..74M (conv phase only)
  u16*   qkvb  = (u16*)(wsp + (24ull << 20));         // 24..36M (qkv->attn)
  u16*   inwb  = (u16*)(wsp + (40ull << 20));         // 40..46M (qkv phase)
  u16*   outwb = (u16*)(wsp + (40ull << 20));         // 40..42M (out phase, after qkv)
  u16*   Vt    = (u16*)(wsp + (46ull << 20));         // 46..50M (attn phase)
  u16*   ctxb  = hb;                                  // 0..4M  (after qkv)
  float* x2    = (float*)(wsp + (52ull << 20));       // 52..60M
  int*   inv   = (int*)(wsp + (60ull << 20));         // 60M.. 8KB (tok->slot; written post-conv)
  u16*   x2g   = (u16*)(wsp + (64ull << 20));         // 64..68M (slot-packed tokens)
  u16*   wgt   = (u16*)(wsp + (4ull << 20));          // 4..36M (w1t, then w2t; MoE phase)
  u16*   h1    = (u16*)(wsp + (36ull << 20));         // 36..52M (MoE phase, slot-ordered)
  int*   gat   = (int*)(wsp + (74ull << 20));         // 32KB
  int*   cnts  = gat + GG * NTOK;                     // 16B
  int*   offp  = cnts + GG;                           // 20B
  int*   gidx  = offp + (GG + 1);                     // 8KB

  // ---- conv block (v6: barrier-free taps, private B ring-3, linear frag read) ----
  ln_kernel<<<NTOK, 256, 0, stream>>>(x, cn_g, cn_b, hb);
  prep_convw<<<1024, 256, 0, stream>>>(conv_w, Wb);
  conv_kernel<<<256, 512, 0, stream>>>(hb, Wb, Pc);
  combine_kernel<<<NTOK * DD / 1024, 256, 0, stream>>>(Pc, conv_b, x, x1);
  // ---- routing (Wb now dead; inv lives in its hole; needed by out_kernel) ----
  zero_counts_kernel<<<1, 64, 0, stream>>>(cnts);
  gather_kernel<<<NTOK / 256, 256, 0, stream>>>(gid, cnts, gat);
  scan_kernel<<<1, 64, 0, stream>>>(cnts, offp);
  pack_kernel<<<dim3(NTOK / 256, GG), 256, 0, stream>>>(gat, cnts, offp, gidx, inv);
  // ---- attention block ----
  ln_kernel<<<NTOK, 256, 0, stream>>>(x1, an_g, an_b, hb);
  cvt_kernel<<<3072, 256, 0, stream>>>(in_w, inwb, 3 * DD * DD / 4);
  qkv_kernel<<<dim3(D3 / 64, NTOK / 128), 256, 0, stream>>>(hb, inwb, in_b, qkvb);
  vtr_kernel<<<dim3(SS / 32, HDIM / 32, BB * HH), 256, 0, stream>>>(qkvb, Vt);
  attn_kernel<<<dim3(SS / 128, HH, BB), 512, 0, stream>>>(qkvb, Vt, ctxb);
  cvt_kernel<<<1024, 256, 0, stream>>>(out_w, outwb, DD * DD / 4);
  out_kernel<<<dim3(DD / 64, NTOK / 128), 256, 0, stream>>>(ctxb, outwb, out_b, x1, x2, x2g, inv);
  // ---- MoE (slot-packed + dense-fastest grids: all 8 XCDs active) ----
  tr_kernel<<<dim3(HIDN / 32, DD / 32, GG * EE), 256, 0, stream>>>(e_w1, wgt, DD, HIDN);
  moe1_kernel<<<dim3(HIDN / 64, NTOK / 128, GG * EE), 256, 0, stream>>>(x2g, wgt, e_b1, offp, cnts, h1);
  tr_kernel<<<dim3(DD / 32, HIDN / 32, GG * EE), 256, 0, stream>>>(e_w2, wgt, HIDN, DD);
  moe2_kernel<<<dim3(DD / 64, NTOK / 128, GG), 256, 0, stream>>>(h1, wgt, e_b2, offp, cnts, gidx, x2, outp);
}

// Round 9
// 493.631 us; speedup vs baseline: 1.1325x; 1.1325x over previous
//
#include <hip/hip_runtime.h>
#include <hip/hip_bf16.h>
#include <math.h>

#define BB 2
#define SS 1024
#define DD 1024
#define HH 16
#define HDIM 64
#define KK 31
#define GG 4
#define EE 2
#define HIDN 2048
#define NTOK (BB*SS)
#define D3 (3*DD)

typedef unsigned short u16;
typedef __attribute__((ext_vector_type(8))) short s16x8;
typedef __attribute__((ext_vector_type(8))) unsigned short u16x8;
typedef __attribute__((ext_vector_type(4))) unsigned short u16x4;
typedef __attribute__((ext_vector_type(4))) float f32x4;
typedef __attribute__((ext_vector_type(2))) unsigned int u32x2;

__device__ __forceinline__ float gelu_f(float x) {
  return 0.5f * x * (1.0f + erff(x * 0.7071067811865475f));
}
__device__ __forceinline__ u16 f2bf(float f) {
  unsigned u = __builtin_bit_cast(unsigned, f);
  u = (u + 0x7fffu + ((u >> 16) & 1u)) >> 16;
  return (u16)u;
}
__device__ __forceinline__ float bf2f(u16 u) {
  return __builtin_bit_cast(float, ((unsigned)u) << 16);
}
__device__ __forceinline__ f32x4 MFMA16(s16x8 a, s16x8 b, f32x4 c) {
  return __builtin_amdgcn_mfma_f32_16x16x32_bf16(a, b, c, 0, 0, 0);
}
#define GLOAD16(gp, lp) __builtin_amdgcn_global_load_lds( \
    (const __attribute__((address_space(1))) void*)(gp),  \
    (__attribute__((address_space(3))) void*)(lp), 16, 0, 0)

// ---------------- LayerNorm: fp32 in -> bf16 out, one block per row ----------------
__global__ void ln_kernel(const float* __restrict__ x, const float* __restrict__ g,
                          const float* __restrict__ b, u16* __restrict__ out) {
  const int row = blockIdx.x;
  const int tid = threadIdx.x;
  __shared__ float red[4];
  const float4 v = reinterpret_cast<const float4*>(x + (size_t)row * DD)[tid];
  float s = v.x + v.y + v.z + v.w;
  s += __shfl_down(s, 32); s += __shfl_down(s, 16); s += __shfl_down(s, 8);
  s += __shfl_down(s, 4);  s += __shfl_down(s, 2);  s += __shfl_down(s, 1);
  if ((tid & 63) == 0) red[tid >> 6] = s;
  __syncthreads();
  const float mean = (red[0] + red[1] + red[2] + red[3]) * (1.0f / DD);
  __syncthreads();
  const float4 d = make_float4(v.x - mean, v.y - mean, v.z - mean, v.w - mean);
  float sq = d.x*d.x + d.y*d.y + d.z*d.z + d.w*d.w;
  sq += __shfl_down(sq, 32); sq += __shfl_down(sq, 16); sq += __shfl_down(sq, 8);
  sq += __shfl_down(sq, 4);  sq += __shfl_down(sq, 2);  sq += __shfl_down(sq, 1);
  if ((tid & 63) == 0) red[tid >> 6] = sq;
  __syncthreads();
  const float var = (red[0] + red[1] + red[2] + red[3]) * (1.0f / DD);
  const float rstd = rsqrtf(var + 1e-5f);
  const float4 gv = reinterpret_cast<const float4*>(g)[tid];
  const float4 bv = reinterpret_cast<const float4*>(b)[tid];
  u16x4 o;
  o[0] = f2bf(d.x * rstd * gv.x + bv.x);
  o[1] = f2bf(d.y * rstd * gv.y + bv.y);
  o[2] = f2bf(d.z * rstd * gv.z + bv.z);
  o[3] = f2bf(d.w * rstd * gv.w + bv.w);
  *reinterpret_cast<u16x4*>(out + (size_t)row * DD + tid * 4) = o;
}

// ---------------- conv weight reorder: conv_w[o][i][k] f32 -> Wb[k][o][i] bf16 ----------------
__global__ void prep_convw(const float* __restrict__ cw, u16* __restrict__ Wb) {
  const int o = blockIdx.x;
#pragma unroll
  for (int rep = 0; rep < 4; ++rep) {
    const int i = rep * 256 + threadIdx.x;
    const float* src = cw + ((size_t)o * DD + i) * KK;
    float wv[KK];
#pragma unroll
    for (int k = 0; k < KK; ++k) wv[k] = src[k];
#pragma unroll
    for (int k = 0; k < KK; ++k)
      Wb[((size_t)k * DD + o) * DD + i] = f2bf(wv[k]);
  }
}

// ---------------- plain f32 -> bf16 convert ----------------
__global__ void cvt_kernel(const float* __restrict__ in, u16* __restrict__ outp, int n4) {
  const int i = blockIdx.x * 256 + threadIdx.x;
  if (i < n4) {
    const float4 v = reinterpret_cast<const float4*>(in)[i];
    u16x4 o; o[0] = f2bf(v.x); o[1] = f2bf(v.y); o[2] = f2bf(v.z); o[3] = f2bf(v.w);
    reinterpret_cast<u16x4*>(outp)[i] = o;
  }
}

// ---------------- transpose-convert: src[z][R][C] f32 -> dst[z][C][R] bf16 ----------------
__global__ void tr_kernel(const float* __restrict__ src, u16* __restrict__ dst, int R, int C) {
  __shared__ float tile[32][33];
  const int c0 = blockIdx.x * 32, r0 = blockIdx.y * 32;
  const size_t base = (size_t)blockIdx.z * R * C;
  const int tx = threadIdx.x & 31, ty = threadIdx.x >> 5;  // ty 0..7
#pragma unroll
  for (int i = 0; i < 4; ++i)
    tile[ty + i * 8][tx] = src[base + (size_t)(r0 + ty + i * 8) * C + c0 + tx];
  __syncthreads();
#pragma unroll
  for (int i = 0; i < 4; ++i)
    dst[base + (size_t)(c0 + ty + i * 8) * R + r0 + tx] = f2bf(tile[tx][ty + i * 8]);
}

// ---------------- V transpose: qkvb V-part -> Vt[b][h][d][k] bf16 ----------------
__global__ void vtr_kernel(const u16* __restrict__ qkvb, u16* __restrict__ Vt) {
  __shared__ u16 tile[32][40];
  const int k0 = blockIdx.x * 32, d0 = blockIdx.y * 32, bh = blockIdx.z;
  const int b = bh >> 4, h = bh & 15;
  const int tx = threadIdx.x & 31, ty = threadIdx.x >> 5;  // ty 0..7
#pragma unroll
  for (int i = 0; i < 4; ++i)
    tile[ty + i * 8][tx] =
        qkvb[(size_t)(b * SS + k0 + ty + i * 8) * D3 + 2 * DD + h * HDIM + d0 + tx];
  __syncthreads();
#pragma unroll
  for (int i = 0; i < 4; ++i)
    Vt[((size_t)(b * HH + h) * HDIM + d0 + ty + i * 8) * SS + k0 + tx] = tile[tx][ty + i * 8];
}

// ---------------- conv via MFMA v7: barrier-free taps, private B ring-3, coalesced + conflict-free ----------------
// v6 post-mortem: lane-linear read fixed conflicts (8.2M->131K) but broke GLOBAL coalescing
// (16B scatter, 4x requests) -> 252us. v7 satisfies BOTH constraints:
//   store (instr q, lane l, j=l>>2): o = q*16+j, c16 = (l&3) ^ ((j>>1)&3)
//     -> each quad reads one row's contiguous 64B segment (coalescing = v5)
//   read (lane g,q15; region nf): off = nf*1024 + q15*64 + (g ^ ((q15>>1)&3))*16
//     -> bank-quad = 4*(q15&1) + ((g^(q15>>1))&3): bijective per 8-lane phase, 0-conflict.
// Carry-free algebra: writer l_w = q15*4 + (g^((q15>>1)&3)); l_w>>3 = q15>>1 -> chunk = g. OK.
__global__ __launch_bounds__(512) void conv_kernel(const u16* __restrict__ hb,
                                                   const u16* __restrict__ Wb,
                                                   u16* __restrict__ P) {
  const int L = blockIdx.x;            // 0..255
  const int o_t = L & 7;               // o-tile pinned per XCD (B L2 reuse)
  const int rest = L >> 3;
  const int s_t = rest >> 1;           // 0..15
  const int z = rest & 1;              // i-half
  const int b = s_t >> 3, sloc = s_t & 7;
  const int s0l = sloc * 128;
  const int o0 = o_t * 128;
  const int ibase = z * 512;
  const int tid = threadIdx.x, lane = tid & 63, w = tid >> 6;
  const int wm = (w >> 2) & 1, wn = (w >> 1) & 1, ksid = w & 1;
  const int q15 = lane & 15, g = lane >> 4;
  __shared__ __align__(16) u16 Ad[2][160 * 64];   // 40 KB, dbuf over i-slices
  __shared__ __align__(16) u16 Bp[8][3][2048];    // 96 KB, wave-private ring-3 (4KB slots)
  const int rlo = (sloc == 0) ? 15 : 0;
  const int rhi = (sloc == 7) ? 143 : 158;
  if (sloc == 0)
    for (int i = tid; i < 15 * 64; i += 512) { Ad[0][i] = 0; Ad[1][i] = 0; }
  if (sloc == 7)
    for (int i = tid; i < 17 * 64; i += 512) { Ad[0][143 * 64 + i] = 0; Ad[1][143 * 64 + i] = 0; }
  auto stageA = [&](int buf, int i0) {
    for (int q = w; q < 20; q += 8) {
      const int r = q * 8 + (lane >> 3);
      const int c = (lane & 7) ^ (r & 7);
      if (r >= rlo && r < rhi)
        GLOAD16(hb + (size_t)(b * SS + s0l - 15 + r) * DD + i0 + c * 8, &Ad[buf][q * 512]);
    }
  };
  // private: this wave's 64o x 32i quarter for tap k at absolute i-base i0w.
  // Quad (j=l>>2) reads row o=q*16+j's 64B segment; chunk order permuted by (j>>1)&3 so the
  // frag read below is bank-quad bijective per 8-lane phase (conflict-free) while global stays
  // 64B-coalesced.
  auto stageBp = [&](int slot, int k, int i0w) {
#pragma unroll
    for (int q = 0; q < 4; ++q) {
      const int j = lane >> 2;                      // o-subrow 0..15
      const int r = q * 16 + j;                     // o-row local 0..63
      const int c16 = (lane & 3) ^ ((j >> 1) & 3);  // chunk 0..3, quad-permuted
      GLOAD16(Wb + ((size_t)k * DD + o0 + wn * 64 + r) * DD + i0w + c16 * 8,
              &Bp[w][slot][q * 512]);
    }
  };
  f32x4 acc[4][4];
#pragma unroll
  for (int i = 0; i < 4; ++i)
#pragma unroll
    for (int j = 0; j < 4; ++j) acc[i][j] = f32x4{0.f, 0.f, 0.f, 0.f};
  const int ib0 = ibase + ksid * 32;
  stageA(0, ibase);
  stageBp(0, 0, ib0);
  stageBp(1, 1, ib0);
  asm volatile("s_waitcnt vmcnt(0)" ::: "memory");
  __syncthreads();
  const int T = 8 * KK;  // 248 taps
  const int kx = ksid * 64;  // byte XOR selecting this wave's K=32 half in Ad rows
  const int bro = q15 * 64 + ((g ^ ((q15 >> 1) & 3)) << 4);  // per-lane B frag offset
  int t = 0;
  for (int i0i = 0; i0i < 8; ++i0i) {
    const u16* Ab = Ad[i0i & 1];
    for (int k = 0; k < KK; ++k, ++t) {
      {  // prefetch own B(t+2) into private ring
        const int tn = t + 2;
        if (tn < T) stageBp(tn % 3, tn % KK, ibase + (tn / KK) * 64 + ksid * 32);
      }
      // A frags from shared Ad (slice-stable)
      s16x8 af[4];
      const int rk0 = wm * 64 + q15 + k;
#pragma unroll
      for (int mf = 0; mf < 4; ++mf) {
        const int rr = rk0 + mf * 16;
        const char* p = (const char*)Ab + rr * 128;
        af[mf] = *(const s16x8*)(p + (((g ^ (rr & 7)) * 16) ^ kx));
      }
      // own B(t) landed when <= 2 taps' worth of own loads outstanding
      if (t + 2 < T)      asm volatile("s_waitcnt vmcnt(8)" ::: "memory");
      else if (t + 1 < T) asm volatile("s_waitcnt vmcnt(4)" ::: "memory");
      else                asm volatile("s_waitcnt vmcnt(0)" ::: "memory");
      // A prefetch AFTER the counted wait (issue-only; consumed after slice barrier)
      if (k == 5 && i0i < 7) stageA((i0i + 1) & 1, ibase + (i0i + 1) * 64);
      const char* Bb = (const char*)&Bp[w][t % 3][0];
      s16x8 bfr[4];
#pragma unroll
      for (int nf = 0; nf < 4; ++nf)
        bfr[nf] = *(const s16x8*)(Bb + nf * 1024 + bro);   // bank-quad bijective, 0-conflict
      __builtin_amdgcn_s_setprio(1);
#pragma unroll
      for (int mf = 0; mf < 4; ++mf)
#pragma unroll
        for (int nf = 0; nf < 4; ++nf)
          acc[mf][nf] = MFMA16(af[mf], bfr[nf], acc[mf][nf]);
      __builtin_amdgcn_s_setprio(0);
    }
    if (i0i < 7) {                       // slice boundary: Ad swap (cross-wave A visibility)
      asm volatile("s_waitcnt vmcnt(0)" ::: "memory");
      __syncthreads();
    }
  }
  // ---- ks-pair reduction: ks1 waves stash f32 acc in LDS (reuse Bp), ks0 sums+writes ----
  __syncthreads();
  float* scr = (float*)(&Bp[0][0][0]) + (wm * 2 + wn) * 4096;
  if (ksid == 1) {
#pragma unroll
    for (int mf = 0; mf < 4; ++mf)
#pragma unroll
      for (int nf = 0; nf < 4; ++nf) {
        const int col = nf * 16 + q15;
        *(f32x4*)&scr[col * 64 + ((mf * 16 + g * 4) ^ ((col & 7) << 3))] = acc[mf][nf];
      }
  }
  __syncthreads();
  if (ksid == 0) {
    u16* Pz = P + (size_t)z * NTOK * DD;
#pragma unroll
    for (int mf = 0; mf < 4; ++mf) {
      f32x4 sum[4];
#pragma unroll
      for (int nf = 0; nf < 4; ++nf) {
        const int col = nf * 16 + q15;
        const f32x4 o = *(const f32x4*)&scr[col * 64 + ((mf * 16 + g * 4) ^ ((col & 7) << 3))];
        sum[nf] = acc[mf][nf] + o;
      }
#pragma unroll
      for (int r = 0; r < 4; ++r) {
        const int srow = s0l + wm * 64 + mf * 16 + g * 4 + r;
        u16* orow = Pz + (size_t)(b * SS + srow) * DD + o0 + wn * 64;
#pragma unroll
        for (int nf = 0; nf < 4; ++nf)
          orow[nf * 16 + q15] = f2bf(sum[nf][r]);
      }
    }
  }
}

// ---------------- combine: x1 = gelu(P0+P1+cb) + x ----------------
__global__ void combine_kernel(const u16* __restrict__ P, const float* __restrict__ cb,
                               const float* __restrict__ x, float* __restrict__ x1) {
  const int idx = blockIdx.x * 256 + threadIdx.x;
  const size_t base = (size_t)idx * 4;
  const int col = (int)(base & (DD - 1));
  const u16x4 p0 = *(const u16x4*)(P + base);
  const u16x4 p1 = *(const u16x4*)(P + (size_t)NTOK * DD + base);
  const float4 xv = *(const float4*)(x + base);
  const float4 cbv = *(const float4*)(cb + col);
  float4 o;
  o.x = gelu_f(bf2f(p0[0]) + bf2f(p1[0]) + cbv.x) + xv.x;
  o.y = gelu_f(bf2f(p0[1]) + bf2f(p1[1]) + cbv.y) + xv.y;
  o.z = gelu_f(bf2f(p0[2]) + bf2f(p1[2]) + cbv.z) + xv.z;
  o.w = gelu_f(bf2f(p0[3]) + bf2f(p1[3]) + cbv.w) + xv.w;
  *(float4*)(x1 + base) = o;
}

// ---------------- qkv GEMM: qkvb[2048][3072] = hb @ inwb^T + in_b (bf16 out) ----------------
__global__ __launch_bounds__(256) void qkv_kernel(const u16* __restrict__ A, const u16* __restrict__ B,
                           const float* __restrict__ bias, u16* __restrict__ C) {
  const int n0 = blockIdx.x * 64, m0 = blockIdx.y * 128;
  const int tid = threadIdx.x, lane = tid & 63, w = tid >> 6;
  const int wm = w >> 1, wn = w & 1;
  __shared__ u16 As[2][128 * 64];
  __shared__ u16 Bs[2][64 * 64];
  f32x4 acc[4][2];
#pragma unroll
  for (int i = 0; i < 4; ++i)
#pragma unroll
    for (int j = 0; j < 2; ++j) acc[i][j] = f32x4{0.f, 0.f, 0.f, 0.f};
  auto stage = [&](int t, int buf) {
    const int k0 = t * 64;
#pragma unroll
    for (int q = 0; q < 4; ++q) {
      const int idx = w * 4 + q, r = idx * 8 + (lane >> 3), c = (lane & 7) ^ (r & 7);
      GLOAD16(A + (size_t)(m0 + r) * DD + k0 + c * 8, &As[buf][idx * 512]);
    }
#pragma unroll
    for (int q = 0; q < 2; ++q) {
      const int idx = w * 2 + q, r = idx * 8 + (lane >> 3), c = (lane & 7) ^ (r & 7);
      GLOAD16(B + (size_t)(n0 + r) * DD + k0 + c * 8, &Bs[buf][idx * 512]);
    }
  };
  stage(0, 0);
  asm volatile("s_waitcnt vmcnt(0)" ::: "memory");
  __syncthreads();
  const int T = DD / 64;
  for (int t = 0; t < T; ++t) {
    if (t + 1 < T) stage(t + 1, (t + 1) & 1);
    const u16* Ab = As[t & 1];
    const u16* Bb = Bs[t & 1];
    const int xb = (((lane >> 4) ^ (lane & 7)) * 16);
    s16x8 af[4][2], bfr[2][2];
#pragma unroll
    for (int mf = 0; mf < 4; ++mf) {
      const char* p = (const char*)Ab + (wm * 64 + mf * 16 + (lane & 15)) * 128;
      af[mf][0] = *(const s16x8*)(p + xb);
      af[mf][1] = *(const s16x8*)(p + (xb ^ 64));
    }
#pragma unroll
    for (int nf = 0; nf < 2; ++nf) {
      const char* p = (const char*)Bb + (wn * 32 + nf * 16 + (lane & 15)) * 128;
      bfr[nf][0] = *(const s16x8*)(p + xb);
      bfr[nf][1] = *(const s16x8*)(p + (xb ^ 64));
    }
#pragma unroll
    for (int ks = 0; ks < 2; ++ks)
#pragma unroll
      for (int mf = 0; mf < 4; ++mf)
#pragma unroll
        for (int nf = 0; nf < 2; ++nf)
          acc[mf][nf] = MFMA16(af[mf][ks], bfr[nf][ks], acc[mf][nf]);
    asm volatile("s_waitcnt vmcnt(0)" ::: "memory");
    __syncthreads();
  }
#pragma unroll
  for (int mf = 0; mf < 4; ++mf)
#pragma unroll
    for (int rr = 0; rr < 4; ++rr) {
      const int row = m0 + wm * 64 + mf * 16 + (lane >> 4) * 4 + rr;
#pragma unroll
      for (int nf = 0; nf < 2; ++nf) {
        const int col = n0 + wn * 32 + nf * 16 + (lane & 15);
        C[(size_t)row * D3 + col] = f2bf(acc[mf][nf][rr] + bias[col]);
      }
    }
}

// ---------------- out proj: x2 = ctxb @ outwb^T + out_b + x1 (f32 out + bf16 scatter to x2g) ----------------
__global__ __launch_bounds__(256) void out_kernel(const u16* __restrict__ A, const u16* __restrict__ B,
                           const float* __restrict__ bias, const float* __restrict__ resid,
                           float* __restrict__ C, u16* __restrict__ x2g,
                           const int* __restrict__ inv) {
  const int n0 = blockIdx.x * 64, m0 = blockIdx.y * 128;
  const int tid = threadIdx.x, lane = tid & 63, w = tid >> 6;
  const int wm = w >> 1, wn = w & 1;
  __shared__ u16 As[2][128 * 64];
  __shared__ u16 Bs[2][64 * 64];
  f32x4 acc[4][2];
#pragma unroll
  for (int i = 0; i < 4; ++i)
#pragma unroll
    for (int j = 0; j < 2; ++j) acc[i][j] = f32x4{0.f, 0.f, 0.f, 0.f};
  auto stage = [&](int t, int buf) {
    const int k0 = t * 64;
#pragma unroll
    for (int q = 0; q < 4; ++q) {
      const int idx = w * 4 + q, r = idx * 8 + (lane >> 3), c = (lane & 7) ^ (r & 7);
      GLOAD16(A + (size_t)(m0 + r) * DD + k0 + c * 8, &As[buf][idx * 512]);
    }
#pragma unroll
    for (int q = 0; q < 2; ++q) {
      const int idx = w * 2 + q, r = idx * 8 + (lane >> 3), c = (lane & 7) ^ (r & 7);
      GLOAD16(B + (size_t)(n0 + r) * DD + k0 + c * 8, &Bs[buf][idx * 512]);
    }
  };
  stage(0, 0);
  asm volatile("s_waitcnt vmcnt(0)" ::: "memory");
  __syncthreads();
  const int T = DD / 64;
  for (int t = 0; t < T; ++t) {
    if (t + 1 < T) stage(t + 1, (t + 1) & 1);
    const u16* Ab = As[t & 1];
    const u16* Bb = Bs[t & 1];
    const int xb = (((lane >> 4) ^ (lane & 7)) * 16);
    s16x8 af[4][2], bfr[2][2];
#pragma unroll
    for (int mf = 0; mf < 4; ++mf) {
      const char* p = (const char*)Ab + (wm * 64 + mf * 16 + (lane & 15)) * 128;
      af[mf][0] = *(const s16x8*)(p + xb);
      af[mf][1] = *(const s16x8*)(p + (xb ^ 64));
    }
#pragma unroll
    for (int nf = 0; nf < 2; ++nf) {
      const char* p = (const char*)Bb + (wn * 32 + nf * 16 + (lane & 15)) * 128;
      bfr[nf][0] = *(const s16x8*)(p + xb);
      bfr[nf][1] = *(const s16x8*)(p + (xb ^ 64));
    }
#pragma unroll
    for (int ks = 0; ks < 2; ++ks)
#pragma unroll
      for (int mf = 0; mf < 4; ++mf)
#pragma unroll
        for (int nf = 0; nf < 2; ++nf)
          acc[mf][nf] = MFMA16(af[mf][ks], bfr[nf][ks], acc[mf][nf]);
    asm volatile("s_waitcnt vmcnt(0)" ::: "memory");
    __syncthreads();
  }
#pragma unroll
  for (int mf = 0; mf < 4; ++mf)
#pragma unroll
    for (int rr = 0; rr < 4; ++rr) {
      const int row = m0 + wm * 64 + mf * 16 + (lane >> 4) * 4 + rr;
      const int slot = inv[row];
#pragma unroll
      for (int nf = 0; nf < 2; ++nf) {
        const int col = n0 + wn * 32 + nf * 16 + (lane & 15);
        const float v = acc[mf][nf][rr] + bias[col] + resid[(size_t)row * DD + col];
        C[(size_t)row * DD + col] = v;
        x2g[(size_t)slot * DD + col] = f2bf(v);
      }
    }
}

// ---------------- MFMA flash attention: 128 q x (b,h) per block, 8 waves x 16 q ----------------
__global__ __launch_bounds__(512) void attn_kernel(const u16* __restrict__ qkv,
                                                   const u16* __restrict__ Vt,
                                                   u16* __restrict__ ctx) {
  const int q0 = blockIdx.x * 128, h = blockIdx.y, b = blockIdx.z;
  const int tid = threadIdx.x, lane = tid & 63, w = tid >> 6;
  const int q15 = lane & 15, g = lane >> 4, l7 = lane & 7;
  __shared__ u16 Q_lds[128 * 64];
  __shared__ u16 K_lds[2][64 * 64];
  __shared__ u16 V_lds[2][64 * 64];
  __shared__ u16 P_lds[8][16 * 72];
  __shared__ float s_lds[8][16];

#pragma unroll
  for (int q2 = 0; q2 < 2; ++q2) {
    const int idx = w * 2 + q2;
    const int r = idx * 8 + (lane >> 3);
    const int c = l7 ^ (r & 7);
    GLOAD16(qkv + (size_t)(b * SS + q0 + r) * D3 + h * HDIM + c * 8, &Q_lds[idx * 512]);
  }
  auto stageK = [&](int buf, int kt) {
    const int r = w * 8 + (lane >> 3);
    const int c = l7 ^ (r & 7);
    GLOAD16(qkv + (size_t)(b * SS + kt * 64 + r) * D3 + DD + h * HDIM + c * 8,
            &K_lds[buf][w * 512]);
  };
  auto stageV = [&](int buf, int kt) {
    const int r = w * 8 + (lane >> 3);
    const int c = l7 ^ (r & 7);
    GLOAD16(Vt + ((size_t)(b * HH + h) * HDIM + r) * SS + kt * 64 + c * 8,
            &V_lds[buf][w * 512]);
  };
  stageK(0, 0);
  stageV(0, 0);
  asm volatile("s_waitcnt vmcnt(0)" ::: "memory");
  __syncthreads();
  s16x8 bq[2];
#pragma unroll
  for (int ks = 0; ks < 2; ++ks)
    bq[ks] = *(const s16x8*)((const char*)Q_lds + (w * 16 + q15) * 128 + ((4 * ks + g) ^ l7) * 16);
  f32x4 oacc[4];
#pragma unroll
  for (int nf = 0; nf < 4; ++nf) oacc[nf] = f32x4{0.f, 0.f, 0.f, 0.f};
  float mrun = -3.0e38f, lrun = 0.0f;
  int buf = 0;
  for (int kt = 0; kt < 16; ++kt) {
    if (kt < 15) { stageK(buf ^ 1, kt + 1); stageV(buf ^ 1, kt + 1); }
    f32x4 st[4];
#pragma unroll
    for (int mf = 0; mf < 4; ++mf) st[mf] = f32x4{0.f, 0.f, 0.f, 0.f};
#pragma unroll
    for (int ks = 0; ks < 2; ++ks) {
#pragma unroll
      for (int mf = 0; mf < 4; ++mf) {
        const s16x8 ka = *(const s16x8*)((const char*)K_lds[buf] + (mf * 16 + q15) * 128 +
                                         ((4 * ks + g) ^ l7) * 16);
        st[mf] = MFMA16(ka, bq[ks], st[mf]);
      }
    }
    float t0[4][4];
    float cmax = -3.0e38f;
#pragma unroll
    for (int mf = 0; mf < 4; ++mf)
#pragma unroll
      for (int r = 0; r < 4; ++r) {
        const float v = st[mf][r] * 0.125f;
        t0[mf][r] = v;
        cmax = fmaxf(cmax, v);
      }
    cmax = fmaxf(cmax, __shfl_xor(cmax, 16));
    cmax = fmaxf(cmax, __shfl_xor(cmax, 32));
    const float mnew = fmaxf(mrun, cmax);
    const float scf = __expf(mrun - mnew);
    float psum = 0.f;
#pragma unroll
    for (int mf = 0; mf < 4; ++mf)
#pragma unroll
      for (int r = 0; r < 4; ++r) {
        const float p = __expf(t0[mf][r] - mnew);
        t0[mf][r] = p;
        psum += p;
      }
    psum += __shfl_xor(psum, 16);
    psum += __shfl_xor(psum, 32);
    lrun = lrun * scf + psum;
    mrun = mnew;
    s_lds[w][q15] = scf;
    u16* pw = &P_lds[w][0];
#pragma unroll
    for (int mf = 0; mf < 4; ++mf) {
      u32x2 pk;
      pk[0] = (unsigned)f2bf(t0[mf][0]) | ((unsigned)f2bf(t0[mf][1]) << 16);
      pk[1] = (unsigned)f2bf(t0[mf][2]) | ((unsigned)f2bf(t0[mf][3]) << 16);
      *(u32x2*)(pw + q15 * 72 + mf * 16 + g * 4) = pk;
    }
    asm volatile("s_waitcnt lgkmcnt(0)" ::: "memory");
    const f32x4 scv = *(const f32x4*)&s_lds[w][g * 4];
#pragma unroll
    for (int nf = 0; nf < 4; ++nf)
#pragma unroll
      for (int r = 0; r < 4; ++r) oacc[nf][r] *= scv[r];
#pragma unroll
    for (int ks = 0; ks < 2; ++ks) {
      const s16x8 pa = *(const s16x8*)(pw + q15 * 72 + ks * 32 + g * 8);
#pragma unroll
      for (int nf = 0; nf < 4; ++nf) {
        const s16x8 bv = *(const s16x8*)((const char*)V_lds[buf] + (nf * 16 + q15) * 128 +
                                         ((4 * ks + g) ^ l7) * 16);
        oacc[nf] = MFMA16(pa, bv, oacc[nf]);
      }
    }
    asm volatile("s_waitcnt vmcnt(0)" ::: "memory");
    __syncthreads();
    buf ^= 1;
  }
  const float linv = 1.0f / lrun;
  s_lds[w][q15] = linv;
  asm volatile("s_waitcnt lgkmcnt(0)" ::: "memory");
  const f32x4 lv = *(const f32x4*)&s_lds[w][g * 4];
#pragma unroll
  for (int nf = 0; nf < 4; ++nf)
#pragma unroll
    for (int r = 0; r < 4; ++r) {
      const int qg = q0 + w * 16 + g * 4 + r;
      ctx[(size_t)(b * SS + qg) * DD + h * HDIM + nf * 16 + q15] = f2bf(oacc[nf][r] * lv[r]);
    }
}

// ---------------- MoE routing ----------------
__global__ void zero_counts_kernel(int* c) { if (threadIdx.x < GG) c[threadIdx.x] = 0; }

__global__ void gather_kernel(const int* __restrict__ gid, int* __restrict__ counts,
                              int* __restrict__ gather) {
  const int n = blockIdx.x * 256 + threadIdx.x;
  if (n < NTOK) {
    const int g = gid[n];
    const int slot = atomicAdd(&counts[g], 1);
    gather[g * NTOK + slot] = n;
  }
}

// off[g] = exclusive prefix sum of counts; off[GG] = NTOK
__global__ void scan_kernel(const int* __restrict__ cnts, int* __restrict__ off) {
  if (threadIdx.x == 0) {
    int s = 0;
#pragma unroll
    for (int g = 0; g < GG; ++g) { off[g] = s; s += cnts[g]; }
    off[GG] = s;
  }
}

// gidx[off[g]+slot] = tok ; inv[tok] = off[g]+slot
__global__ void pack_kernel(const int* __restrict__ gat, const int* __restrict__ cnts,
                            const int* __restrict__ off, int* __restrict__ gidx,
                            int* __restrict__ inv) {
  const int g = blockIdx.y;
  const int slot = blockIdx.x * 256 + threadIdx.x;
  if (slot < cnts[g]) {
    const int tok = gat[g * NTOK + slot];
    const int sg = off[g] + slot;
    gidx[sg] = tok;
    inv[tok] = sg;
  }
}

// ---------------- MoE GEMM1: h1[e][base+slot] = gelu(x2g[base+slot] @ w1t[g,e]^T + b1) ----------------
// grid x = n-tile (dense -> all XCD residues active), y = m-tile (sparse early-exit).
__global__ __launch_bounds__(256) void moe1_kernel(const u16* __restrict__ x2g, const u16* __restrict__ w1t,
                            const float* __restrict__ e_b1, const int* __restrict__ off,
                            const int* __restrict__ cnts, u16* __restrict__ h1) {
  const int ge = blockIdx.z, g = ge >> 1, e = ge & 1;
  const int cnt = cnts[g];
  const int m0 = blockIdx.y * 128;
  if (m0 >= cnt) return;
  const int base = off[g];
  const int n0 = blockIdx.x * 64;
  const u16* A = x2g + (size_t)base * DD;       // contiguous rows of this group
  const u16* B = w1t + (size_t)ge * HIDN * DD;  // [HID][D]
  const int tid = threadIdx.x, lane = tid & 63, w = tid >> 6;
  const int wm = w >> 1, wn = w & 1;
  __shared__ u16 As[2][128 * 64];
  __shared__ u16 Bs[2][64 * 64];
  f32x4 acc[4][2];
#pragma unroll
  for (int i = 0; i < 4; ++i)
#pragma unroll
    for (int j = 0; j < 2; ++j) acc[i][j] = f32x4{0.f, 0.f, 0.f, 0.f};
  auto stage = [&](int t, int buf) {
    const int k0 = t * 64;
#pragma unroll
    for (int q = 0; q < 4; ++q) {
      const int idx = w * 4 + q, r = idx * 8 + (lane >> 3), c = (lane & 7) ^ (r & 7);
      int rg = m0 + r; if (rg > cnt - 1) rg = cnt - 1;
      GLOAD16(A + (size_t)rg * DD + k0 + c * 8, &As[buf][idx * 512]);
    }
#pragma unroll
    for (int q = 0; q < 2; ++q) {
      const int idx = w * 2 + q, r = idx * 8 + (lane >> 3), c = (lane & 7) ^ (r & 7);
      GLOAD16(B + (size_t)(n0 + r) * DD + k0 + c * 8, &Bs[buf][idx * 512]);
    }
  };
  stage(0, 0);
  asm volatile("s_waitcnt vmcnt(0)" ::: "memory");
  __syncthreads();
  const int T = DD / 64;
  for (int t = 0; t < T; ++t) {
    if (t + 1 < T) stage(t + 1, (t + 1) & 1);
    const u16* Ab = As[t & 1];
    const u16* Bb = Bs[t & 1];
    const int xb = (((lane >> 4) ^ (lane & 7)) * 16);
    s16x8 af[4][2], bfr[2][2];
#pragma unroll
    for (int mf = 0; mf < 4; ++mf) {
      const char* p = (const char*)Ab + (wm * 64 + mf * 16 + (lane & 15)) * 128;
      af[mf][0] = *(const s16x8*)(p + xb);
      af[mf][1] = *(const s16x8*)(p + (xb ^ 64));
    }
#pragma unroll
    for (int nf = 0; nf < 2; ++nf) {
      const char* p = (const char*)Bb + (wn * 32 + nf * 16 + (lane & 15)) * 128;
      bfr[nf][0] = *(const s16x8*)(p + xb);
      bfr[nf][1] = *(const s16x8*)(p + (xb ^ 64));
    }
#pragma unroll
    for (int ks = 0; ks < 2; ++ks)
#pragma unroll
      for (int mf = 0; mf < 4; ++mf)
#pragma unroll
        for (int nf = 0; nf < 2; ++nf)
          acc[mf][nf] = MFMA16(af[mf][ks], bfr[nf][ks], acc[mf][nf]);
    asm volatile("s_waitcnt vmcnt(0)" ::: "memory");
    __syncthreads();
  }
  const float* b1 = e_b1 + (size_t)ge * HIDN;
#pragma unroll
  for (int mf = 0; mf < 4; ++mf)
#pragma unroll
    for (int rr = 0; rr < 4; ++rr) {
      const int rowg = m0 + wm * 64 + mf * 16 + (lane >> 4) * 4 + rr;
      if (rowg < cnt) {
        u16* orow = h1 + ((size_t)e * NTOK + base + rowg) * HIDN;  // slot-ordered
#pragma unroll
        for (int nf = 0; nf < 2; ++nf) {
          const int col = n0 + wn * 32 + nf * 16 + (lane & 15);
          orow[col] = f2bf(gelu_f(acc[mf][nf][rr] + b1[col]));
        }
      }
    }
}

// ---------------- MoE GEMM2: out[tok] = 0.5*sum_e h1[e][slot] @ w2t[g,e]^T + 0.5*(b2_0+b2_1) + x2 ----------------
// grid x = n-tile (dense), y = m-tile (sparse early-exit); scatter only in the epilogue.
__global__ __launch_bounds__(256) void moe2_kernel(const u16* __restrict__ h1, const u16* __restrict__ w2t,
                            const float* __restrict__ e_b2, const int* __restrict__ off,
                            const int* __restrict__ cnts, const int* __restrict__ gidx,
                            const float* __restrict__ x2, float* __restrict__ outp) {
  const int g = blockIdx.z;
  const int cnt = cnts[g];
  const int m0 = blockIdx.y * 128;
  if (m0 >= cnt) return;
  const int base = off[g];
  const int n0 = blockIdx.x * 64;
  const int tid = threadIdx.x, lane = tid & 63, w = tid >> 6;
  const int wm = w >> 1, wn = w & 1;
  __shared__ u16 As[2][128 * 64];
  __shared__ u16 Bs[2][64 * 64];
  f32x4 acc[4][2];
#pragma unroll
  for (int i = 0; i < 4; ++i)
#pragma unroll
    for (int j = 0; j < 2; ++j) acc[i][j] = f32x4{0.f, 0.f, 0.f, 0.f};
  auto stage = [&](int t, int buf) {
    const int e = t >> 5;
    const int k0 = (t & 31) * 64;
#pragma unroll
    for (int q = 0; q < 4; ++q) {
      const int idx = w * 4 + q, r = idx * 8 + (lane >> 3), c = (lane & 7) ^ (r & 7);
      int rg = m0 + r; if (rg > cnt - 1) rg = cnt - 1;
      GLOAD16(h1 + ((size_t)e * NTOK + base + rg) * HIDN + k0 + c * 8, &As[buf][idx * 512]);
    }
#pragma unroll
    for (int q = 0; q < 2; ++q) {
      const int idx = w * 2 + q, r = idx * 8 + (lane >> 3), c = (lane & 7) ^ (r & 7);
      GLOAD16(w2t + ((size_t)(g * EE + e) * DD + n0 + r) * HIDN + k0 + c * 8, &Bs[buf][idx * 512]);
    }
  };
  stage(0, 0);
  asm volatile("s_waitcnt vmcnt(0)" ::: "memory");
  __syncthreads();
  const int T = 64;
  for (int t = 0; t < T; ++t) {
    if (t + 1 < T) stage(t + 1, (t + 1) & 1);
    const u16* Ab = As[t & 1];
    const u16* Bb = Bs[t & 1];
    const int xb = (((lane >> 4) ^ (lane & 7)) * 16);
    s16x8 af[4][2], bfr[2][2];
#pragma unroll
    for (int mf = 0; mf < 4; ++mf) {
      const char* p = (const char*)Ab + (wm * 64 + mf * 16 + (lane & 15)) * 128;
      af[mf][0] = *(const s16x8*)(p + xb);
      af[mf][1] = *(const s16x8*)(p + (xb ^ 64));
    }
#pragma unroll
    for (int nf = 0; nf < 2; ++nf) {
      const char* p = (const char*)Bb + (wn * 32 + nf * 16 + (lane & 15)) * 128;
      bfr[nf][0] = *(const s16x8*)(p + xb);
      bfr[nf][1] = *(const s16x8*)(p + (xb ^ 64));
    }
#pragma unroll
    for (int ks = 0; ks < 2; ++ks)
#pragma unroll
      for (int mf = 0; mf < 4; ++mf)
#pragma unroll
        for (int nf = 0; nf < 2; ++nf)
          acc[mf][nf] = MFMA16(af[mf][ks], bfr[nf][ks], acc[mf][nf]);
    asm volatile("s_waitcnt vmcnt(0)" ::: "memory");
    __syncthreads();
  }
  const float* b20 = e_b2 + (size_t)(g * EE + 0) * DD;
  const float* b21 = e_b2 + (size_t)(g * EE + 1) * DD;
#pragma unroll
  for (int mf = 0; mf < 4; ++mf)
#pragma unroll
    for (int rr = 0; rr < 4; ++rr) {
      const int rowg = m0 + wm * 64 + mf * 16 + (lane >> 4) * 4 + rr;
      if (rowg < cnt) {
        const int tok = gidx[base + rowg];
#pragma unroll
        for (int nf = 0; nf < 2; ++nf) {
          const int col = n0 + wn * 32 + nf * 16 + (lane & 15);
          outp[(size_t)tok * DD + col] =
              0.5f * acc[mf][nf][rr] + 0.5f * (b20[col] + b21[col]) + x2[(size_t)tok * DD + col];
        }
      }
    }
}

extern "C" void kernel_launch(void* const* d_in, const int* in_sizes, int n_in,
                              void* d_out, int out_size, void* d_ws, size_t ws_size,
                              hipStream_t stream) {
  (void)in_sizes; (void)n_in; (void)out_size; (void)ws_size;
  const float* x      = (const float*)d_in[0];
  const int*   gid    = (const int*)d_in[1];
  const float* cn_g   = (const float*)d_in[2];
  const float* cn_b   = (const float*)d_in[3];
  const float* conv_w = (const float*)d_in[4];
  const float* conv_b = (const float*)d_in[5];
  const float* an_g   = (const float*)d_in[6];
  const float* an_b   = (const float*)d_in[7];
  const float* in_w   = (const float*)d_in[8];
  const float* in_b   = (const float*)d_in[9];
  const float* out_w  = (const float*)d_in[10];
  const float* out_b  = (const float*)d_in[11];
  const float* e_w1   = (const float*)d_in[12];
  const float* e_b1   = (const float*)d_in[13];
  const float* e_w2   = (const float*)d_in[14];
  const float* e_b2   = (const float*)d_in[15];
  float* outp = (float*)d_out;

  // ---- workspace map (high-water 74MB + ~41KB, identical to r5-r8 pass) ----
  // conv phase: hb 0..4 | Pc 4..12 | Wb 12..74 (dead after conv_kernel)
  // post-conv:  x1 12..20 | qkvb 24..36 | inwb 40..46 | outwb 40..42 | Vt 46..50
  //             x2 52..60 | inv 60..60.008 (in dead-Wb hole) | x2g 64..68
  // MoE phase:  wgt 4..36 | h1 36..52 | tail at 74M: gat/cnts/offp/gidx
  // ROUTING RUNS AFTER CONV (r4 lesson: prep_convw clobbers anything inside Wb's span).
  char* wsp = (char*)d_ws;
  u16*   hb    = (u16*)(wsp);                         // 0..4M  (ln out; ctxb reuse)
  u16*   Pc    = (u16*)(wsp + (4ull << 20));          // 4..12M (conv partials x2, conv phase)
  float* x1    = (float*)(wsp + (12ull << 20));       // 12..20M (combine out)
  u16*   Wb    = (u16*)(wsp + (12ull << 20));         // 12..74M (conv phase only)
  u16*   qkvb  = (u16*)(wsp + (24ull << 20));         // 24..36M (qkv->attn)
  u16*   inwb  = (u16*)(wsp + (40ull << 20));         // 40..46M (qkv phase)
  u16*   outwb = (u16*)(wsp + (40ull << 20));         // 40..42M (out phase, after qkv)
  u16*   Vt    = (u16*)(wsp + (46ull << 20));         // 46..50M (attn phase)
  u16*   ctxb  = hb;                                  // 0..4M  (after qkv)
  float* x2    = (float*)(wsp + (52ull << 20));       // 52..60M
  int*   inv   = (int*)(wsp + (60ull << 20));         // 60M.. 8KB (tok->slot; written post-conv)
  u16*   x2g   = (u16*)(wsp + (64ull << 20));         // 64..68M (slot-packed tokens)
  u16*   wgt   = (u16*)(wsp + (4ull << 20));          // 4..36M (w1t, then w2t; MoE phase)
  u16*   h1    = (u16*)(wsp + (36ull << 20));         // 36..52M (MoE phase, slot-ordered)
  int*   gat   = (int*)(wsp + (74ull << 20));         // 32KB
  int*   cnts  = gat + GG * NTOK;                     // 16B
  int*   offp  = cnts + GG;                           // 20B
  int*   gidx  = offp + (GG + 1);                     // 8KB

  // ---- conv block (v7: barrier-free taps, private B ring-3, coalesced + conflict-free) ----
  ln_kernel<<<NTOK, 256, 0, stream>>>(x, cn_g, cn_b, hb);
  prep_convw<<<1024, 256, 0, stream>>>(conv_w, Wb);
  conv_kernel<<<256, 512, 0, stream>>>(hb, Wb, Pc);
  combine_kernel<<<NTOK * DD / 1024, 256, 0, stream>>>(Pc, conv_b, x, x1);
  // ---- routing (Wb now dead; inv lives in its hole; needed by out_kernel) ----
  zero_counts_kernel<<<1, 64, 0, stream>>>(cnts);
  gather_kernel<<<NTOK / 256, 256, 0, stream>>>(gid, cnts, gat);
  scan_kernel<<<1, 64, 0, stream>>>(cnts, offp);
  pack_kernel<<<dim3(NTOK / 256, GG), 256, 0, stream>>>(gat, cnts, offp, gidx, inv);
  // ---- attention block ----
  ln_kernel<<<NTOK, 256, 0, stream>>>(x1, an_g, an_b, hb);
  cvt_kernel<<<3072, 256, 0, stream>>>(in_w, inwb, 3 * DD * DD / 4);
  qkv_kernel<<<dim3(D3 / 64, NTOK / 128), 256, 0, stream>>>(hb, inwb, in_b, qkvb);
  vtr_kernel<<<dim3(SS / 32, HDIM / 32, BB * HH), 256, 0, stream>>>(qkvb, Vt);
  attn_kernel<<<dim3(SS / 128, HH, BB), 512, 0, stream>>>(qkvb, Vt, ctxb);
  cvt_kernel<<<1024, 256, 0, stream>>>(out_w, outwb, DD * DD / 4);
  out_kernel<<<dim3(DD / 64, NTOK / 128), 256, 0, stream>>>(ctxb, outwb, out_b, x1, x2, x2g, inv);
  // ---- MoE (slot-packed + dense-fastest grids: all 8 XCDs active) ----
  tr_kernel<<<dim3(HIDN / 32, DD / 32, GG * EE), 256, 0, stream>>>(e_w1, wgt, DD, HIDN);
  moe1_kernel<<<dim3(HIDN / 64, NTOK / 128, GG * EE), 256, 0, stream>>>(x2g, wgt, e_b1, offp, cnts, h1);
  tr_kernel<<<dim3(DD / 32, HIDN / 32, GG * EE), 256, 0, stream>>>(e_w2, wgt, HIDN, DD);
  moe2_kernel<<<dim3(DD / 64, NTOK / 128, GG), 256, 0, stream>>>(h1, wgt, e_b2, offp, cnts, gidx, x2, outp);
}

// Round 11
// 493.116 us; speedup vs baseline: 1.1337x; 1.0010x over previous
//
#include <hip/hip_runtime.h>
#include <hip/hip_bf16.h>
#include <math.h>

#define BB 2
#define SS 1024
#define DD 1024
#define HH 16
#define HDIM 64
#define KK 31
#define GG 4
#define EE 2
#define HIDN 2048
#define NTOK (BB*SS)
#define D3 (3*DD)

typedef unsigned short u16;
typedef __attribute__((ext_vector_type(8))) short s16x8;
typedef __attribute__((ext_vector_type(8))) unsigned short u16x8;
typedef __attribute__((ext_vector_type(4))) unsigned short u16x4;
typedef __attribute__((ext_vector_type(4))) float f32x4;
typedef __attribute__((ext_vector_type(2))) unsigned int u32x2;

__device__ __forceinline__ float gelu_f(float x) {
  return 0.5f * x * (1.0f + erff(x * 0.7071067811865475f));
}
__device__ __forceinline__ u16 f2bf(float f) {
  unsigned u = __builtin_bit_cast(unsigned, f);
  u = (u + 0x7fffu + ((u >> 16) & 1u)) >> 16;
  return (u16)u;
}
__device__ __forceinline__ float bf2f(u16 u) {
  return __builtin_bit_cast(float, ((unsigned)u) << 16);
}
__device__ __forceinline__ f32x4 MFMA16(s16x8 a, s16x8 b, f32x4 c) {
  return __builtin_amdgcn_mfma_f32_16x16x32_bf16(a, b, c, 0, 0, 0);
}
#define GLOAD16(gp, lp) __builtin_amdgcn_global_load_lds( \
    (const __attribute__((address_space(1))) void*)(gp),  \
    (__attribute__((address_space(3))) void*)(lp), 16, 0, 0)

// ---------------- LayerNorm: fp32 in -> bf16 out, one block per row ----------------
__global__ void ln_kernel(const float* __restrict__ x, const float* __restrict__ g,
                          const float* __restrict__ b, u16* __restrict__ out) {
  const int row = blockIdx.x;
  const int tid = threadIdx.x;
  __shared__ float red[4];
  const float4 v = reinterpret_cast<const float4*>(x + (size_t)row * DD)[tid];
  float s = v.x + v.y + v.z + v.w;
  s += __shfl_down(s, 32); s += __shfl_down(s, 16); s += __shfl_down(s, 8);
  s += __shfl_down(s, 4);  s += __shfl_down(s, 2);  s += __shfl_down(s, 1);
  if ((tid & 63) == 0) red[tid >> 6] = s;
  __syncthreads();
  const float mean = (red[0] + red[1] + red[2] + red[3]) * (1.0f / DD);
  __syncthreads();
  const float4 d = make_float4(v.x - mean, v.y - mean, v.z - mean, v.w - mean);
  float sq = d.x*d.x + d.y*d.y + d.z*d.z + d.w*d.w;
  sq += __shfl_down(sq, 32); sq += __shfl_down(sq, 16); sq += __shfl_down(sq, 8);
  sq += __shfl_down(sq, 4);  sq += __shfl_down(sq, 2);  sq += __shfl_down(sq, 1);
  if ((tid & 63) == 0) red[tid >> 6] = sq;
  __syncthreads();
  const float var = (red[0] + red[1] + red[2] + red[3]) * (1.0f / DD);
  const float rstd = rsqrtf(var + 1e-5f);
  const float4 gv = reinterpret_cast<const float4*>(g)[tid];
  const float4 bv = reinterpret_cast<const float4*>(b)[tid];
  u16x4 o;
  o[0] = f2bf(d.x * rstd * gv.x + bv.x);
  o[1] = f2bf(d.y * rstd * gv.y + bv.y);
  o[2] = f2bf(d.z * rstd * gv.z + bv.z);
  o[3] = f2bf(d.w * rstd * gv.w + bv.w);
  *reinterpret_cast<u16x4*>(out + (size_t)row * DD + tid * 4) = o;
}

// ---------------- conv weight reorder: conv_w[o][i][k] f32 -> Wb[k][o][i] bf16 ----------------
__global__ void prep_convw(const float* __restrict__ cw, u16* __restrict__ Wb) {
  const int o = blockIdx.x;
#pragma unroll
  for (int rep = 0; rep < 4; ++rep) {
    const int i = rep * 256 + threadIdx.x;
    const float* src = cw + ((size_t)o * DD + i) * KK;
    float wv[KK];
#pragma unroll
    for (int k = 0; k < KK; ++k) wv[k] = src[k];
#pragma unroll
    for (int k = 0; k < KK; ++k)
      Wb[((size_t)k * DD + o) * DD + i] = f2bf(wv[k]);
  }
}

// ---------------- plain f32 -> bf16 convert ----------------
__global__ void cvt_kernel(const float* __restrict__ in, u16* __restrict__ outp, int n4) {
  const int i = blockIdx.x * 256 + threadIdx.x;
  if (i < n4) {
    const float4 v = reinterpret_cast<const float4*>(in)[i];
    u16x4 o; o[0] = f2bf(v.x); o[1] = f2bf(v.y); o[2] = f2bf(v.z); o[3] = f2bf(v.w);
    reinterpret_cast<u16x4*>(outp)[i] = o;
  }
}

// ---------------- transpose-convert: src[z][R][C] f32 -> dst[z][C][R] bf16 ----------------
__global__ void tr_kernel(const float* __restrict__ src, u16* __restrict__ dst, int R, int C) {
  __shared__ float tile[32][33];
  const int c0 = blockIdx.x * 32, r0 = blockIdx.y * 32;
  const size_t base = (size_t)blockIdx.z * R * C;
  const int tx = threadIdx.x & 31, ty = threadIdx.x >> 5;  // ty 0..7
#pragma unroll
  for (int i = 0; i < 4; ++i)
    tile[ty + i * 8][tx] = src[base + (size_t)(r0 + ty + i * 8) * C + c0 + tx];
  __syncthreads();
#pragma unroll
  for (int i = 0; i < 4; ++i)
    dst[base + (size_t)(c0 + ty + i * 8) * R + r0 + tx] = f2bf(tile[tx][ty + i * 8]);
}

// ---------------- V transpose: qkvb V-part -> Vt[b][h][d][k] bf16 ----------------
__global__ void vtr_kernel(const u16* __restrict__ qkvb, u16* __restrict__ Vt) {
  __shared__ u16 tile[32][40];
  const int k0 = blockIdx.x * 32, d0 = blockIdx.y * 32, bh = blockIdx.z;
  const int b = bh >> 4, h = bh & 15;
  const int tx = threadIdx.x & 31, ty = threadIdx.x >> 5;  // ty 0..7
#pragma unroll
  for (int i = 0; i < 4; ++i)
    tile[ty + i * 8][tx] =
        qkvb[(size_t)(b * SS + k0 + ty + i * 8) * D3 + 2 * DD + h * HDIM + d0 + tx];
  __syncthreads();
#pragma unroll
  for (int i = 0; i < 4; ++i)
    Vt[((size_t)(b * HH + h) * HDIM + d0 + ty + i * 8) * SS + k0 + tx] = tile[tx][ty + i * 8];
}

// ---------------- conv via MFMA v7 (measured 179us): barrier-free taps, private B ring-3 ----------------
__global__ __launch_bounds__(512) void conv_kernel(const u16* __restrict__ hb,
                                                   const u16* __restrict__ Wb,
                                                   u16* __restrict__ P) {
  const int L = blockIdx.x;            // 0..255
  const int o_t = L & 7;               // o-tile pinned per XCD (B L2 reuse)
  const int rest = L >> 3;
  const int s_t = rest >> 1;           // 0..15
  const int z = rest & 1;              // i-half
  const int b = s_t >> 3, sloc = s_t & 7;
  const int s0l = sloc * 128;
  const int o0 = o_t * 128;
  const int ibase = z * 512;
  const int tid = threadIdx.x, lane = tid & 63, w = tid >> 6;
  const int wm = (w >> 2) & 1, wn = (w >> 1) & 1, ksid = w & 1;
  const int q15 = lane & 15, g = lane >> 4;
  __shared__ __align__(16) u16 Ad[2][160 * 64];   // 40 KB, dbuf over i-slices
  __shared__ __align__(16) u16 Bp[8][3][2048];    // 96 KB, wave-private ring-3 (4KB slots)
  const int rlo = (sloc == 0) ? 15 : 0;
  const int rhi = (sloc == 7) ? 143 : 158;
  if (sloc == 0)
    for (int i = tid; i < 15 * 64; i += 512) { Ad[0][i] = 0; Ad[1][i] = 0; }
  if (sloc == 7)
    for (int i = tid; i < 17 * 64; i += 512) { Ad[0][143 * 64 + i] = 0; Ad[1][143 * 64 + i] = 0; }
  auto stageA = [&](int buf, int i0) {
    for (int q = w; q < 20; q += 8) {
      const int r = q * 8 + (lane >> 3);
      const int c = (lane & 7) ^ (r & 7);
      if (r >= rlo && r < rhi)
        GLOAD16(hb + (size_t)(b * SS + s0l - 15 + r) * DD + i0 + c * 8, &Ad[buf][q * 512]);
    }
  };
  auto stageBp = [&](int slot, int k, int i0w) {
#pragma unroll
    for (int q = 0; q < 4; ++q) {
      const int j = lane >> 2;                      // o-subrow 0..15
      const int r = q * 16 + j;                     // o-row local 0..63
      const int c16 = (lane & 3) ^ ((j >> 1) & 3);  // chunk 0..3, quad-permuted
      GLOAD16(Wb + ((size_t)k * DD + o0 + wn * 64 + r) * DD + i0w + c16 * 8,
              &Bp[w][slot][q * 512]);
    }
  };
  f32x4 acc[4][4];
#pragma unroll
  for (int i = 0; i < 4; ++i)
#pragma unroll
    for (int j = 0; j < 4; ++j) acc[i][j] = f32x4{0.f, 0.f, 0.f, 0.f};
  const int ib0 = ibase + ksid * 32;
  stageA(0, ibase);
  stageBp(0, 0, ib0);
  stageBp(1, 1, ib0);
  asm volatile("s_waitcnt vmcnt(0)" ::: "memory");
  __syncthreads();
  const int T = 8 * KK;  // 248 taps
  const int kx = ksid * 64;  // byte XOR selecting this wave's K=32 half in Ad rows
  const int bro = q15 * 64 + ((g ^ ((q15 >> 1) & 3)) << 4);  // per-lane B frag offset
  int t = 0;
  for (int i0i = 0; i0i < 8; ++i0i) {
    const u16* Ab = Ad[i0i & 1];
    for (int k = 0; k < KK; ++k, ++t) {
      {  // prefetch own B(t+2) into private ring
        const int tn = t + 2;
        if (tn < T) stageBp(tn % 3, tn % KK, ibase + (tn / KK) * 64 + ksid * 32);
      }
      // A frags from shared Ad (slice-stable)
      s16x8 af[4];
      const int rk0 = wm * 64 + q15 + k;
#pragma unroll
      for (int mf = 0; mf < 4; ++mf) {
        const int rr = rk0 + mf * 16;
        const char* p = (const char*)Ab + rr * 128;
        af[mf] = *(const s16x8*)(p + (((g ^ (rr & 7)) * 16) ^ kx));
      }
      // own B(t) landed when <= 2 taps' worth of own loads outstanding
      if (t + 2 < T)      asm volatile("s_waitcnt vmcnt(8)" ::: "memory");
      else if (t + 1 < T) asm volatile("s_waitcnt vmcnt(4)" ::: "memory");
      else                asm volatile("s_waitcnt vmcnt(0)" ::: "memory");
      // A prefetch AFTER the counted wait (issue-only; consumed after slice barrier)
      if (k == 5 && i0i < 7) stageA((i0i + 1) & 1, ibase + (i0i + 1) * 64);
      const char* Bb = (const char*)&Bp[w][t % 3][0];
      s16x8 bfr[4];
#pragma unroll
      for (int nf = 0; nf < 4; ++nf)
        bfr[nf] = *(const s16x8*)(Bb + nf * 1024 + bro);   // bank-quad bijective, 0-conflict
      __builtin_amdgcn_s_setprio(1);
#pragma unroll
      for (int mf = 0; mf < 4; ++mf)
#pragma unroll
        for (int nf = 0; nf < 4; ++nf)
          acc[mf][nf] = MFMA16(af[mf], bfr[nf], acc[mf][nf]);
      __builtin_amdgcn_s_setprio(0);
    }
    if (i0i < 7) {                       // slice boundary: Ad swap (cross-wave A visibility)
      asm volatile("s_waitcnt vmcnt(0)" ::: "memory");
      __syncthreads();
    }
  }
  // ---- ks-pair reduction: ks1 waves stash f32 acc in LDS (reuse Bp), ks0 sums+writes ----
  __syncthreads();
  float* scr = (float*)(&Bp[0][0][0]) + (wm * 2 + wn) * 4096;
  if (ksid == 1) {
#pragma unroll
    for (int mf = 0; mf < 4; ++mf)
#pragma unroll
      for (int nf = 0; nf < 4; ++nf) {
        const int col = nf * 16 + q15;
        *(f32x4*)&scr[col * 64 + ((mf * 16 + g * 4) ^ ((col & 7) << 3))] = acc[mf][nf];
      }
  }
  __syncthreads();
  if (ksid == 0) {
    u16* Pz = P + (size_t)z * NTOK * DD;
#pragma unroll
    for (int mf = 0; mf < 4; ++mf) {
      f32x4 sum[4];
#pragma unroll
      for (int nf = 0; nf < 4; ++nf) {
        const int col = nf * 16 + q15;
        const f32x4 o = *(const f32x4*)&scr[col * 64 + ((mf * 16 + g * 4) ^ ((col & 7) << 3))];
        sum[nf] = acc[mf][nf] + o;
      }
#pragma unroll
      for (int r = 0; r < 4; ++r) {
        const int srow = s0l + wm * 64 + mf * 16 + g * 4 + r;
        u16* orow = Pz + (size_t)(b * SS + srow) * DD + o0 + wn * 64;
#pragma unroll
        for (int nf = 0; nf < 4; ++nf)
          orow[nf * 16 + q15] = f2bf(sum[nf][r]);
      }
    }
  }
}

// ---------------- combine: x1 = gelu(P0+P1+cb) + x ----------------
__global__ void combine_kernel(const u16* __restrict__ P, const float* __restrict__ cb,
                               const float* __restrict__ x, float* __restrict__ x1) {
  const int idx = blockIdx.x * 256 + threadIdx.x;
  const size_t base = (size_t)idx * 4;
  const int col = (int)(base & (DD - 1));
  const u16x4 p0 = *(const u16x4*)(P + base);
  const u16x4 p1 = *(const u16x4*)(P + (size_t)NTOK * DD + base);
  const float4 xv = *(const float4*)(x + base);
  const float4 cbv = *(const float4*)(cb + col);
  float4 o;
  o.x = gelu_f(bf2f(p0[0]) + bf2f(p1[0]) + cbv.x) + xv.x;
  o.y = gelu_f(bf2f(p0[1]) + bf2f(p1[1]) + cbv.y) + xv.y;
  o.z = gelu_f(bf2f(p0[2]) + bf2f(p1[2]) + cbv.z) + xv.z;
  o.w = gelu_f(bf2f(p0[3]) + bf2f(p1[3]) + cbv.w) + xv.w;
  *(float4*)(x1 + base) = o;
}

// ---------------- qkv GEMM: ring-3, counted vmcnt, stage issued AFTER the barrier ----------------
// r10 race fix: stage(t+2) overwrites slot (t-1)%3; issuing it after barrier(t) guarantees all
// waves' step-(t-1) reads of that slot completed (lgkm-consumed before each wave reached the
// barrier). vmcnt(6) leaves only the newest stage in flight; never drains to 0 mid-loop.
__global__ __launch_bounds__(256) void qkv_kernel(const u16* __restrict__ A, const u16* __restrict__ B,
                           const float* __restrict__ bias, u16* __restrict__ C) {
  const int n0 = blockIdx.x * 64, m0 = blockIdx.y * 128;
  const int tid = threadIdx.x, lane = tid & 63, w = tid >> 6;
  const int wm = w >> 1, wn = w & 1;
  __shared__ u16 As[3][128 * 64];
  __shared__ u16 Bs[3][64 * 64];
  f32x4 acc[4][2];
#pragma unroll
  for (int i = 0; i < 4; ++i)
#pragma unroll
    for (int j = 0; j < 2; ++j) acc[i][j] = f32x4{0.f, 0.f, 0.f, 0.f};
  auto stage = [&](int t, int buf) {
    const int k0 = t * 64;
#pragma unroll
    for (int q = 0; q < 4; ++q) {
      const int idx = w * 4 + q, r = idx * 8 + (lane >> 3), c = (lane & 7) ^ (r & 7);
      GLOAD16(A + (size_t)(m0 + r) * DD + k0 + c * 8, &As[buf][idx * 512]);
    }
#pragma unroll
    for (int q = 0; q < 2; ++q) {
      const int idx = w * 2 + q, r = idx * 8 + (lane >> 3), c = (lane & 7) ^ (r & 7);
      GLOAD16(B + (size_t)(n0 + r) * DD + k0 + c * 8, &Bs[buf][idx * 512]);
    }
  };
  stage(0, 0);
  stage(1, 1);
  const int T = DD / 64;
  for (int t = 0; t < T; ++t) {
    if (t + 1 < T) asm volatile("s_waitcnt vmcnt(6)" ::: "memory");
    else           asm volatile("s_waitcnt vmcnt(0)" ::: "memory");
    __builtin_amdgcn_s_barrier();
    asm volatile("" ::: "memory");
    if (t + 2 < T) stage(t + 2, (t + 2) % 3);   // AFTER barrier: slot (t-1)%3 reads all done
    const u16* Ab = As[t % 3];
    const u16* Bb = Bs[t % 3];
    const int xb = (((lane >> 4) ^ (lane & 7)) * 16);
    s16x8 af[4][2], bfr[2][2];
#pragma unroll
    for (int mf = 0; mf < 4; ++mf) {
      const char* p = (const char*)Ab + (wm * 64 + mf * 16 + (lane & 15)) * 128;
      af[mf][0] = *(const s16x8*)(p + xb);
      af[mf][1] = *(const s16x8*)(p + (xb ^ 64));
    }
#pragma unroll
    for (int nf = 0; nf < 2; ++nf) {
      const char* p = (const char*)Bb + (wn * 32 + nf * 16 + (lane & 15)) * 128;
      bfr[nf][0] = *(const s16x8*)(p + xb);
      bfr[nf][1] = *(const s16x8*)(p + (xb ^ 64));
    }
    __builtin_amdgcn_s_setprio(1);
#pragma unroll
    for (int ks = 0; ks < 2; ++ks)
#pragma unroll
      for (int mf = 0; mf < 4; ++mf)
#pragma unroll
        for (int nf = 0; nf < 2; ++nf)
          acc[mf][nf] = MFMA16(af[mf][ks], bfr[nf][ks], acc[mf][nf]);
    __builtin_amdgcn_s_setprio(0);
  }
#pragma unroll
  for (int mf = 0; mf < 4; ++mf)
#pragma unroll
    for (int rr = 0; rr < 4; ++rr) {
      const int row = m0 + wm * 64 + mf * 16 + (lane >> 4) * 4 + rr;
#pragma unroll
      for (int nf = 0; nf < 2; ++nf) {
        const int col = n0 + wn * 32 + nf * 16 + (lane & 15);
        C[(size_t)row * D3 + col] = f2bf(acc[mf][nf][rr] + bias[col]);
      }
    }
}

// ---------------- out proj: ring-3 (race-fixed); f32 out + bf16 scatter to x2g ----------------
__global__ __launch_bounds__(256) void out_kernel(const u16* __restrict__ A, const u16* __restrict__ B,
                           const float* __restrict__ bias, const float* __restrict__ resid,
                           float* __restrict__ C, u16* __restrict__ x2g,
                           const int* __restrict__ inv) {
  const int n0 = blockIdx.x * 64, m0 = blockIdx.y * 128;
  const int tid = threadIdx.x, lane = tid & 63, w = tid >> 6;
  const int wm = w >> 1, wn = w & 1;
  __shared__ u16 As[3][128 * 64];
  __shared__ u16 Bs[3][64 * 64];
  f32x4 acc[4][2];
#pragma unroll
  for (int i = 0; i < 4; ++i)
#pragma unroll
    for (int j = 0; j < 2; ++j) acc[i][j] = f32x4{0.f, 0.f, 0.f, 0.f};
  auto stage = [&](int t, int buf) {
    const int k0 = t * 64;
#pragma unroll
    for (int q = 0; q < 4; ++q) {
      const int idx = w * 4 + q, r = idx * 8 + (lane >> 3), c = (lane & 7) ^ (r & 7);
      GLOAD16(A + (size_t)(m0 + r) * DD + k0 + c * 8, &As[buf][idx * 512]);
    }
#pragma unroll
    for (int q = 0; q < 2; ++q) {
      const int idx = w * 2 + q, r = idx * 8 + (lane >> 3), c = (lane & 7) ^ (r & 7);
      GLOAD16(B + (size_t)(n0 + r) * DD + k0 + c * 8, &Bs[buf][idx * 512]);
    }
  };
  stage(0, 0);
  stage(1, 1);
  const int T = DD / 64;
  for (int t = 0; t < T; ++t) {
    if (t + 1 < T) asm volatile("s_waitcnt vmcnt(6)" ::: "memory");
    else           asm volatile("s_waitcnt vmcnt(0)" ::: "memory");
    __builtin_amdgcn_s_barrier();
    asm volatile("" ::: "memory");
    if (t + 2 < T) stage(t + 2, (t + 2) % 3);
    const u16* Ab = As[t % 3];
    const u16* Bb = Bs[t % 3];
    const int xb = (((lane >> 4) ^ (lane & 7)) * 16);
    s16x8 af[4][2], bfr[2][2];
#pragma unroll
    for (int mf = 0; mf < 4; ++mf) {
      const char* p = (const char*)Ab + (wm * 64 + mf * 16 + (lane & 15)) * 128;
      af[mf][0] = *(const s16x8*)(p + xb);
      af[mf][1] = *(const s16x8*)(p + (xb ^ 64));
    }
#pragma unroll
    for (int nf = 0; nf < 2; ++nf) {
      const char* p = (const char*)Bb + (wn * 32 + nf * 16 + (lane & 15)) * 128;
      bfr[nf][0] = *(const s16x8*)(p + xb);
      bfr[nf][1] = *(const s16x8*)(p + (xb ^ 64));
    }
    __builtin_amdgcn_s_setprio(1);
#pragma unroll
    for (int ks = 0; ks < 2; ++ks)
#pragma unroll
      for (int mf = 0; mf < 4; ++mf)
#pragma unroll
        for (int nf = 0; nf < 2; ++nf)
          acc[mf][nf] = MFMA16(af[mf][ks], bfr[nf][ks], acc[mf][nf]);
    __builtin_amdgcn_s_setprio(0);
  }
#pragma unroll
  for (int mf = 0; mf < 4; ++mf)
#pragma unroll
    for (int rr = 0; rr < 4; ++rr) {
      const int row = m0 + wm * 64 + mf * 16 + (lane >> 4) * 4 + rr;
      const int slot = inv[row];
#pragma unroll
      for (int nf = 0; nf < 2; ++nf) {
        const int col = n0 + wn * 32 + nf * 16 + (lane & 15);
        const float v = acc[mf][nf][rr] + bias[col] + resid[(size_t)row * DD + col];
        C[(size_t)row * DD + col] = v;
        x2g[(size_t)slot * DD + col] = f2bf(v);
      }
    }
}

// ---------------- MFMA flash attention: 128 q x (b,h) per block, 8 waves x 16 q ----------------
__global__ __launch_bounds__(512) void attn_kernel(const u16* __restrict__ qkv,
                                                   const u16* __restrict__ Vt,
                                                   u16* __restrict__ ctx) {
  const int q0 = blockIdx.x * 128, h = blockIdx.y, b = blockIdx.z;
  const int tid = threadIdx.x, lane = tid & 63, w = tid >> 6;
  const int q15 = lane & 15, g = lane >> 4, l7 = lane & 7;
  __shared__ u16 Q_lds[128 * 64];
  __shared__ u16 K_lds[2][64 * 64];
  __shared__ u16 V_lds[2][64 * 64];
  __shared__ u16 P_lds[8][16 * 72];
  __shared__ float s_lds[8][16];

#pragma unroll
  for (int q2 = 0; q2 < 2; ++q2) {
    const int idx = w * 2 + q2;
    const int r = idx * 8 + (lane >> 3);
    const int c = l7 ^ (r & 7);
    GLOAD16(qkv + (size_t)(b * SS + q0 + r) * D3 + h * HDIM + c * 8, &Q_lds[idx * 512]);
  }
  auto stageK = [&](int buf, int kt) {
    const int r = w * 8 + (lane >> 3);
    const int c = l7 ^ (r & 7);
    GLOAD16(qkv + (size_t)(b * SS + kt * 64 + r) * D3 + DD + h * HDIM + c * 8,
            &K_lds[buf][w * 512]);
  };
  auto stageV = [&](int buf, int kt) {
    const int r = w * 8 + (lane >> 3);
    const int c = l7 ^ (r & 7);
    GLOAD16(Vt + ((size_t)(b * HH + h) * HDIM + r) * SS + kt * 64 + c * 8,
            &V_lds[buf][w * 512]);
  };
  stageK(0, 0);
  stageV(0, 0);
  asm volatile("s_waitcnt vmcnt(0)" ::: "memory");
  __syncthreads();
  s16x8 bq[2];
#pragma unroll
  for (int ks = 0; ks < 2; ++ks)
    bq[ks] = *(const s16x8*)((const char*)Q_lds + (w * 16 + q15) * 128 + ((4 * ks + g) ^ l7) * 16);
  f32x4 oacc[4];
#pragma unroll
  for (int nf = 0; nf < 4; ++nf) oacc[nf] = f32x4{0.f, 0.f, 0.f, 0.f};
  float mrun = -3.0e38f, lrun = 0.0f;
  int buf = 0;
  for (int kt = 0; kt < 16; ++kt) {
    if (kt < 15) { stageK(buf ^ 1, kt + 1); stageV(buf ^ 1, kt + 1); }
    f32x4 st[4];
#pragma unroll
    for (int mf = 0; mf < 4; ++mf) st[mf] = f32x4{0.f, 0.f, 0.f, 0.f};
#pragma unroll
    for (int ks = 0; ks < 2; ++ks) {
#pragma unroll
      for (int mf = 0; mf < 4; ++mf) {
        const s16x8 ka = *(const s16x8*)((const char*)K_lds[buf] + (mf * 16 + q15) * 128 +
                                         ((4 * ks + g) ^ l7) * 16);
        st[mf] = MFMA16(ka, bq[ks], st[mf]);
      }
    }
    float t0[4][4];
    float cmax = -3.0e38f;
#pragma unroll
    for (int mf = 0; mf < 4; ++mf)
#pragma unroll
      for (int r = 0; r < 4; ++r) {
        const float v = st[mf][r] * 0.125f;
        t0[mf][r] = v;
        cmax = fmaxf(cmax, v);
      }
    cmax = fmaxf(cmax, __shfl_xor(cmax, 16));
    cmax = fmaxf(cmax, __shfl_xor(cmax, 32));
    const float mnew = fmaxf(mrun, cmax);
    const float scf = __expf(mrun - mnew);
    float psum = 0.f;
#pragma unroll
    for (int mf = 0; mf < 4; ++mf)
#pragma unroll
      for (int r = 0; r < 4; ++r) {
        const float p = __expf(t0[mf][r] - mnew);
        t0[mf][r] = p;
        psum += p;
      }
    psum += __shfl_xor(psum, 16);
    psum += __shfl_xor(psum, 32);
    lrun = lrun * scf + psum;
    mrun = mnew;
    s_lds[w][q15] = scf;
    u16* pw = &P_lds[w][0];
#pragma unroll
    for (int mf = 0; mf < 4; ++mf) {
      u32x2 pk;
      pk[0] = (unsigned)f2bf(t0[mf][0]) | ((unsigned)f2bf(t0[mf][1]) << 16);
      pk[1] = (unsigned)f2bf(t0[mf][2]) | ((unsigned)f2bf(t0[mf][3]) << 16);
      *(u32x2*)(pw + q15 * 72 + mf * 16 + g * 4) = pk;
    }
    asm volatile("s_waitcnt lgkmcnt(0)" ::: "memory");
    const f32x4 scv = *(const f32x4*)&s_lds[w][g * 4];
#pragma unroll
    for (int nf = 0; nf < 4; ++nf)
#pragma unroll
      for (int r = 0; r < 4; ++r) oacc[nf][r] *= scv[r];
#pragma unroll
    for (int ks = 0; ks < 2; ++ks) {
      const s16x8 pa = *(const s16x8*)(pw + q15 * 72 + ks * 32 + g * 8);
#pragma unroll
      for (int nf = 0; nf < 4; ++nf) {
        const s16x8 bv = *(const s16x8*)((const char*)V_lds[buf] + (nf * 16 + q15) * 128 +
                                         ((4 * ks + g) ^ l7) * 16);
        oacc[nf] = MFMA16(pa, bv, oacc[nf]);
      }
    }
    asm volatile("s_waitcnt vmcnt(0)" ::: "memory");
    __syncthreads();
    buf ^= 1;
  }
  const float linv = 1.0f / lrun;
  s_lds[w][q15] = linv;
  asm volatile("s_waitcnt lgkmcnt(0)" ::: "memory");
  const f32x4 lv = *(const f32x4*)&s_lds[w][g * 4];
#pragma unroll
  for (int nf = 0; nf < 4; ++nf)
#pragma unroll
    for (int r = 0; r < 4; ++r) {
      const int qg = q0 + w * 16 + g * 4 + r;
      ctx[(size_t)(b * SS + qg) * DD + h * HDIM + nf * 16 + q15] = f2bf(oacc[nf][r] * lv[r]);
    }
}

// ---------------- MoE routing ----------------
__global__ void zero_counts_kernel(int* c) { if (threadIdx.x < GG) c[threadIdx.x] = 0; }

__global__ void gather_kernel(const int* __restrict__ gid, int* __restrict__ counts,
                              int* __restrict__ gather) {
  const int n = blockIdx.x * 256 + threadIdx.x;
  if (n < NTOK) {
    const int g = gid[n];
    const int slot = atomicAdd(&counts[g], 1);
    gather[g * NTOK + slot] = n;
  }
}

// off[g] = exclusive prefix sum of counts; off[GG] = NTOK
__global__ void scan_kernel(const int* __restrict__ cnts, int* __restrict__ off) {
  if (threadIdx.x == 0) {
    int s = 0;
#pragma unroll
    for (int g = 0; g < GG; ++g) { off[g] = s; s += cnts[g]; }
    off[GG] = s;
  }
}

// gidx[off[g]+slot] = tok ; inv[tok] = off[g]+slot
__global__ void pack_kernel(const int* __restrict__ gat, const int* __restrict__ cnts,
                            const int* __restrict__ off, int* __restrict__ gidx,
                            int* __restrict__ inv) {
  const int g = blockIdx.y;
  const int slot = blockIdx.x * 256 + threadIdx.x;
  if (slot < cnts[g]) {
    const int tok = gat[g * NTOK + slot];
    const int sg = off[g] + slot;
    gidx[sg] = tok;
    inv[tok] = sg;
  }
}

// ---------------- MoE GEMM1: ring-3 (race-fixed) ----------------
__global__ __launch_bounds__(256) void moe1_kernel(const u16* __restrict__ x2g, const u16* __restrict__ w1t,
                            const float* __restrict__ e_b1, const int* __restrict__ off,
                            const int* __restrict__ cnts, u16* __restrict__ h1) {
  const int ge = blockIdx.z, g = ge >> 1, e = ge & 1;
  const int cnt = cnts[g];
  const int m0 = blockIdx.y * 128;
  if (m0 >= cnt) return;
  const int base = off[g];
  const int n0 = blockIdx.x * 64;
  const u16* A = x2g + (size_t)base * DD;       // contiguous rows of this group
  const u16* B = w1t + (size_t)ge * HIDN * DD;  // [HID][D]
  const int tid = threadIdx.x, lane = tid & 63, w = tid >> 6;
  const int wm = w >> 1, wn = w & 1;
  __shared__ u16 As[3][128 * 64];
  __shared__ u16 Bs[3][64 * 64];
  f32x4 acc[4][2];
#pragma unroll
  for (int i = 0; i < 4; ++i)
#pragma unroll
    for (int j = 0; j < 2; ++j) acc[i][j] = f32x4{0.f, 0.f, 0.f, 0.f};
  auto stage = [&](int t, int buf) {
    const int k0 = t * 64;
#pragma unroll
    for (int q = 0; q < 4; ++q) {
      const int idx = w * 4 + q, r = idx * 8 + (lane >> 3), c = (lane & 7) ^ (r & 7);
      int rg = m0 + r; if (rg > cnt - 1) rg = cnt - 1;
      GLOAD16(A + (size_t)rg * DD + k0 + c * 8, &As[buf][idx * 512]);
    }
#pragma unroll
    for (int q = 0; q < 2; ++q) {
      const int idx = w * 2 + q, r = idx * 8 + (lane >> 3), c = (lane & 7) ^ (r & 7);
      GLOAD16(B + (size_t)(n0 + r) * DD + k0 + c * 8, &Bs[buf][idx * 512]);
    }
  };
  stage(0, 0);
  stage(1, 1);
  const int T = DD / 64;
  for (int t = 0; t < T; ++t) {
    if (t + 1 < T) asm volatile("s_waitcnt vmcnt(6)" ::: "memory");
    else           asm volatile("s_waitcnt vmcnt(0)" ::: "memory");
    __builtin_amdgcn_s_barrier();
    asm volatile("" ::: "memory");
    if (t + 2 < T) stage(t + 2, (t + 2) % 3);
    const u16* Ab = As[t % 3];
    const u16* Bb = Bs[t % 3];
    const int xb = (((lane >> 4) ^ (lane & 7)) * 16);
    s16x8 af[4][2], bfr[2][2];
#pragma unroll
    for (int mf = 0; mf < 4; ++mf) {
      const char* p = (const char*)Ab + (wm * 64 + mf * 16 + (lane & 15)) * 128;
      af[mf][0] = *(const s16x8*)(p + xb);
      af[mf][1] = *(const s16x8*)(p + (xb ^ 64));
    }
#pragma unroll
    for (int nf = 0; nf < 2; ++nf) {
      const char* p = (const char*)Bb + (wn * 32 + nf * 16 + (lane & 15)) * 128;
      bfr[nf][0] = *(const s16x8*)(p + xb);
      bfr[nf][1] = *(const s16x8*)(p + (xb ^ 64));
    }
    __builtin_amdgcn_s_setprio(1);
#pragma unroll
    for (int ks = 0; ks < 2; ++ks)
#pragma unroll
      for (int mf = 0; mf < 4; ++mf)
#pragma unroll
        for (int nf = 0; nf < 2; ++nf)
          acc[mf][nf] = MFMA16(af[mf][ks], bfr[nf][ks], acc[mf][nf]);
    __builtin_amdgcn_s_setprio(0);
  }
  const float* b1 = e_b1 + (size_t)ge * HIDN;
#pragma unroll
  for (int mf = 0; mf < 4; ++mf)
#pragma unroll
    for (int rr = 0; rr < 4; ++rr) {
      const int rowg = m0 + wm * 64 + mf * 16 + (lane >> 4) * 4 + rr;
      if (rowg < cnt) {
        u16* orow = h1 + ((size_t)e * NTOK + base + rowg) * HIDN;  // slot-ordered
#pragma unroll
        for (int nf = 0; nf < 2; ++nf) {
          const int col = n0 + wn * 32 + nf * 16 + (lane & 15);
          orow[col] = f2bf(gelu_f(acc[mf][nf][rr] + b1[col]));
        }
      }
    }
}

// ---------------- MoE GEMM2: ring-3 (race-fixed); scatter epilogue ----------------
__global__ __launch_bounds__(256) void moe2_kernel(const u16* __restrict__ h1, const u16* __restrict__ w2t,
                            const float* __restrict__ e_b2, const int* __restrict__ off,
                            const int* __restrict__ cnts, const int* __restrict__ gidx,
                            const float* __restrict__ x2, float* __restrict__ outp) {
  const int g = blockIdx.z;
  const int cnt = cnts[g];
  const int m0 = blockIdx.y * 128;
  if (m0 >= cnt) return;
  const int base = off[g];
  const int n0 = blockIdx.x * 64;
  const int tid = threadIdx.x, lane = tid & 63, w = tid >> 6;
  const int wm = w >> 1, wn = w & 1;
  __shared__ u16 As[3][128 * 64];
  __shared__ u16 Bs[3][64 * 64];
  f32x4 acc[4][2];
#pragma unroll
  for (int i = 0; i < 4; ++i)
#pragma unroll
    for (int j = 0; j < 2; ++j) acc[i][j] = f32x4{0.f, 0.f, 0.f, 0.f};
  auto stage = [&](int t, int buf) {
    const int e = t >> 5;
    const int k0 = (t & 31) * 64;
#pragma unroll
    for (int q = 0; q < 4; ++q) {
      const int idx = w * 4 + q, r = idx * 8 + (lane >> 3), c = (lane & 7) ^ (r & 7);
      int rg = m0 + r; if (rg > cnt - 1) rg = cnt - 1;
      GLOAD16(h1 + ((size_t)e * NTOK + base + rg) * HIDN + k0 + c * 8, &As[buf][idx * 512]);
    }
#pragma unroll
    for (int q = 0; q < 2; ++q) {
      const int idx = w * 2 + q, r = idx * 8 + (lane >> 3), c = (lane & 7) ^ (r & 7);
      GLOAD16(w2t + ((size_t)(g * EE + e) * DD + n0 + r) * HIDN + k0 + c * 8, &Bs[buf][idx * 512]);
    }
  };
  stage(0, 0);
  stage(1, 1);
  const int T = 64;
  for (int t = 0; t < T; ++t) {
    if (t + 1 < T) asm volatile("s_waitcnt vmcnt(6)" ::: "memory");
    else           asm volatile("s_waitcnt vmcnt(0)" ::: "memory");
    __builtin_amdgcn_s_barrier();
    asm volatile("" ::: "memory");
    if (t + 2 < T) stage(t + 2, (t + 2) % 3);
    const u16* Ab = As[t % 3];
    const u16* Bb = Bs[t % 3];
    const int xb = (((lane >> 4) ^ (lane & 7)) * 16);
    s16x8 af[4][2], bfr[2][2];
#pragma unroll
    for (int mf = 0; mf < 4; ++mf) {
      const char* p = (const char*)Ab + (wm * 64 + mf * 16 + (lane & 15)) * 128;
      af[mf][0] = *(const s16x8*)(p + xb);
      af[mf][1] = *(const s16x8*)(p + (xb ^ 64));
    }
#pragma unroll
    for (int nf = 0; nf < 2; ++nf) {
      const char* p = (const char*)Bb + (wn * 32 + nf * 16 + (lane & 15)) * 128;
      bfr[nf][0] = *(const s16x8*)(p + xb);
      bfr[nf][1] = *(const s16x8*)(p + (xb ^ 64));
    }
    __builtin_amdgcn_s_setprio(1);
#pragma unroll
    for (int ks = 0; ks < 2; ++ks)
#pragma unroll
      for (int mf = 0; mf < 4; ++mf)
#pragma unroll
        for (int nf = 0; nf < 2; ++nf)
          acc[mf][nf] = MFMA16(af[mf][ks], bfr[nf][ks], acc[mf][nf]);
    __builtin_amdgcn_s_setprio(0);
  }
  const float* b20 = e_b2 + (size_t)(g * EE + 0) * DD;
  const float* b21 = e_b2 + (size_t)(g * EE + 1) * DD;
#pragma unroll
  for (int mf = 0; mf < 4; ++mf)
#pragma unroll
    for (int rr = 0; rr < 4; ++rr) {
      const int rowg = m0 + wm * 64 + mf * 16 + (lane >> 4) * 4 + rr;
      if (rowg < cnt) {
        const int tok = gidx[base + rowg];
#pragma unroll
        for (int nf = 0; nf < 2; ++nf) {
          const int col = n0 + wn * 32 + nf * 16 + (lane & 15);
          outp[(size_t)tok * DD + col] =
              0.5f * acc[mf][nf][rr] + 0.5f * (b20[col] + b21[col]) + x2[(size_t)tok * DD + col];
        }
      }
    }
}

extern "C" void kernel_launch(void* const* d_in, const int* in_sizes, int n_in,
                              void* d_out, int out_size, void* d_ws, size_t ws_size,
                              hipStream_t stream) {
  (void)in_sizes; (void)n_in; (void)out_size; (void)ws_size;
  const float* x      = (const float*)d_in[0];
  const int*   gid    = (const int*)d_in[1];
  const float* cn_g   = (const float*)d_in[2];
  const float* cn_b   = (const float*)d_in[3];
  const float* conv_w = (const float*)d_in[4];
  const float* conv_b = (const float*)d_in[5];
  const float* an_g   = (const float*)d_in[6];
  const float* an_b   = (const float*)d_in[7];
  const float* in_w   = (const float*)d_in[8];
  const float* in_b   = (const float*)d_in[9];
  const float* out_w  = (const float*)d_in[10];
  const float* out_b  = (const float*)d_in[11];
  const float* e_w1   = (const float*)d_in[12];
  const float* e_b1   = (const float*)d_in[13];
  const float* e_w2   = (const float*)d_in[14];
  const float* e_b2   = (const float*)d_in[15];
  float* outp = (float*)d_out;

  // ---- workspace map (high-water 74MB + ~41KB, identical to r5-r9 pass) ----
  // conv phase: hb 0..4 | Pc 4..12 | Wb 12..74 (dead after conv_kernel)
  // post-conv:  x1 12..20 | qkvb 24..36 | inwb 40..46 | outwb 40..42 | Vt 46..50
  //             x2 52..60 | inv 60..60.008 (in dead-Wb hole) | x2g 64..68
  // MoE phase:  wgt 4..36 | h1 36..52 | tail at 74M: gat/cnts/offp/gidx
  // ROUTING RUNS AFTER CONV (r4 lesson: prep_convw clobbers anything inside Wb's span).
  char* wsp = (char*)d_ws;
  u16*   hb    = (u16*)(wsp);                         // 0..4M  (ln out; ctxb reuse)
  u16*   Pc    = (u16*)(wsp + (4ull << 20));          // 4..12M (conv partials x2, conv phase)
  float* x1    = (float*)(wsp + (12ull << 20));       // 12..20M (combine out)
  u16*   Wb    = (u16*)(wsp + (12ull << 20));         // 12..74M (conv phase only)
  u16*   qkvb  = (u16*)(wsp + (24ull << 20));         // 24..36M (qkv->attn)
  u16*   inwb  = (u16*)(wsp + (40ull << 20));         // 40..46M (qkv phase)
  u16*   outwb = (u16*)(wsp + (40ull << 20));         // 40..42M (out phase, after qkv)
  u16*   Vt    = (u16*)(wsp + (46ull << 20));         // 46..50M (attn phase)
  u16*   ctxb  = hb;                                  // 0..4M  (after qkv)
  float* x2    = (float*)(wsp + (52ull << 20));       // 52..60M
  int*   inv   = (int*)(wsp + (60ull << 20));         // 60M.. 8KB (tok->slot; written post-conv)
  u16*   x2g   = (u16*)(wsp + (64ull << 20));         // 64..68M (slot-packed tokens)
  u16*   wgt   = (u16*)(wsp + (4ull << 20));          // 4..36M (w1t, then w2t; MoE phase)
  u16*   h1    = (u16*)(wsp + (36ull << 20));         // 36..52M (MoE phase, slot-ordered)
  int*   gat   = (int*)(wsp + (74ull << 20));         // 32KB
  int*   cnts  = gat + GG * NTOK;                     // 16B
  int*   offp  = cnts + GG;                           // 20B
  int*   gidx  = offp + (GG + 1);                     // 8KB

  // ---- conv block (v7, measured 179us) ----
  ln_kernel<<<NTOK, 256, 0, stream>>>(x, cn_g, cn_b, hb);
  prep_convw<<<1024, 256, 0, stream>>>(conv_w, Wb);
  conv_kernel<<<256, 512, 0, stream>>>(hb, Wb, Pc);
  combine_kernel<<<NTOK * DD / 1024, 256, 0, stream>>>(Pc, conv_b, x, x1);
  // ---- routing (Wb now dead; inv lives in its hole; needed by out_kernel) ----
  zero_counts_kernel<<<1, 64, 0, stream>>>(cnts);
  gather_kernel<<<NTOK / 256, 256, 0, stream>>>(gid, cnts, gat);
  scan_kernel<<<1, 64, 0, stream>>>(cnts, offp);
  pack_kernel<<<dim3(NTOK / 256, GG), 256, 0, stream>>>(gat, cnts, offp, gidx, inv);
  // ---- attention block ----
  ln_kernel<<<NTOK, 256, 0, stream>>>(x1, an_g, an_b, hb);
  cvt_kernel<<<3072, 256, 0, stream>>>(in_w, inwb, 3 * DD * DD / 4);
  qkv_kernel<<<dim3(D3 / 64, NTOK / 128), 256, 0, stream>>>(hb, inwb, in_b, qkvb);
  vtr_kernel<<<dim3(SS / 32, HDIM / 32, BB * HH), 256, 0, stream>>>(qkvb, Vt);
  attn_kernel<<<dim3(SS / 128, HH, BB), 512, 0, stream>>>(qkvb, Vt, ctxb);
  cvt_kernel<<<1024, 256, 0, stream>>>(out_w, outwb, DD * DD / 4);
  out_kernel<<<dim3(DD / 64, NTOK / 128), 256, 0, stream>>>(ctxb, outwb, out_b, x1, x2, x2g, inv);
  // ---- MoE (slot-packed + dense-fastest grids: all 8 XCDs active) ----
  tr_kernel<<<dim3(HIDN / 32, DD / 32, GG * EE), 256, 0, stream>>>(e_w1, wgt, DD, HIDN);
  moe1_kernel<<<dim3(HIDN / 64, NTOK / 128, GG * EE), 256, 0, stream>>>(x2g, wgt, e_b1, offp, cnts, h1);
  tr_kernel<<<dim3(DD / 32, HIDN / 32, GG * EE), 256, 0, stream>>>(e_w2, wgt, HIDN, DD);
  moe2_kernel<<<dim3(DD / 64, NTOK / 128, GG), 256, 0, stream>>>(h1, wgt, e_b2, offp, cnts, gidx, x2, outp);
}

// Round 12
// 489.448 us; speedup vs baseline: 1.1422x; 1.0075x over previous
//
#include <hip/hip_runtime.h>
#include <hip/hip_bf16.h>
#include <math.h>

#define BB 2
#define SS 1024
#define DD 1024
#define HH 16
#define HDIM 64
#define KK 31
#define GG 4
#define EE 2
#define HIDN 2048
#define NTOK (BB*SS)
#define D3 (3*DD)

typedef unsigned short u16;
typedef __attribute__((ext_vector_type(8))) short s16x8;
typedef __attribute__((ext_vector_type(8))) unsigned short u16x8;
typedef __attribute__((ext_vector_type(4))) unsigned short u16x4;
typedef __attribute__((ext_vector_type(4))) float f32x4;
typedef __attribute__((ext_vector_type(2))) unsigned int u32x2;

__device__ __forceinline__ float gelu_f(float x) {
  return 0.5f * x * (1.0f + erff(x * 0.7071067811865475f));
}
__device__ __forceinline__ u16 f2bf(float f) {
  unsigned u = __builtin_bit_cast(unsigned, f);
  u = (u + 0x7fffu + ((u >> 16) & 1u)) >> 16;
  return (u16)u;
}
__device__ __forceinline__ float bf2f(u16 u) {
  return __builtin_bit_cast(float, ((unsigned)u) << 16);
}
__device__ __forceinline__ f32x4 MFMA16(s16x8 a, s16x8 b, f32x4 c) {
  return __builtin_amdgcn_mfma_f32_16x16x32_bf16(a, b, c, 0, 0, 0);
}
#define GLOAD16(gp, lp) __builtin_amdgcn_global_load_lds( \
    (const __attribute__((address_space(1))) void*)(gp),  \
    (__attribute__((address_space(3))) void*)(lp), 16, 0, 0)

// ---------------- LayerNorm: fp32 in -> bf16 out, one block per row ----------------
__global__ void ln_kernel(const float* __restrict__ x, const float* __restrict__ g,
                          const float* __restrict__ b, u16* __restrict__ out) {
  const int row = blockIdx.x;
  const int tid = threadIdx.x;
  __shared__ float red[4];
  const float4 v = reinterpret_cast<const float4*>(x + (size_t)row * DD)[tid];
  float s = v.x + v.y + v.z + v.w;
  s += __shfl_down(s, 32); s += __shfl_down(s, 16); s += __shfl_down(s, 8);
  s += __shfl_down(s, 4);  s += __shfl_down(s, 2);  s += __shfl_down(s, 1);
  if ((tid & 63) == 0) red[tid >> 6] = s;
  __syncthreads();
  const float mean = (red[0] + red[1] + red[2] + red[3]) * (1.0f / DD);
  __syncthreads();
  const float4 d = make_float4(v.x - mean, v.y - mean, v.z - mean, v.w - mean);
  float sq = d.x*d.x + d.y*d.y + d.z*d.z + d.w*d.w;
  sq += __shfl_down(sq, 32); sq += __shfl_down(sq, 16); sq += __shfl_down(sq, 8);
  sq += __shfl_down(sq, 4);  sq += __shfl_down(sq, 2);  sq += __shfl_down(sq, 1);
  if ((tid & 63) == 0) red[tid >> 6] = sq;
  __syncthreads();
  const float var = (red[0] + red[1] + red[2] + red[3]) * (1.0f / DD);
  const float rstd = rsqrtf(var + 1e-5f);
  const float4 gv = reinterpret_cast<const float4*>(g)[tid];
  const float4 bv = reinterpret_cast<const float4*>(b)[tid];
  u16x4 o;
  o[0] = f2bf(d.x * rstd * gv.x + bv.x);
  o[1] = f2bf(d.y * rstd * gv.y + bv.y);
  o[2] = f2bf(d.z * rstd * gv.z + bv.z);
  o[3] = f2bf(d.w * rstd * gv.w + bv.w);
  *reinterpret_cast<u16x4*>(out + (size_t)row * DD + tid * 4) = o;
}

// ---------------- conv weight reorder: conv_w[o][i][k] f32 -> Wb[k][o][i] bf16 ----------------
// v2: 4 consecutive i per thread -> u16x4 vector stores (31 x 8B vs 124 x 2B scalar).
__global__ void prep_convw(const float* __restrict__ cw, u16* __restrict__ Wb) {
  const int o = blockIdx.x;
  const int i4 = threadIdx.x * 4;
  float wv[4][KK];
#pragma unroll
  for (int j = 0; j < 4; ++j) {
    const float* src = cw + ((size_t)o * DD + i4 + j) * KK;
#pragma unroll
    for (int k = 0; k < KK; ++k) wv[j][k] = src[k];
  }
#pragma unroll
  for (int k = 0; k < KK; ++k) {
    u16x4 o4;
    o4[0] = f2bf(wv[0][k]); o4[1] = f2bf(wv[1][k]);
    o4[2] = f2bf(wv[2][k]); o4[3] = f2bf(wv[3][k]);
    *(u16x4*)&Wb[((size_t)k * DD + o) * DD + i4] = o4;
  }
}

// ---------------- plain f32 -> bf16 convert ----------------
__global__ void cvt_kernel(const float* __restrict__ in, u16* __restrict__ outp, int n4) {
  const int i = blockIdx.x * 256 + threadIdx.x;
  if (i < n4) {
    const float4 v = reinterpret_cast<const float4*>(in)[i];
    u16x4 o; o[0] = f2bf(v.x); o[1] = f2bf(v.y); o[2] = f2bf(v.z); o[3] = f2bf(v.w);
    reinterpret_cast<u16x4*>(outp)[i] = o;
  }
}

// ---------------- transpose-convert: src[z][R][C] f32 -> dst[z][C][R] bf16 ----------------
__global__ void tr_kernel(const float* __restrict__ src, u16* __restrict__ dst, int R, int C) {
  __shared__ float tile[32][33];
  const int c0 = blockIdx.x * 32, r0 = blockIdx.y * 32;
  const size_t base = (size_t)blockIdx.z * R * C;
  const int tx = threadIdx.x & 31, ty = threadIdx.x >> 5;  // ty 0..7
#pragma unroll
  for (int i = 0; i < 4; ++i)
    tile[ty + i * 8][tx] = src[base + (size_t)(r0 + ty + i * 8) * C + c0 + tx];
  __syncthreads();
#pragma unroll
  for (int i = 0; i < 4; ++i)
    dst[base + (size_t)(c0 + ty + i * 8) * R + r0 + tx] = f2bf(tile[tx][ty + i * 8]);
}

// ---------------- V transpose: qkvb V-part -> Vt[b][h][d][k] bf16 ----------------
__global__ void vtr_kernel(const u16* __restrict__ qkvb, u16* __restrict__ Vt) {
  __shared__ u16 tile[32][40];
  const int k0 = blockIdx.x * 32, d0 = blockIdx.y * 32, bh = blockIdx.z;
  const int b = bh >> 4, h = bh & 15;
  const int tx = threadIdx.x & 31, ty = threadIdx.x >> 5;  // ty 0..7
#pragma unroll
  for (int i = 0; i < 4; ++i)
    tile[ty + i * 8][tx] =
        qkvb[(size_t)(b * SS + k0 + ty + i * 8) * D3 + 2 * DD + h * HDIM + d0 + tx];
  __syncthreads();
#pragma unroll
  for (int i = 0; i < 4; ++i)
    Vt[((size_t)(b * HH + h) * HDIM + d0 + ty + i * 8) * SS + k0 + tx] = tile[tx][ty + i * 8];
}

// ---------------- conv via MFMA v7 (measured 179us): barrier-free taps, private B ring-3 ----------------
__global__ __launch_bounds__(512) void conv_kernel(const u16* __restrict__ hb,
                                                   const u16* __restrict__ Wb,
                                                   u16* __restrict__ P) {
  const int L = blockIdx.x;            // 0..255
  const int o_t = L & 7;               // o-tile pinned per XCD (B L2 reuse)
  const int rest = L >> 3;
  const int s_t = rest >> 1;           // 0..15
  const int z = rest & 1;              // i-half
  const int b = s_t >> 3, sloc = s_t & 7;
  const int s0l = sloc * 128;
  const int o0 = o_t * 128;
  const int ibase = z * 512;
  const int tid = threadIdx.x, lane = tid & 63, w = tid >> 6;
  const int wm = (w >> 2) & 1, wn = (w >> 1) & 1, ksid = w & 1;
  const int q15 = lane & 15, g = lane >> 4;
  __shared__ __align__(16) u16 Ad[2][160 * 64];   // 40 KB, dbuf over i-slices
  __shared__ __align__(16) u16 Bp[8][3][2048];    // 96 KB, wave-private ring-3 (4KB slots)
  const int rlo = (sloc == 0) ? 15 : 0;
  const int rhi = (sloc == 7) ? 143 : 158;
  if (sloc == 0)
    for (int i = tid; i < 15 * 64; i += 512) { Ad[0][i] = 0; Ad[1][i] = 0; }
  if (sloc == 7)
    for (int i = tid; i < 17 * 64; i += 512) { Ad[0][143 * 64 + i] = 0; Ad[1][143 * 64 + i] = 0; }
  auto stageA = [&](int buf, int i0) {
    for (int q = w; q < 20; q += 8) {
      const int r = q * 8 + (lane >> 3);
      const int c = (lane & 7) ^ (r & 7);
      if (r >= rlo && r < rhi)
        GLOAD16(hb + (size_t)(b * SS + s0l - 15 + r) * DD + i0 + c * 8, &Ad[buf][q * 512]);
    }
  };
  auto stageBp = [&](int slot, int k, int i0w) {
#pragma unroll
    for (int q = 0; q < 4; ++q) {
      const int j = lane >> 2;                      // o-subrow 0..15
      const int r = q * 16 + j;                     // o-row local 0..63
      const int c16 = (lane & 3) ^ ((j >> 1) & 3);  // chunk 0..3, quad-permuted
      GLOAD16(Wb + ((size_t)k * DD + o0 + wn * 64 + r) * DD + i0w + c16 * 8,
              &Bp[w][slot][q * 512]);
    }
  };
  f32x4 acc[4][4];
#pragma unroll
  for (int i = 0; i < 4; ++i)
#pragma unroll
    for (int j = 0; j < 4; ++j) acc[i][j] = f32x4{0.f, 0.f, 0.f, 0.f};
  const int ib0 = ibase + ksid * 32;
  stageA(0, ibase);
  stageBp(0, 0, ib0);
  stageBp(1, 1, ib0);
  asm volatile("s_waitcnt vmcnt(0)" ::: "memory");
  __syncthreads();
  const int T = 8 * KK;  // 248 taps
  const int kx = ksid * 64;  // byte XOR selecting this wave's K=32 half in Ad rows
  const int bro = q15 * 64 + ((g ^ ((q15 >> 1) & 3)) << 4);  // per-lane B frag offset
  int t = 0;
  for (int i0i = 0; i0i < 8; ++i0i) {
    const u16* Ab = Ad[i0i & 1];
    for (int k = 0; k < KK; ++k, ++t) {
      {  // prefetch own B(t+2) into private ring
        const int tn = t + 2;
        if (tn < T) stageBp(tn % 3, tn % KK, ibase + (tn / KK) * 64 + ksid * 32);
      }
      // A frags from shared Ad (slice-stable)
      s16x8 af[4];
      const int rk0 = wm * 64 + q15 + k;
#pragma unroll
      for (int mf = 0; mf < 4; ++mf) {
        const int rr = rk0 + mf * 16;
        const char* p = (const char*)Ab + rr * 128;
        af[mf] = *(const s16x8*)(p + (((g ^ (rr & 7)) * 16) ^ kx));
      }
      // own B(t) landed when <= 2 taps' worth of own loads outstanding
      if (t + 2 < T)      asm volatile("s_waitcnt vmcnt(8)" ::: "memory");
      else if (t + 1 < T) asm volatile("s_waitcnt vmcnt(4)" ::: "memory");
      else                asm volatile("s_waitcnt vmcnt(0)" ::: "memory");
      // A prefetch AFTER the counted wait (issue-only; consumed after slice barrier)
      if (k == 5 && i0i < 7) stageA((i0i + 1) & 1, ibase + (i0i + 1) * 64);
      const char* Bb = (const char*)&Bp[w][t % 3][0];
      s16x8 bfr[4];
#pragma unroll
      for (int nf = 0; nf < 4; ++nf)
        bfr[nf] = *(const s16x8*)(Bb + nf * 1024 + bro);   // bank-quad bijective, 0-conflict
      __builtin_amdgcn_s_setprio(1);
#pragma unroll
      for (int mf = 0; mf < 4; ++mf)
#pragma unroll
        for (int nf = 0; nf < 4; ++nf)
          acc[mf][nf] = MFMA16(af[mf], bfr[nf], acc[mf][nf]);
      __builtin_amdgcn_s_setprio(0);
    }
    if (i0i < 7) {                       // slice boundary: Ad swap (cross-wave A visibility)
      asm volatile("s_waitcnt vmcnt(0)" ::: "memory");
      __syncthreads();
    }
  }
  // ---- ks-pair reduction: ks1 waves stash f32 acc in LDS (reuse Bp), ks0 sums+writes ----
  __syncthreads();
  float* scr = (float*)(&Bp[0][0][0]) + (wm * 2 + wn) * 4096;
  if (ksid == 1) {
#pragma unroll
    for (int mf = 0; mf < 4; ++mf)
#pragma unroll
      for (int nf = 0; nf < 4; ++nf) {
        const int col = nf * 16 + q15;
        *(f32x4*)&scr[col * 64 + ((mf * 16 + g * 4) ^ ((col & 7) << 3))] = acc[mf][nf];
      }
  }
  __syncthreads();
  if (ksid == 0) {
    u16* Pz = P + (size_t)z * NTOK * DD;
#pragma unroll
    for (int mf = 0; mf < 4; ++mf) {
      f32x4 sum[4];
#pragma unroll
      for (int nf = 0; nf < 4; ++nf) {
        const int col = nf * 16 + q15;
        const f32x4 o = *(const f32x4*)&scr[col * 64 + ((mf * 16 + g * 4) ^ ((col & 7) << 3))];
        sum[nf] = acc[mf][nf] + o;
      }
#pragma unroll
      for (int r = 0; r < 4; ++r) {
        const int srow = s0l + wm * 64 + mf * 16 + g * 4 + r;
        u16* orow = Pz + (size_t)(b * SS + srow) * DD + o0 + wn * 64;
#pragma unroll
        for (int nf = 0; nf < 4; ++nf)
          orow[nf * 16 + q15] = f2bf(sum[nf][r]);
      }
    }
  }
}

// ---------------- combine: x1 = gelu(P0+P1+cb) + x ----------------
__global__ void combine_kernel(const u16* __restrict__ P, const float* __restrict__ cb,
                               const float* __restrict__ x, float* __restrict__ x1) {
  const int idx = blockIdx.x * 256 + threadIdx.x;
  const size_t base = (size_t)idx * 4;
  const int col = (int)(base & (DD - 1));
  const u16x4 p0 = *(const u16x4*)(P + base);
  const u16x4 p1 = *(const u16x4*)(P + (size_t)NTOK * DD + base);
  const float4 xv = *(const float4*)(x + base);
  const float4 cbv = *(const float4*)(cb + col);
  float4 o;
  o.x = gelu_f(bf2f(p0[0]) + bf2f(p1[0]) + cbv.x) + xv.x;
  o.y = gelu_f(bf2f(p0[1]) + bf2f(p1[1]) + cbv.y) + xv.y;
  o.z = gelu_f(bf2f(p0[2]) + bf2f(p1[2]) + cbv.z) + xv.z;
  o.w = gelu_f(bf2f(p0[3]) + bf2f(p1[3]) + cbv.w) + xv.w;
  *(float4*)(x1 + base) = o;
}

// ---------------- qkv GEMM v2: 128x128 tile (m97 structure), dbuf-2, stage after barrier ----------------
// Guide tile ladder at this structure: 64^2=343 TF, 128^2=912 TF. LDS 64KB -> 2 blocks/CU.
__global__ __launch_bounds__(256) void qkv_kernel(const u16* __restrict__ A, const u16* __restrict__ B,
                           const float* __restrict__ bias, u16* __restrict__ C) {
  const int n0 = blockIdx.x * 128, m0 = blockIdx.y * 128;
  const int tid = threadIdx.x, lane = tid & 63, w = tid >> 6;
  const int wm = w >> 1, wn = w & 1;
  __shared__ u16 As[2][128 * 64];
  __shared__ u16 Bs[2][128 * 64];
  f32x4 acc[4][4];
#pragma unroll
  for (int i = 0; i < 4; ++i)
#pragma unroll
    for (int j = 0; j < 4; ++j) acc[i][j] = f32x4{0.f, 0.f, 0.f, 0.f};
  auto stage = [&](int t, int buf) {
    const int k0 = t * 64;
#pragma unroll
    for (int q = 0; q < 4; ++q) {
      const int idx = w * 4 + q, r = idx * 8 + (lane >> 3), c = (lane & 7) ^ (r & 7);
      GLOAD16(A + (size_t)(m0 + r) * DD + k0 + c * 8, &As[buf][idx * 512]);
    }
#pragma unroll
    for (int q = 0; q < 4; ++q) {
      const int idx = w * 4 + q, r = idx * 8 + (lane >> 3), c = (lane & 7) ^ (r & 7);
      GLOAD16(B + (size_t)(n0 + r) * DD + k0 + c * 8, &Bs[buf][idx * 512]);
    }
  };
  stage(0, 0);
  asm volatile("s_waitcnt vmcnt(0)" ::: "memory");
  __syncthreads();
  const int T = DD / 64;
  for (int t = 0; t < T; ++t) {
    if (t > 0) {
      asm volatile("s_waitcnt vmcnt(0)" ::: "memory");
      __builtin_amdgcn_s_barrier();
      asm volatile("" ::: "memory");
    }
    if (t + 1 < T) stage(t + 1, (t + 1) & 1);  // after barrier: prev readers of this slot done
    const u16* Ab = As[t & 1];
    const u16* Bb = Bs[t & 1];
    const int xb = (((lane >> 4) ^ (lane & 7)) * 16);
    s16x8 af[4][2], bfr[4][2];
#pragma unroll
    for (int mf = 0; mf < 4; ++mf) {
      const char* p = (const char*)Ab + (wm * 64 + mf * 16 + (lane & 15)) * 128;
      af[mf][0] = *(const s16x8*)(p + xb);
      af[mf][1] = *(const s16x8*)(p + (xb ^ 64));
    }
#pragma unroll
    for (int nf = 0; nf < 4; ++nf) {
      const char* p = (const char*)Bb + (wn * 64 + nf * 16 + (lane & 15)) * 128;
      bfr[nf][0] = *(const s16x8*)(p + xb);
      bfr[nf][1] = *(const s16x8*)(p + (xb ^ 64));
    }
    __builtin_amdgcn_s_setprio(1);
#pragma unroll
    for (int ks = 0; ks < 2; ++ks)
#pragma unroll
      for (int mf = 0; mf < 4; ++mf)
#pragma unroll
        for (int nf = 0; nf < 4; ++nf)
          acc[mf][nf] = MFMA16(af[mf][ks], bfr[nf][ks], acc[mf][nf]);
    __builtin_amdgcn_s_setprio(0);
  }
#pragma unroll
  for (int mf = 0; mf < 4; ++mf)
#pragma unroll
    for (int rr = 0; rr < 4; ++rr) {
      const int row = m0 + wm * 64 + mf * 16 + (lane >> 4) * 4 + rr;
#pragma unroll
      for (int nf = 0; nf < 4; ++nf) {
        const int col = n0 + wn * 64 + nf * 16 + (lane & 15);
        C[(size_t)row * D3 + col] = f2bf(acc[mf][nf][rr] + bias[col]);
      }
    }
}

// ---------------- out proj: ring-3 (r11, passed); f32 out + bf16 scatter to x2g ----------------
__global__ __launch_bounds__(256) void out_kernel(const u16* __restrict__ A, const u16* __restrict__ B,
                           const float* __restrict__ bias, const float* __restrict__ resid,
                           float* __restrict__ C, u16* __restrict__ x2g,
                           const int* __restrict__ inv) {
  const int n0 = blockIdx.x * 64, m0 = blockIdx.y * 128;
  const int tid = threadIdx.x, lane = tid & 63, w = tid >> 6;
  const int wm = w >> 1, wn = w & 1;
  __shared__ u16 As[3][128 * 64];
  __shared__ u16 Bs[3][64 * 64];
  f32x4 acc[4][2];
#pragma unroll
  for (int i = 0; i < 4; ++i)
#pragma unroll
    for (int j = 0; j < 2; ++j) acc[i][j] = f32x4{0.f, 0.f, 0.f, 0.f};
  auto stage = [&](int t, int buf) {
    const int k0 = t * 64;
#pragma unroll
    for (int q = 0; q < 4; ++q) {
      const int idx = w * 4 + q, r = idx * 8 + (lane >> 3), c = (lane & 7) ^ (r & 7);
      GLOAD16(A + (size_t)(m0 + r) * DD + k0 + c * 8, &As[buf][idx * 512]);
    }
#pragma unroll
    for (int q = 0; q < 2; ++q) {
      const int idx = w * 2 + q, r = idx * 8 + (lane >> 3), c = (lane & 7) ^ (r & 7);
      GLOAD16(B + (size_t)(n0 + r) * DD + k0 + c * 8, &Bs[buf][idx * 512]);
    }
  };
  stage(0, 0);
  stage(1, 1);
  const int T = DD / 64;
  for (int t = 0; t < T; ++t) {
    if (t + 1 < T) asm volatile("s_waitcnt vmcnt(6)" ::: "memory");
    else           asm volatile("s_waitcnt vmcnt(0)" ::: "memory");
    __builtin_amdgcn_s_barrier();
    asm volatile("" ::: "memory");
    if (t + 2 < T) stage(t + 2, (t + 2) % 3);
    const u16* Ab = As[t % 3];
    const u16* Bb = Bs[t % 3];
    const int xb = (((lane >> 4) ^ (lane & 7)) * 16);
    s16x8 af[4][2], bfr[2][2];
#pragma unroll
    for (int mf = 0; mf < 4; ++mf) {
      const char* p = (const char*)Ab + (wm * 64 + mf * 16 + (lane & 15)) * 128;
      af[mf][0] = *(const s16x8*)(p + xb);
      af[mf][1] = *(const s16x8*)(p + (xb ^ 64));
    }
#pragma unroll
    for (int nf = 0; nf < 2; ++nf) {
      const char* p = (const char*)Bb + (wn * 32 + nf * 16 + (lane & 15)) * 128;
      bfr[nf][0] = *(const s16x8*)(p + xb);
      bfr[nf][1] = *(const s16x8*)(p + (xb ^ 64));
    }
    __builtin_amdgcn_s_setprio(1);
#pragma unroll
    for (int ks = 0; ks < 2; ++ks)
#pragma unroll
      for (int mf = 0; mf < 4; ++mf)
#pragma unroll
        for (int nf = 0; nf < 2; ++nf)
          acc[mf][nf] = MFMA16(af[mf][ks], bfr[nf][ks], acc[mf][nf]);
    __builtin_amdgcn_s_setprio(0);
  }
#pragma unroll
  for (int mf = 0; mf < 4; ++mf)
#pragma unroll
    for (int rr = 0; rr < 4; ++rr) {
      const int row = m0 + wm * 64 + mf * 16 + (lane >> 4) * 4 + rr;
      const int slot = inv[row];
#pragma unroll
      for (int nf = 0; nf < 2; ++nf) {
        const int col = n0 + wn * 32 + nf * 16 + (lane & 15);
        const float v = acc[mf][nf][rr] + bias[col] + resid[(size_t)row * DD + col];
        C[(size_t)row * DD + col] = v;
        x2g[(size_t)slot * DD + col] = f2bf(v);
      }
    }
}

// ---------------- MFMA flash attention: 128 q x (b,h) per block, 8 waves x 16 q ----------------
__global__ __launch_bounds__(512) void attn_kernel(const u16* __restrict__ qkv,
                                                   const u16* __restrict__ Vt,
                                                   u16* __restrict__ ctx) {
  const int q0 = blockIdx.x * 128, h = blockIdx.y, b = blockIdx.z;
  const int tid = threadIdx.x, lane = tid & 63, w = tid >> 6;
  const int q15 = lane & 15, g = lane >> 4, l7 = lane & 7;
  __shared__ u16 Q_lds[128 * 64];
  __shared__ u16 K_lds[2][64 * 64];
  __shared__ u16 V_lds[2][64 * 64];
  __shared__ u16 P_lds[8][16 * 72];
  __shared__ float s_lds[8][16];

#pragma unroll
  for (int q2 = 0; q2 < 2; ++q2) {
    const int idx = w * 2 + q2;
    const int r = idx * 8 + (lane >> 3);
    const int c = l7 ^ (r & 7);
    GLOAD16(qkv + (size_t)(b * SS + q0 + r) * D3 + h * HDIM + c * 8, &Q_lds[idx * 512]);
  }
  auto stageK = [&](int buf, int kt) {
    const int r = w * 8 + (lane >> 3);
    const int c = l7 ^ (r & 7);
    GLOAD16(qkv + (size_t)(b * SS + kt * 64 + r) * D3 + DD + h * HDIM + c * 8,
            &K_lds[buf][w * 512]);
  };
  auto stageV = [&](int buf, int kt) {
    const int r = w * 8 + (lane >> 3);
    const int c = l7 ^ (r & 7);
    GLOAD16(Vt + ((size_t)(b * HH + h) * HDIM + r) * SS + kt * 64 + c * 8,
            &V_lds[buf][w * 512]);
  };
  stageK(0, 0);
  stageV(0, 0);
  asm volatile("s_waitcnt vmcnt(0)" ::: "memory");
  __syncthreads();
  s16x8 bq[2];
#pragma unroll
  for (int ks = 0; ks < 2; ++ks)
    bq[ks] = *(const s16x8*)((const char*)Q_lds + (w * 16 + q15) * 128 + ((4 * ks + g) ^ l7) * 16);
  f32x4 oacc[4];
#pragma unroll
  for (int nf = 0; nf < 4; ++nf) oacc[nf] = f32x4{0.f, 0.f, 0.f, 0.f};
  float mrun = -3.0e38f, lrun = 0.0f;
  int buf = 0;
  for (int kt = 0; kt < 16; ++kt) {
    if (kt < 15) { stageK(buf ^ 1, kt + 1); stageV(buf ^ 1, kt + 1); }
    f32x4 st[4];
#pragma unroll
    for (int mf = 0; mf < 4; ++mf) st[mf] = f32x4{0.f, 0.f, 0.f, 0.f};
#pragma unroll
    for (int ks = 0; ks < 2; ++ks) {
#pragma unroll
      for (int mf = 0; mf < 4; ++mf) {
        const s16x8 ka = *(const s16x8*)((const char*)K_lds[buf] + (mf * 16 + q15) * 128 +
                                         ((4 * ks + g) ^ l7) * 16);
        st[mf] = MFMA16(ka, bq[ks], st[mf]);
      }
    }
    float t0[4][4];
    float cmax = -3.0e38f;
#pragma unroll
    for (int mf = 0; mf < 4; ++mf)
#pragma unroll
      for (int r = 0; r < 4; ++r) {
        const float v = st[mf][r] * 0.125f;
        t0[mf][r] = v;
        cmax = fmaxf(cmax, v);
      }
    cmax = fmaxf(cmax, __shfl_xor(cmax, 16));
    cmax = fmaxf(cmax, __shfl_xor(cmax, 32));
    const float mnew = fmaxf(mrun, cmax);
    const float scf = __expf(mrun - mnew);
    float psum = 0.f;
#pragma unroll
    for (int mf = 0; mf < 4; ++mf)
#pragma unroll
      for (int r = 0; r < 4; ++r) {
        const float p = __expf(t0[mf][r] - mnew);
        t0[mf][r] = p;
        psum += p;
      }
    psum += __shfl_xor(psum, 16);
    psum += __shfl_xor(psum, 32);
    lrun = lrun * scf + psum;
    mrun = mnew;
    s_lds[w][q15] = scf;
    u16* pw = &P_lds[w][0];
#pragma unroll
    for (int mf = 0; mf < 4; ++mf) {
      u32x2 pk;
      pk[0] = (unsigned)f2bf(t0[mf][0]) | ((unsigned)f2bf(t0[mf][1]) << 16);
      pk[1] = (unsigned)f2bf(t0[mf][2]) | ((unsigned)f2bf(t0[mf][3]) << 16);
      *(u32x2*)(pw + q15 * 72 + mf * 16 + g * 4) = pk;
    }
    asm volatile("s_waitcnt lgkmcnt(0)" ::: "memory");
    const f32x4 scv = *(const f32x4*)&s_lds[w][g * 4];
#pragma unroll
    for (int nf = 0; nf < 4; ++nf)
#pragma unroll
      for (int r = 0; r < 4; ++r) oacc[nf][r] *= scv[r];
#pragma unroll
    for (int ks = 0; ks < 2; ++ks) {
      const s16x8 pa = *(const s16x8*)(pw + q15 * 72 + ks * 32 + g * 8);
#pragma unroll
      for (int nf = 0; nf < 4; ++nf) {
        const s16x8 bv = *(const s16x8*)((const char*)V_lds[buf] + (nf * 16 + q15) * 128 +
                                         ((4 * ks + g) ^ l7) * 16);
        oacc[nf] = MFMA16(pa, bv, oacc[nf]);
      }
    }
    asm volatile("s_waitcnt vmcnt(0)" ::: "memory");
    __syncthreads();
    buf ^= 1;
  }
  const float linv = 1.0f / lrun;
  s_lds[w][q15] = linv;
  asm volatile("s_waitcnt lgkmcnt(0)" ::: "memory");
  const f32x4 lv = *(const f32x4*)&s_lds[w][g * 4];
#pragma unroll
  for (int nf = 0; nf < 4; ++nf)
#pragma unroll
    for (int r = 0; r < 4; ++r) {
      const int qg = q0 + w * 16 + g * 4 + r;
      ctx[(size_t)(b * SS + qg) * DD + h * HDIM + nf * 16 + q15] = f2bf(oacc[nf][r] * lv[r]);
    }
}

// ---------------- MoE routing ----------------
__global__ void zero_counts_kernel(int* c) { if (threadIdx.x < GG) c[threadIdx.x] = 0; }

__global__ void gather_kernel(const int* __restrict__ gid, int* __restrict__ counts,
                              int* __restrict__ gather) {
  const int n = blockIdx.x * 256 + threadIdx.x;
  if (n < NTOK) {
    const int g = gid[n];
    const int slot = atomicAdd(&counts[g], 1);
    gather[g * NTOK + slot] = n;
  }
}

// off[g] = exclusive prefix sum of counts; off[GG] = NTOK
__global__ void scan_kernel(const int* __restrict__ cnts, int* __restrict__ off) {
  if (threadIdx.x == 0) {
    int s = 0;
#pragma unroll
    for (int g = 0; g < GG; ++g) { off[g] = s; s += cnts[g]; }
    off[GG] = s;
  }
}

// gidx[off[g]+slot] = tok ; inv[tok] = off[g]+slot
__global__ void pack_kernel(const int* __restrict__ gat, const int* __restrict__ cnts,
                            const int* __restrict__ off, int* __restrict__ gidx,
                            int* __restrict__ inv) {
  const int g = blockIdx.y;
  const int slot = blockIdx.x * 256 + threadIdx.x;
  if (slot < cnts[g]) {
    const int tok = gat[g * NTOK + slot];
    const int sg = off[g] + slot;
    gidx[sg] = tok;
    inv[tok] = sg;
  }
}

// ---------------- MoE GEMM1 v2: 128x128 tile (m97 structure), dbuf-2 ----------------
// grid x = n-tile (dense -> all XCDs), y = m-tile (sparse early-exit).
__global__ __launch_bounds__(256) void moe1_kernel(const u16* __restrict__ x2g, const u16* __restrict__ w1t,
                            const float* __restrict__ e_b1, const int* __restrict__ off,
                            const int* __restrict__ cnts, u16* __restrict__ h1) {
  const int ge = blockIdx.z, g = ge >> 1, e = ge & 1;
  const int cnt = cnts[g];
  const int m0 = blockIdx.y * 128;
  if (m0 >= cnt) return;
  const int base = off[g];
  const int n0 = blockIdx.x * 128;
  const u16* A = x2g + (size_t)base * DD;       // contiguous rows of this group
  const u16* B = w1t + (size_t)ge * HIDN * DD;  // [HID][D]
  const int tid = threadIdx.x, lane = tid & 63, w = tid >> 6;
  const int wm = w >> 1, wn = w & 1;
  __shared__ u16 As[2][128 * 64];
  __shared__ u16 Bs[2][128 * 64];
  f32x4 acc[4][4];
#pragma unroll
  for (int i = 0; i < 4; ++i)
#pragma unroll
    for (int j = 0; j < 4; ++j) acc[i][j] = f32x4{0.f, 0.f, 0.f, 0.f};
  auto stage = [&](int t, int buf) {
    const int k0 = t * 64;
#pragma unroll
    for (int q = 0; q < 4; ++q) {
      const int idx = w * 4 + q, r = idx * 8 + (lane >> 3), c = (lane & 7) ^ (r & 7);
      int rg = m0 + r; if (rg > cnt - 1) rg = cnt - 1;
      GLOAD16(A + (size_t)rg * DD + k0 + c * 8, &As[buf][idx * 512]);
    }
#pragma unroll
    for (int q = 0; q < 4; ++q) {
      const int idx = w * 4 + q, r = idx * 8 + (lane >> 3), c = (lane & 7) ^ (r & 7);
      GLOAD16(B + (size_t)(n0 + r) * DD + k0 + c * 8, &Bs[buf][idx * 512]);
    }
  };
  stage(0, 0);
  asm volatile("s_waitcnt vmcnt(0)" ::: "memory");
  __syncthreads();
  const int T = DD / 64;
  for (int t = 0; t < T; ++t) {
    if (t > 0) {
      asm volatile("s_waitcnt vmcnt(0)" ::: "memory");
      __builtin_amdgcn_s_barrier();
      asm volatile("" ::: "memory");
    }
    if (t + 1 < T) stage(t + 1, (t + 1) & 1);
    const u16* Ab = As[t & 1];
    const u16* Bb = Bs[t & 1];
    const int xb = (((lane >> 4) ^ (lane & 7)) * 16);
    s16x8 af[4][2], bfr[4][2];
#pragma unroll
    for (int mf = 0; mf < 4; ++mf) {
      const char* p = (const char*)Ab + (wm * 64 + mf * 16 + (lane & 15)) * 128;
      af[mf][0] = *(const s16x8*)(p + xb);
      af[mf][1] = *(const s16x8*)(p + (xb ^ 64));
    }
#pragma unroll
    for (int nf = 0; nf < 4; ++nf) {
      const char* p = (const char*)Bb + (wn * 64 + nf * 16 + (lane & 15)) * 128;
      bfr[nf][0] = *(const s16x8*)(p + xb);
      bfr[nf][1] = *(const s16x8*)(p + (xb ^ 64));
    }
    __builtin_amdgcn_s_setprio(1);
#pragma unroll
    for (int ks = 0; ks < 2; ++ks)
#pragma unroll
      for (int mf = 0; mf < 4; ++mf)
#pragma unroll
        for (int nf = 0; nf < 4; ++nf)
          acc[mf][nf] = MFMA16(af[mf][ks], bfr[nf][ks], acc[mf][nf]);
    __builtin_amdgcn_s_setprio(0);
  }
  const float* b1 = e_b1 + (size_t)ge * HIDN;
#pragma unroll
  for (int mf = 0; mf < 4; ++mf)
#pragma unroll
    for (int rr = 0; rr < 4; ++rr) {
      const int rowg = m0 + wm * 64 + mf * 16 + (lane >> 4) * 4 + rr;
      if (rowg < cnt) {
        u16* orow = h1 + ((size_t)e * NTOK + base + rowg) * HIDN;  // slot-ordered
#pragma unroll
        for (int nf = 0; nf < 4; ++nf) {
          const int col = n0 + wn * 64 + nf * 16 + (lane & 15);
          orow[col] = f2bf(gelu_f(acc[mf][nf][rr] + b1[col]));
        }
      }
    }
}

// ---------------- MoE GEMM2: ring-3 (r11, passed); scatter epilogue ----------------
__global__ __launch_bounds__(256) void moe2_kernel(const u16* __restrict__ h1, const u16* __restrict__ w2t,
                            const float* __restrict__ e_b2, const int* __restrict__ off,
                            const int* __restrict__ cnts, const int* __restrict__ gidx,
                            const float* __restrict__ x2, float* __restrict__ outp) {
  const int g = blockIdx.z;
  const int cnt = cnts[g];
  const int m0 = blockIdx.y * 128;
  if (m0 >= cnt) return;
  const int base = off[g];
  const int n0 = blockIdx.x * 64;
  const int tid = threadIdx.x, lane = tid & 63, w = tid >> 6;
  const int wm = w >> 1, wn = w & 1;
  __shared__ u16 As[3][128 * 64];
  __shared__ u16 Bs[3][64 * 64];
  f32x4 acc[4][2];
#pragma unroll
  for (int i = 0; i < 4; ++i)
#pragma unroll
    for (int j = 0; j < 2; ++j) acc[i][j] = f32x4{0.f, 0.f, 0.f, 0.f};
  auto stage = [&](int t, int buf) {
    const int e = t >> 5;
    const int k0 = (t & 31) * 64;
#pragma unroll
    for (int q = 0; q < 4; ++q) {
      const int idx = w * 4 + q, r = idx * 8 + (lane >> 3), c = (lane & 7) ^ (r & 7);
      int rg = m0 + r; if (rg > cnt - 1) rg = cnt - 1;
      GLOAD16(h1 + ((size_t)e * NTOK + base + rg) * HIDN + k0 + c * 8, &As[buf][idx * 512]);
    }
#pragma unroll
    for (int q = 0; q < 2; ++q) {
      const int idx = w * 2 + q, r = idx * 8 + (lane >> 3), c = (lane & 7) ^ (r & 7);
      GLOAD16(w2t + ((size_t)(g * EE + e) * DD + n0 + r) * HIDN + k0 + c * 8, &Bs[buf][idx * 512]);
    }
  };
  stage(0, 0);
  stage(1, 1);
  const int T = 64;
  for (int t = 0; t < T; ++t) {
    if (t + 1 < T) asm volatile("s_waitcnt vmcnt(6)" ::: "memory");
    else           asm volatile("s_waitcnt vmcnt(0)" ::: "memory");
    __builtin_amdgcn_s_barrier();
    asm volatile("" ::: "memory");
    if (t + 2 < T) stage(t + 2, (t + 2) % 3);
    const u16* Ab = As[t % 3];
    const u16* Bb = Bs[t % 3];
    const int xb = (((lane >> 4) ^ (lane & 7)) * 16);
    s16x8 af[4][2], bfr[2][2];
#pragma unroll
    for (int mf = 0; mf < 4; ++mf) {
      const char* p = (const char*)Ab + (wm * 64 + mf * 16 + (lane & 15)) * 128;
      af[mf][0] = *(const s16x8*)(p + xb);
      af[mf][1] = *(const s16x8*)(p + (xb ^ 64));
    }
#pragma unroll
    for (int nf = 0; nf < 2; ++nf) {
      const char* p = (const char*)Bb + (wn * 32 + nf * 16 + (lane & 15)) * 128;
      bfr[nf][0] = *(const s16x8*)(p + xb);
      bfr[nf][1] = *(const s16x8*)(p + (xb ^ 64));
    }
    __builtin_amdgcn_s_setprio(1);
#pragma unroll
    for (int ks = 0; ks < 2; ++ks)
#pragma unroll
      for (int mf = 0; mf < 4; ++mf)
#pragma unroll
        for (int nf = 0; nf < 2; ++nf)
          acc[mf][nf] = MFMA16(af[mf][ks], bfr[nf][ks], acc[mf][nf]);
    __builtin_amdgcn_s_setprio(0);
  }
  const float* b20 = e_b2 + (size_t)(g * EE + 0) * DD;
  const float* b21 = e_b2 + (size_t)(g * EE + 1) * DD;
#pragma unroll
  for (int mf = 0; mf < 4; ++mf)
#pragma unroll
    for (int rr = 0; rr < 4; ++rr) {
      const int rowg = m0 + wm * 64 + mf * 16 + (lane >> 4) * 4 + rr;
      if (rowg < cnt) {
        const int tok = gidx[base + rowg];
#pragma unroll
        for (int nf = 0; nf < 2; ++nf) {
          const int col = n0 + wn * 32 + nf * 16 + (lane & 15);
          outp[(size_t)tok * DD + col] =
              0.5f * acc[mf][nf][rr] + 0.5f * (b20[col] + b21[col]) + x2[(size_t)tok * DD + col];
        }
      }
    }
}

extern "C" void kernel_launch(void* const* d_in, const int* in_sizes, int n_in,
                              void* d_out, int out_size, void* d_ws, size_t ws_size,
                              hipStream_t stream) {
  (void)in_sizes; (void)n_in; (void)out_size; (void)ws_size;
  const float* x      = (const float*)d_in[0];
  const int*   gid    = (const int*)d_in[1];
  const float* cn_g   = (const float*)d_in[2];
  const float* cn_b   = (const float*)d_in[3];
  const float* conv_w = (const float*)d_in[4];
  const float* conv_b = (const float*)d_in[5];
  const float* an_g   = (const float*)d_in[6];
  const float* an_b   = (const float*)d_in[7];
  const float* in_w   = (const float*)d_in[8];
  const float* in_b   = (const float*)d_in[9];
  const float* out_w  = (const float*)d_in[10];
  const float* out_b  = (const float*)d_in[11];
  const float* e_w1   = (const float*)d_in[12];
  const float* e_b1   = (const float*)d_in[13];
  const float* e_w2   = (const float*)d_in[14];
  const float* e_b2   = (const float*)d_in[15];
  float* outp = (float*)d_out;

  // ---- workspace map (high-water 74MB + ~41KB, identical to r5-r11 pass) ----
  char* wsp = (char*)d_ws;
  u16*   hb    = (u16*)(wsp);                         // 0..4M  (ln out; ctxb reuse)
  u16*   Pc    = (u16*)(wsp + (4ull << 20));          // 4..12M (conv partials x2, conv phase)
  float* x1    = (float*)(wsp + (12ull << 20));       // 12..20M (combine out)
  u16*   Wb    = (u16*)(wsp + (12ull << 20));         // 12..74M (conv phase only)
  u16*   qkvb  = (u16*)(wsp + (24ull << 20));         // 24..36M (qkv->attn)
  u16*   inwb  = (u16*)(wsp + (40ull << 20));         // 40..46M (qkv phase)
  u16*   outwb = (u16*)(wsp + (40ull << 20));         // 40..42M (out phase, after qkv)
  u16*   Vt    = (u16*)(wsp + (46ull << 20));         // 46..50M (attn phase)
  u16*   ctxb  = hb;                                  // 0..4M  (after qkv)
  float* x2    = (float*)(wsp + (52ull << 20));       // 52..60M
  int*   inv   = (int*)(wsp + (60ull << 20));         // 60M.. 8KB (tok->slot; written post-conv)
  u16*   x2g   = (u16*)(wsp + (64ull << 20));         // 64..68M (slot-packed tokens)
  u16*   wgt   = (u16*)(wsp + (4ull << 20));          // 4..36M (w1t, then w2t; MoE phase)
  u16*   h1    = (u16*)(wsp + (36ull << 20));         // 36..52M (MoE phase, slot-ordered)
  int*   gat   = (int*)(wsp + (74ull << 20));         // 32KB
  int*   cnts  = gat + GG * NTOK;                     // 16B
  int*   offp  = cnts + GG;                           // 20B
  int*   gidx  = offp + (GG + 1);                     // 8KB

  // ---- conv block (v7, measured 179us) ----
  ln_kernel<<<NTOK, 256, 0, stream>>>(x, cn_g, cn_b, hb);
  prep_convw<<<1024, 256, 0, stream>>>(conv_w, Wb);
  conv_kernel<<<256, 512, 0, stream>>>(hb, Wb, Pc);
  combine_kernel<<<NTOK * DD / 1024, 256, 0, stream>>>(Pc, conv_b, x, x1);
  // ---- routing (Wb now dead; inv lives in its hole; needed by out_kernel) ----
  zero_counts_kernel<<<1, 64, 0, stream>>>(cnts);
  gather_kernel<<<NTOK / 256, 256, 0, stream>>>(gid, cnts, gat);
  scan_kernel<<<1, 64, 0, stream>>>(cnts, offp);
  pack_kernel<<<dim3(NTOK / 256, GG), 256, 0, stream>>>(gat, cnts, offp, gidx, inv);
  // ---- attention block ----
  ln_kernel<<<NTOK, 256, 0, stream>>>(x1, an_g, an_b, hb);
  cvt_kernel<<<3072, 256, 0, stream>>>(in_w, inwb, 3 * DD * DD / 4);
  qkv_kernel<<<dim3(D3 / 128, NTOK / 128), 256, 0, stream>>>(hb, inwb, in_b, qkvb);
  vtr_kernel<<<dim3(SS / 32, HDIM / 32, BB * HH), 256, 0, stream>>>(qkvb, Vt);
  attn_kernel<<<dim3(SS / 128, HH, BB), 512, 0, stream>>>(qkvb, Vt, ctxb);
  cvt_kernel<<<1024, 256, 0, stream>>>(out_w, outwb, DD * DD / 4);
  out_kernel<<<dim3(DD / 64, NTOK / 128), 256, 0, stream>>>(ctxb, outwb, out_b, x1, x2, x2g, inv);
  // ---- MoE (slot-packed + dense-fastest grids: all 8 XCDs active) ----
  tr_kernel<<<dim3(HIDN / 32, DD / 32, GG * EE), 256, 0, stream>>>(e_w1, wgt, DD, HIDN);
  moe1_kernel<<<dim3(HIDN / 128, NTOK / 128, GG * EE), 256, 0, stream>>>(x2g, wgt, e_b1, offp, cnts, h1);
  tr_kernel<<<dim3(DD / 32, HIDN / 32, GG * EE), 256, 0, stream>>>(e_w2, wgt, HIDN, DD);
  moe2_kernel<<<dim3(DD / 64, NTOK / 128, GG), 256, 0, stream>>>(h1, wgt, e_b2, offp, cnts, gidx, x2, outp);
}

// Round 13
// 472.014 us; speedup vs baseline: 1.1844x; 1.0369x over previous
//
#include <hip/hip_runtime.h>
#include <hip/hip_bf16.h>
#include <math.h>

#define BB 2
#define SS 1024
#define DD 1024
#define HH 16
#define HDIM 64
#define KK 31
#define GG 4
#define EE 2
#define HIDN 2048
#define NTOK (BB*SS)
#define D3 (3*DD)

typedef unsigned short u16;
typedef __attribute__((ext_vector_type(8))) short s16x8;
typedef __attribute__((ext_vector_type(8))) unsigned short u16x8;
typedef __attribute__((ext_vector_type(4))) unsigned short u16x4;
typedef __attribute__((ext_vector_type(2))) unsigned short u16x2;
typedef __attribute__((ext_vector_type(4))) float f32x4;
typedef __attribute__((ext_vector_type(2))) unsigned int u32x2;

__device__ __forceinline__ float gelu_f(float x) {
  return 0.5f * x * (1.0f + erff(x * 0.7071067811865475f));
}
__device__ __forceinline__ u16 f2bf(float f) {
  unsigned u = __builtin_bit_cast(unsigned, f);
  u = (u + 0x7fffu + ((u >> 16) & 1u)) >> 16;
  return (u16)u;
}
__device__ __forceinline__ float bf2f(u16 u) {
  return __builtin_bit_cast(float, ((unsigned)u) << 16);
}
__device__ __forceinline__ f32x4 MFMA16(s16x8 a, s16x8 b, f32x4 c) {
  return __builtin_amdgcn_mfma_f32_16x16x32_bf16(a, b, c, 0, 0, 0);
}
#define GLOAD16(gp, lp) __builtin_amdgcn_global_load_lds( \
    (const __attribute__((address_space(1))) void*)(gp),  \
    (__attribute__((address_space(3))) void*)(lp), 16, 0, 0)

// ---------------- LayerNorm: fp32 in -> bf16 out, one block per row ----------------
__global__ void ln_kernel(const float* __restrict__ x, const float* __restrict__ g,
                          const float* __restrict__ b, u16* __restrict__ out) {
  const int row = blockIdx.x;
  const int tid = threadIdx.x;
  __shared__ float red[4];
  const float4 v = reinterpret_cast<const float4*>(x + (size_t)row * DD)[tid];
  float s = v.x + v.y + v.z + v.w;
  s += __shfl_down(s, 32); s += __shfl_down(s, 16); s += __shfl_down(s, 8);
  s += __shfl_down(s, 4);  s += __shfl_down(s, 2);  s += __shfl_down(s, 1);
  if ((tid & 63) == 0) red[tid >> 6] = s;
  __syncthreads();
  const float mean = (red[0] + red[1] + red[2] + red[3]) * (1.0f / DD);
  __syncthreads();
  const float4 d = make_float4(v.x - mean, v.y - mean, v.z - mean, v.w - mean);
  float sq = d.x*d.x + d.y*d.y + d.z*d.z + d.w*d.w;
  sq += __shfl_down(sq, 32); sq += __shfl_down(sq, 16); sq += __shfl_down(sq, 8);
  sq += __shfl_down(sq, 4);  sq += __shfl_down(sq, 2);  sq += __shfl_down(sq, 1);
  if ((tid & 63) == 0) red[tid >> 6] = sq;
  __syncthreads();
  const float var = (red[0] + red[1] + red[2] + red[3]) * (1.0f / DD);
  const float rstd = rsqrtf(var + 1e-5f);
  const float4 gv = reinterpret_cast<const float4*>(g)[tid];
  const float4 bv = reinterpret_cast<const float4*>(b)[tid];
  u16x4 o;
  o[0] = f2bf(d.x * rstd * gv.x + bv.x);
  o[1] = f2bf(d.y * rstd * gv.y + bv.y);
  o[2] = f2bf(d.z * rstd * gv.z + bv.z);
  o[3] = f2bf(d.w * rstd * gv.w + bv.w);
  *reinterpret_cast<u16x4*>(out + (size_t)row * DD + tid * 4) = o;
}

// ---------------- conv weight reorder: conv_w[o][i][k] f32 -> Wb[k][o][i] bf16 ----------------
// 4 consecutive i per thread -> u16x4 vector stores.
__global__ void prep_convw(const float* __restrict__ cw, u16* __restrict__ Wb) {
  const int o = blockIdx.x;
  const int i4 = threadIdx.x * 4;
  float wv[4][KK];
#pragma unroll
  for (int j = 0; j < 4; ++j) {
    const float* src = cw + ((size_t)o * DD + i4 + j) * KK;
#pragma unroll
    for (int k = 0; k < KK; ++k) wv[j][k] = src[k];
  }
#pragma unroll
  for (int k = 0; k < KK; ++k) {
    u16x4 o4;
    o4[0] = f2bf(wv[0][k]); o4[1] = f2bf(wv[1][k]);
    o4[2] = f2bf(wv[2][k]); o4[3] = f2bf(wv[3][k]);
    *(u16x4*)&Wb[((size_t)k * DD + o) * DD + i4] = o4;
  }
}

// ---------------- plain f32 -> bf16 convert ----------------
__global__ void cvt_kernel(const float* __restrict__ in, u16* __restrict__ outp, int n4) {
  const int i = blockIdx.x * 256 + threadIdx.x;
  if (i < n4) {
    const float4 v = reinterpret_cast<const float4*>(in)[i];
    u16x4 o; o[0] = f2bf(v.x); o[1] = f2bf(v.y); o[2] = f2bf(v.z); o[3] = f2bf(v.w);
    reinterpret_cast<u16x4*>(outp)[i] = o;
  }
}

// ---------------- transpose-convert v2: src[z][R][C] f32 -> dst[z][C][R] bf16, paired stores ----------------
__global__ void tr_kernel(const float* __restrict__ src, u16* __restrict__ dst, int R, int C) {
  __shared__ float tile[32][33];   // [r-local][c-local]
  const int c0 = blockIdx.x * 32, r0 = blockIdx.y * 32;
  const size_t base = (size_t)blockIdx.z * R * C;
  const int tx = threadIdx.x & 31, ty = threadIdx.x >> 5;  // ty 0..7
#pragma unroll
  for (int i = 0; i < 4; ++i)
    tile[ty + i * 8][tx] = src[base + (size_t)(r0 + ty + i * 8) * C + c0 + tx];
  __syncthreads();
  // store phase: rx = r-pair (0..15), cy covers c in two halves; u16x2 stores (4B, even r0 -> aligned)
  const int rx = threadIdx.x & 15, cy = threadIdx.x >> 4;  // cy 0..15
#pragma unroll
  for (int i = 0; i < 2; ++i) {
    const int c = cy + i * 16;
    u16x2 o2;
    o2[0] = f2bf(tile[2 * rx][c]);
    o2[1] = f2bf(tile[2 * rx + 1][c]);
    *(u16x2*)&dst[base + (size_t)(c0 + c) * R + r0 + 2 * rx] = o2;
  }
}

// ---------------- V transpose: qkvb V-part -> Vt[b][h][d][k] bf16 ----------------
__global__ void vtr_kernel(const u16* __restrict__ qkvb, u16* __restrict__ Vt) {
  __shared__ u16 tile[32][40];
  const int k0 = blockIdx.x * 32, d0 = blockIdx.y * 32, bh = blockIdx.z;
  const int b = bh >> 4, h = bh & 15;
  const int tx = threadIdx.x & 31, ty = threadIdx.x >> 5;  // ty 0..7
#pragma unroll
  for (int i = 0; i < 4; ++i)
    tile[ty + i * 8][tx] =
        qkvb[(size_t)(b * SS + k0 + ty + i * 8) * D3 + 2 * DD + h * HDIM + d0 + tx];
  __syncthreads();
#pragma unroll
  for (int i = 0; i < 4; ++i)
    Vt[((size_t)(b * HH + h) * HDIM + d0 + ty + i * 8) * SS + k0 + tx] = tile[tx][ty + i * 8];
}

// ---------------- conv via MFMA v7 (measured 179us): barrier-free taps, private B ring-3 ----------------
__global__ __launch_bounds__(512) void conv_kernel(const u16* __restrict__ hb,
                                                   const u16* __restrict__ Wb,
                                                   u16* __restrict__ P) {
  const int L = blockIdx.x;            // 0..255
  const int o_t = L & 7;               // o-tile pinned per XCD (B L2 reuse)
  const int rest = L >> 3;
  const int s_t = rest >> 1;           // 0..15
  const int z = rest & 1;              // i-half
  const int b = s_t >> 3, sloc = s_t & 7;
  const int s0l = sloc * 128;
  const int o0 = o_t * 128;
  const int ibase = z * 512;
  const int tid = threadIdx.x, lane = tid & 63, w = tid >> 6;
  const int wm = (w >> 2) & 1, wn = (w >> 1) & 1, ksid = w & 1;
  const int q15 = lane & 15, g = lane >> 4;
  __shared__ __align__(16) u16 Ad[2][160 * 64];   // 40 KB, dbuf over i-slices
  __shared__ __align__(16) u16 Bp[8][3][2048];    // 96 KB, wave-private ring-3 (4KB slots)
  const int rlo = (sloc == 0) ? 15 : 0;
  const int rhi = (sloc == 7) ? 143 : 158;
  if (sloc == 0)
    for (int i = tid; i < 15 * 64; i += 512) { Ad[0][i] = 0; Ad[1][i] = 0; }
  if (sloc == 7)
    for (int i = tid; i < 17 * 64; i += 512) { Ad[0][143 * 64 + i] = 0; Ad[1][143 * 64 + i] = 0; }
  auto stageA = [&](int buf, int i0) {
    for (int q = w; q < 20; q += 8) {
      const int r = q * 8 + (lane >> 3);
      const int c = (lane & 7) ^ (r & 7);
      if (r >= rlo && r < rhi)
        GLOAD16(hb + (size_t)(b * SS + s0l - 15 + r) * DD + i0 + c * 8, &Ad[buf][q * 512]);
    }
  };
  auto stageBp = [&](int slot, int k, int i0w) {
#pragma unroll
    for (int q = 0; q < 4; ++q) {
      const int j = lane >> 2;                      // o-subrow 0..15
      const int r = q * 16 + j;                     // o-row local 0..63
      const int c16 = (lane & 3) ^ ((j >> 1) & 3);  // chunk 0..3, quad-permuted
      GLOAD16(Wb + ((size_t)k * DD + o0 + wn * 64 + r) * DD + i0w + c16 * 8,
              &Bp[w][slot][q * 512]);
    }
  };
  f32x4 acc[4][4];
#pragma unroll
  for (int i = 0; i < 4; ++i)
#pragma unroll
    for (int j = 0; j < 4; ++j) acc[i][j] = f32x4{0.f, 0.f, 0.f, 0.f};
  const int ib0 = ibase + ksid * 32;
  stageA(0, ibase);
  stageBp(0, 0, ib0);
  stageBp(1, 1, ib0);
  asm volatile("s_waitcnt vmcnt(0)" ::: "memory");
  __syncthreads();
  const int T = 8 * KK;  // 248 taps
  const int kx = ksid * 64;  // byte XOR selecting this wave's K=32 half in Ad rows
  const int bro = q15 * 64 + ((g ^ ((q15 >> 1) & 3)) << 4);  // per-lane B frag offset
  int t = 0;
  for (int i0i = 0; i0i < 8; ++i0i) {
    const u16* Ab = Ad[i0i & 1];
    for (int k = 0; k < KK; ++k, ++t) {
      {  // prefetch own B(t+2) into private ring
        const int tn = t + 2;
        if (tn < T) stageBp(tn % 3, tn % KK, ibase + (tn / KK) * 64 + ksid * 32);
      }
      // A frags from shared Ad (slice-stable)
      s16x8 af[4];
      const int rk0 = wm * 64 + q15 + k;
#pragma unroll
      for (int mf = 0; mf < 4; ++mf) {
        const int rr = rk0 + mf * 16;
        const char* p = (const char*)Ab + rr * 128;
        af[mf] = *(const s16x8*)(p + (((g ^ (rr & 7)) * 16) ^ kx));
      }
      // own B(t) landed when <= 2 taps' worth of own loads outstanding
      if (t + 2 < T)      asm volatile("s_waitcnt vmcnt(8)" ::: "memory");
      else if (t + 1 < T) asm volatile("s_waitcnt vmcnt(4)" ::: "memory");
      else                asm volatile("s_waitcnt vmcnt(0)" ::: "memory");
      // A prefetch AFTER the counted wait (issue-only; consumed after slice barrier)
      if (k == 5 && i0i < 7) stageA((i0i + 1) & 1, ibase + (i0i + 1) * 64);
      const char* Bb = (const char*)&Bp[w][t % 3][0];
      s16x8 bfr[4];
#pragma unroll
      for (int nf = 0; nf < 4; ++nf)
        bfr[nf] = *(const s16x8*)(Bb + nf * 1024 + bro);   // bank-quad bijective, 0-conflict
      __builtin_amdgcn_s_setprio(1);
#pragma unroll
      for (int mf = 0; mf < 4; ++mf)
#pragma unroll
        for (int nf = 0; nf < 4; ++nf)
          acc[mf][nf] = MFMA16(af[mf], bfr[nf], acc[mf][nf]);
      __builtin_amdgcn_s_setprio(0);
    }
    if (i0i < 7) {                       // slice boundary: Ad swap (cross-wave A visibility)
      asm volatile("s_waitcnt vmcnt(0)" ::: "memory");
      __syncthreads();
    }
  }
  // ---- ks-pair reduction: ks1 waves stash f32 acc in LDS (reuse Bp), ks0 sums+writes ----
  __syncthreads();
  float* scr = (float*)(&Bp[0][0][0]) + (wm * 2 + wn) * 4096;
  if (ksid == 1) {
#pragma unroll
    for (int mf = 0; mf < 4; ++mf)
#pragma unroll
      for (int nf = 0; nf < 4; ++nf) {
        const int col = nf * 16 + q15;
        *(f32x4*)&scr[col * 64 + ((mf * 16 + g * 4) ^ ((col & 7) << 3))] = acc[mf][nf];
      }
  }
  __syncthreads();
  if (ksid == 0) {
    u16* Pz = P + (size_t)z * NTOK * DD;
#pragma unroll
    for (int mf = 0; mf < 4; ++mf) {
      f32x4 sum[4];
#pragma unroll
      for (int nf = 0; nf < 4; ++nf) {
        const int col = nf * 16 + q15;
        const f32x4 o = *(const f32x4*)&scr[col * 64 + ((mf * 16 + g * 4) ^ ((col & 7) << 3))];
        sum[nf] = acc[mf][nf] + o;
      }
#pragma unroll
      for (int r = 0; r < 4; ++r) {
        const int srow = s0l + wm * 64 + mf * 16 + g * 4 + r;
        u16* orow = Pz + (size_t)(b * SS + srow) * DD + o0 + wn * 64;
#pragma unroll
        for (int nf = 0; nf < 4; ++nf)
          orow[nf * 16 + q15] = f2bf(sum[nf][r]);
      }
    }
  }
}

// ---------------- combine+LN fused: x1 = gelu(P0+P1+cb)+x ; hb = LN(x1)*an_g+an_b ----------------
// One block per token row (256 thr x 4 elems = DD). LN math identical to ln_kernel.
__global__ void combine_kernel(const u16* __restrict__ P, const float* __restrict__ cb,
                               const float* __restrict__ x, const float* __restrict__ an_g,
                               const float* __restrict__ an_b, float* __restrict__ x1,
                               u16* __restrict__ hb) {
  const int row = blockIdx.x;
  const int tid = threadIdx.x;
  const size_t base = (size_t)row * DD + tid * 4;
  const int col = tid * 4;
  __shared__ float red[4];
  const u16x4 p0 = *(const u16x4*)(P + base);
  const u16x4 p1 = *(const u16x4*)(P + (size_t)NTOK * DD + base);
  const float4 xv = *(const float4*)(x + base);
  const float4 cbv = *(const float4*)(cb + col);
  float4 v;
  v.x = gelu_f(bf2f(p0[0]) + bf2f(p1[0]) + cbv.x) + xv.x;
  v.y = gelu_f(bf2f(p0[1]) + bf2f(p1[1]) + cbv.y) + xv.y;
  v.z = gelu_f(bf2f(p0[2]) + bf2f(p1[2]) + cbv.z) + xv.z;
  v.w = gelu_f(bf2f(p0[3]) + bf2f(p1[3]) + cbv.w) + xv.w;
  *(float4*)(x1 + base) = v;
  float s = v.x + v.y + v.z + v.w;
  s += __shfl_down(s, 32); s += __shfl_down(s, 16); s += __shfl_down(s, 8);
  s += __shfl_down(s, 4);  s += __shfl_down(s, 2);  s += __shfl_down(s, 1);
  if ((tid & 63) == 0) red[tid >> 6] = s;
  __syncthreads();
  const float mean = (red[0] + red[1] + red[2] + red[3]) * (1.0f / DD);
  __syncthreads();
  const float4 d = make_float4(v.x - mean, v.y - mean, v.z - mean, v.w - mean);
  float sq = d.x*d.x + d.y*d.y + d.z*d.z + d.w*d.w;
  sq += __shfl_down(sq, 32); sq += __shfl_down(sq, 16); sq += __shfl_down(sq, 8);
  sq += __shfl_down(sq, 4);  sq += __shfl_down(sq, 2);  sq += __shfl_down(sq, 1);
  if ((tid & 63) == 0) red[tid >> 6] = sq;
  __syncthreads();
  const float var = (red[0] + red[1] + red[2] + red[3]) * (1.0f / DD);
  const float rstd = rsqrtf(var + 1e-5f);
  const float4 gv = reinterpret_cast<const float4*>(an_g)[tid];
  const float4 bv = reinterpret_cast<const float4*>(an_b)[tid];
  u16x4 o;
  o[0] = f2bf(d.x * rstd * gv.x + bv.x);
  o[1] = f2bf(d.y * rstd * gv.y + bv.y);
  o[2] = f2bf(d.z * rstd * gv.z + bv.z);
  o[3] = f2bf(d.w * rstd * gv.w + bv.w);
  *reinterpret_cast<u16x4*>(hb + (size_t)row * DD + tid * 4) = o;
}

// ---------------- qkv GEMM v2: 128x128 tile, dbuf-2, stage after barrier ----------------
__global__ __launch_bounds__(256) void qkv_kernel(const u16* __restrict__ A, const u16* __restrict__ B,
                           const float* __restrict__ bias, u16* __restrict__ C) {
  const int n0 = blockIdx.x * 128, m0 = blockIdx.y * 128;
  const int tid = threadIdx.x, lane = tid & 63, w = tid >> 6;
  const int wm = w >> 1, wn = w & 1;
  __shared__ u16 As[2][128 * 64];
  __shared__ u16 Bs[2][128 * 64];
  f32x4 acc[4][4];
#pragma unroll
  for (int i = 0; i < 4; ++i)
#pragma unroll
    for (int j = 0; j < 4; ++j) acc[i][j] = f32x4{0.f, 0.f, 0.f, 0.f};
  auto stage = [&](int t, int buf) {
    const int k0 = t * 64;
#pragma unroll
    for (int q = 0; q < 4; ++q) {
      const int idx = w * 4 + q, r = idx * 8 + (lane >> 3), c = (lane & 7) ^ (r & 7);
      GLOAD16(A + (size_t)(m0 + r) * DD + k0 + c * 8, &As[buf][idx * 512]);
    }
#pragma unroll
    for (int q = 0; q < 4; ++q) {
      const int idx = w * 4 + q, r = idx * 8 + (lane >> 3), c = (lane & 7) ^ (r & 7);
      GLOAD16(B + (size_t)(n0 + r) * DD + k0 + c * 8, &Bs[buf][idx * 512]);
    }
  };
  stage(0, 0);
  asm volatile("s_waitcnt vmcnt(0)" ::: "memory");
  __syncthreads();
  const int T = DD / 64;
  for (int t = 0; t < T; ++t) {
    if (t > 0) {
      asm volatile("s_waitcnt vmcnt(0)" ::: "memory");
      __builtin_amdgcn_s_barrier();
      asm volatile("" ::: "memory");
    }
    if (t + 1 < T) stage(t + 1, (t + 1) & 1);
    const u16* Ab = As[t & 1];
    const u16* Bb = Bs[t & 1];
    const int xb = (((lane >> 4) ^ (lane & 7)) * 16);
    s16x8 af[4][2], bfr[4][2];
#pragma unroll
    for (int mf = 0; mf < 4; ++mf) {
      const char* p = (const char*)Ab + (wm * 64 + mf * 16 + (lane & 15)) * 128;
      af[mf][0] = *(const s16x8*)(p + xb);
      af[mf][1] = *(const s16x8*)(p + (xb ^ 64));
    }
#pragma unroll
    for (int nf = 0; nf < 4; ++nf) {
      const char* p = (const char*)Bb + (wn * 64 + nf * 16 + (lane & 15)) * 128;
      bfr[nf][0] = *(const s16x8*)(p + xb);
      bfr[nf][1] = *(const s16x8*)(p + (xb ^ 64));
    }
    __builtin_amdgcn_s_setprio(1);
#pragma unroll
    for (int ks = 0; ks < 2; ++ks)
#pragma unroll
      for (int mf = 0; mf < 4; ++mf)
#pragma unroll
        for (int nf = 0; nf < 4; ++nf)
          acc[mf][nf] = MFMA16(af[mf][ks], bfr[nf][ks], acc[mf][nf]);
    __builtin_amdgcn_s_setprio(0);
  }
#pragma unroll
  for (int mf = 0; mf < 4; ++mf)
#pragma unroll
    for (int rr = 0; rr < 4; ++rr) {
      const int row = m0 + wm * 64 + mf * 16 + (lane >> 4) * 4 + rr;
#pragma unroll
      for (int nf = 0; nf < 4; ++nf) {
        const int col = n0 + wn * 64 + nf * 16 + (lane & 15);
        C[(size_t)row * D3 + col] = f2bf(acc[mf][nf][rr] + bias[col]);
      }
    }
}

// ---------------- out proj: ring-3 (r11, passed); f32 out + bf16 scatter to x2g ----------------
__global__ __launch_bounds__(256) void out_kernel(const u16* __restrict__ A, const u16* __restrict__ B,
                           const float* __restrict__ bias, const float* __restrict__ resid,
                           float* __restrict__ C, u16* __restrict__ x2g,
                           const int* __restrict__ inv) {
  const int n0 = blockIdx.x * 64, m0 = blockIdx.y * 128;
  const int tid = threadIdx.x, lane = tid & 63, w = tid >> 6;
  const int wm = w >> 1, wn = w & 1;
  __shared__ u16 As[3][128 * 64];
  __shared__ u16 Bs[3][64 * 64];
  f32x4 acc[4][2];
#pragma unroll
  for (int i = 0; i < 4; ++i)
#pragma unroll
    for (int j = 0; j < 2; ++j) acc[i][j] = f32x4{0.f, 0.f, 0.f, 0.f};
  auto stage = [&](int t, int buf) {
    const int k0 = t * 64;
#pragma unroll
    for (int q = 0; q < 4; ++q) {
      const int idx = w * 4 + q, r = idx * 8 + (lane >> 3), c = (lane & 7) ^ (r & 7);
      GLOAD16(A + (size_t)(m0 + r) * DD + k0 + c * 8, &As[buf][idx * 512]);
    }
#pragma unroll
    for (int q = 0; q < 2; ++q) {
      const int idx = w * 2 + q, r = idx * 8 + (lane >> 3), c = (lane & 7) ^ (r & 7);
      GLOAD16(B + (size_t)(n0 + r) * DD + k0 + c * 8, &Bs[buf][idx * 512]);
    }
  };
  stage(0, 0);
  stage(1, 1);
  const int T = DD / 64;
  for (int t = 0; t < T; ++t) {
    if (t + 1 < T) asm volatile("s_waitcnt vmcnt(6)" ::: "memory");
    else           asm volatile("s_waitcnt vmcnt(0)" ::: "memory");
    __builtin_amdgcn_s_barrier();
    asm volatile("" ::: "memory");
    if (t + 2 < T) stage(t + 2, (t + 2) % 3);
    const u16* Ab = As[t % 3];
    const u16* Bb = Bs[t % 3];
    const int xb = (((lane >> 4) ^ (lane & 7)) * 16);
    s16x8 af[4][2], bfr[2][2];
#pragma unroll
    for (int mf = 0; mf < 4; ++mf) {
      const char* p = (const char*)Ab + (wm * 64 + mf * 16 + (lane & 15)) * 128;
      af[mf][0] = *(const s16x8*)(p + xb);
      af[mf][1] = *(const s16x8*)(p + (xb ^ 64));
    }
#pragma unroll
    for (int nf = 0; nf < 2; ++nf) {
      const char* p = (const char*)Bb + (wn * 32 + nf * 16 + (lane & 15)) * 128;
      bfr[nf][0] = *(const s16x8*)(p + xb);
      bfr[nf][1] = *(const s16x8*)(p + (xb ^ 64));
    }
    __builtin_amdgcn_s_setprio(1);
#pragma unroll
    for (int ks = 0; ks < 2; ++ks)
#pragma unroll
      for (int mf = 0; mf < 4; ++mf)
#pragma unroll
        for (int nf = 0; nf < 2; ++nf)
          acc[mf][nf] = MFMA16(af[mf][ks], bfr[nf][ks], acc[mf][nf]);
    __builtin_amdgcn_s_setprio(0);
  }
#pragma unroll
  for (int mf = 0; mf < 4; ++mf)
#pragma unroll
    for (int rr = 0; rr < 4; ++rr) {
      const int row = m0 + wm * 64 + mf * 16 + (lane >> 4) * 4 + rr;
      const int slot = inv[row];
#pragma unroll
      for (int nf = 0; nf < 2; ++nf) {
        const int col = n0 + wn * 32 + nf * 16 + (lane & 15);
        const float v = acc[mf][nf][rr] + bias[col] + resid[(size_t)row * DD + col];
        C[(size_t)row * DD + col] = v;
        x2g[(size_t)slot * DD + col] = f2bf(v);
      }
    }
}

// ---------------- MFMA flash attention: 128 q x (b,h) per block, 8 waves x 16 q ----------------
__global__ __launch_bounds__(512) void attn_kernel(const u16* __restrict__ qkv,
                                                   const u16* __restrict__ Vt,
                                                   u16* __restrict__ ctx) {
  const int q0 = blockIdx.x * 128, h = blockIdx.y, b = blockIdx.z;
  const int tid = threadIdx.x, lane = tid & 63, w = tid >> 6;
  const int q15 = lane & 15, g = lane >> 4, l7 = lane & 7;
  __shared__ u16 Q_lds[128 * 64];
  __shared__ u16 K_lds[2][64 * 64];
  __shared__ u16 V_lds[2][64 * 64];
  __shared__ u16 P_lds[8][16 * 72];
  __shared__ float s_lds[8][16];

#pragma unroll
  for (int q2 = 0; q2 < 2; ++q2) {
    const int idx = w * 2 + q2;
    const int r = idx * 8 + (lane >> 3);
    const int c = l7 ^ (r & 7);
    GLOAD16(qkv + (size_t)(b * SS + q0 + r) * D3 + h * HDIM + c * 8, &Q_lds[idx * 512]);
  }
  auto stageK = [&](int buf, int kt) {
    const int r = w * 8 + (lane >> 3);
    const int c = l7 ^ (r & 7);
    GLOAD16(qkv + (size_t)(b * SS + kt * 64 + r) * D3 + DD + h * HDIM + c * 8,
            &K_lds[buf][w * 512]);
  };
  auto stageV = [&](int buf, int kt) {
    const int r = w * 8 + (lane >> 3);
    const int c = l7 ^ (r & 7);
    GLOAD16(Vt + ((size_t)(b * HH + h) * HDIM + r) * SS + kt * 64 + c * 8,
            &V_lds[buf][w * 512]);
  };
  stageK(0, 0);
  stageV(0, 0);
  asm volatile("s_waitcnt vmcnt(0)" ::: "memory");
  __syncthreads();
  s16x8 bq[2];
#pragma unroll
  for (int ks = 0; ks < 2; ++ks)
    bq[ks] = *(const s16x8*)((const char*)Q_lds + (w * 16 + q15) * 128 + ((4 * ks + g) ^ l7) * 16);
  f32x4 oacc[4];
#pragma unroll
  for (int nf = 0; nf < 4; ++nf) oacc[nf] = f32x4{0.f, 0.f, 0.f, 0.f};
  float mrun = -3.0e38f, lrun = 0.0f;
  int buf = 0;
  for (int kt = 0; kt < 16; ++kt) {
    if (kt < 15) { stageK(buf ^ 1, kt + 1); stageV(buf ^ 1, kt + 1); }
    f32x4 st[4];
#pragma unroll
    for (int mf = 0; mf < 4; ++mf) st[mf] = f32x4{0.f, 0.f, 0.f, 0.f};
#pragma unroll
    for (int ks = 0; ks < 2; ++ks) {
#pragma unroll
      for (int mf = 0; mf < 4; ++mf) {
        const s16x8 ka = *(const s16x8*)((const char*)K_lds[buf] + (mf * 16 + q15) * 128 +
                                         ((4 * ks + g) ^ l7) * 16);
        st[mf] = MFMA16(ka, bq[ks], st[mf]);
      }
    }
    float t0[4][4];
    float cmax = -3.0e38f;
#pragma unroll
    for (int mf = 0; mf < 4; ++mf)
#pragma unroll
      for (int r = 0; r < 4; ++r) {
        const float v = st[mf][r] * 0.125f;
        t0[mf][r] = v;
        cmax = fmaxf(cmax, v);
      }
    cmax = fmaxf(cmax, __shfl_xor(cmax, 16));
    cmax = fmaxf(cmax, __shfl_xor(cmax, 32));
    const float mnew = fmaxf(mrun, cmax);
    const float scf = __expf(mrun - mnew);
    float psum = 0.f;
#pragma unroll
    for (int mf = 0; mf < 4; ++mf)
#pragma unroll
      for (int r = 0; r < 4; ++r) {
        const float p = __expf(t0[mf][r] - mnew);
        t0[mf][r] = p;
        psum += p;
      }
    psum += __shfl_xor(psum, 16);
    psum += __shfl_xor(psum, 32);
    lrun = lrun * scf + psum;
    mrun = mnew;
    s_lds[w][q15] = scf;
    u16* pw = &P_lds[w][0];
#pragma unroll
    for (int mf = 0; mf < 4; ++mf) {
      u32x2 pk;
      pk[0] = (unsigned)f2bf(t0[mf][0]) | ((unsigned)f2bf(t0[mf][1]) << 16);
      pk[1] = (unsigned)f2bf(t0[mf][2]) | ((unsigned)f2bf(t0[mf][3]) << 16);
      *(u32x2*)(pw + q15 * 72 + mf * 16 + g * 4) = pk;
    }
    asm volatile("s_waitcnt lgkmcnt(0)" ::: "memory");
    const f32x4 scv = *(const f32x4*)&s_lds[w][g * 4];
#pragma unroll
    for (int nf = 0; nf < 4; ++nf)
#pragma unroll
      for (int r = 0; r < 4; ++r) oacc[nf][r] *= scv[r];
#pragma unroll
    for (int ks = 0; ks < 2; ++ks) {
      const s16x8 pa = *(const s16x8*)(pw + q15 * 72 + ks * 32 + g * 8);
#pragma unroll
      for (int nf = 0; nf < 4; ++nf) {
        const s16x8 bv = *(const s16x8*)((const char*)V_lds[buf] + (nf * 16 + q15) * 128 +
                                         ((4 * ks + g) ^ l7) * 16);
        oacc[nf] = MFMA16(pa, bv, oacc[nf]);
      }
    }
    asm volatile("s_waitcnt vmcnt(0)" ::: "memory");
    __syncthreads();
    buf ^= 1;
  }
  const float linv = 1.0f / lrun;
  s_lds[w][q15] = linv;
  asm volatile("s_waitcnt lgkmcnt(0)" ::: "memory");
  const f32x4 lv = *(const f32x4*)&s_lds[w][g * 4];
#pragma unroll
  for (int nf = 0; nf < 4; ++nf)
#pragma unroll
    for (int r = 0; r < 4; ++r) {
      const int qg = q0 + w * 16 + g * 4 + r;
      ctx[(size_t)(b * SS + qg) * DD + h * HDIM + nf * 16 + q15] = f2bf(oacc[nf][r] * lv[r]);
    }
}

// ---------------- routing (single launch): counts, offsets, slot-pack, inverse ----------------
__global__ void routing_kernel(const int* __restrict__ gid, int* __restrict__ cnts_g,
                               int* __restrict__ off_g, int* __restrict__ gidx,
                               int* __restrict__ inv) {
  __shared__ int cnt[GG];
  __shared__ int off[GG + 1];
  const int tid = threadIdx.x;  // 1024 threads
  if (tid < GG) cnt[tid] = 0;
  __syncthreads();
  const int t0 = tid, t1 = tid + 1024;
  const int g0 = gid[t0], g1 = gid[t1];
  const int s0 = atomicAdd(&cnt[g0], 1);
  const int s1 = atomicAdd(&cnt[g1], 1);
  __syncthreads();
  if (tid == 0) {
    int s = 0;
#pragma unroll
    for (int g = 0; g < GG; ++g) { off[g] = s; s += cnt[g]; }
    off[GG] = s;
  }
  __syncthreads();
  const int sg0 = off[g0] + s0;
  gidx[sg0] = t0; inv[t0] = sg0;
  const int sg1 = off[g1] + s1;
  gidx[sg1] = t1; inv[t1] = sg1;
  if (tid < GG) cnts_g[tid] = cnt[tid];
  if (tid <= GG) off_g[tid] = off[tid];
}

// ---------------- MoE GEMM1 v2: 128x128 tile, dbuf-2 ----------------
__global__ __launch_bounds__(256) void moe1_kernel(const u16* __restrict__ x2g, const u16* __restrict__ w1t,
                            const float* __restrict__ e_b1, const int* __restrict__ off,
                            const int* __restrict__ cnts, u16* __restrict__ h1) {
  const int ge = blockIdx.z, g = ge >> 1, e = ge & 1;
  const int cnt = cnts[g];
  const int m0 = blockIdx.y * 128;
  if (m0 >= cnt) return;
  const int base = off[g];
  const int n0 = blockIdx.x * 128;
  const u16* A = x2g + (size_t)base * DD;       // contiguous rows of this group
  const u16* B = w1t + (size_t)ge * HIDN * DD;  // [HID][D]
  const int tid = threadIdx.x, lane = tid & 63, w = tid >> 6;
  const int wm = w >> 1, wn = w & 1;
  __shared__ u16 As[2][128 * 64];
  __shared__ u16 Bs[2][128 * 64];
  f32x4 acc[4][4];
#pragma unroll
  for (int i = 0; i < 4; ++i)
#pragma unroll
    for (int j = 0; j < 4; ++j) acc[i][j] = f32x4{0.f, 0.f, 0.f, 0.f};
  auto stage = [&](int t, int buf) {
    const int k0 = t * 64;
#pragma unroll
    for (int q = 0; q < 4; ++q) {
      const int idx = w * 4 + q, r = idx * 8 + (lane >> 3), c = (lane & 7) ^ (r & 7);
      int rg = m0 + r; if (rg > cnt - 1) rg = cnt - 1;
      GLOAD16(A + (size_t)rg * DD + k0 + c * 8, &As[buf][idx * 512]);
    }
#pragma unroll
    for (int q = 0; q < 4; ++q) {
      const int idx = w * 4 + q, r = idx * 8 + (lane >> 3), c = (lane & 7) ^ (r & 7);
      GLOAD16(B + (size_t)(n0 + r) * DD + k0 + c * 8, &Bs[buf][idx * 512]);
    }
  };
  stage(0, 0);
  asm volatile("s_waitcnt vmcnt(0)" ::: "memory");
  __syncthreads();
  const int T = DD / 64;
  for (int t = 0; t < T; ++t) {
    if (t > 0) {
      asm volatile("s_waitcnt vmcnt(0)" ::: "memory");
      __builtin_amdgcn_s_barrier();
      asm volatile("" ::: "memory");
    }
    if (t + 1 < T) stage(t + 1, (t + 1) & 1);
    const u16* Ab = As[t & 1];
    const u16* Bb = Bs[t & 1];
    const int xb = (((lane >> 4) ^ (lane & 7)) * 16);
    s16x8 af[4][2], bfr[4][2];
#pragma unroll
    for (int mf = 0; mf < 4; ++mf) {
      const char* p = (const char*)Ab + (wm * 64 + mf * 16 + (lane & 15)) * 128;
      af[mf][0] = *(const s16x8*)(p + xb);
      af[mf][1] = *(const s16x8*)(p + (xb ^ 64));
    }
#pragma unroll
    for (int nf = 0; nf < 4; ++nf) {
      const char* p = (const char*)Bb + (wn * 64 + nf * 16 + (lane & 15)) * 128;
      bfr[nf][0] = *(const s16x8*)(p + xb);
      bfr[nf][1] = *(const s16x8*)(p + (xb ^ 64));
    }
    __builtin_amdgcn_s_setprio(1);
#pragma unroll
    for (int ks = 0; ks < 2; ++ks)
#pragma unroll
      for (int mf = 0; mf < 4; ++mf)
#pragma unroll
        for (int nf = 0; nf < 4; ++nf)
          acc[mf][nf] = MFMA16(af[mf][ks], bfr[nf][ks], acc[mf][nf]);
    __builtin_amdgcn_s_setprio(0);
  }
  const float* b1 = e_b1 + (size_t)ge * HIDN;
#pragma unroll
  for (int mf = 0; mf < 4; ++mf)
#pragma unroll
    for (int rr = 0; rr < 4; ++rr) {
      const int rowg = m0 + wm * 64 + mf * 16 + (lane >> 4) * 4 + rr;
      if (rowg < cnt) {
        u16* orow = h1 + ((size_t)e * NTOK + base + rowg) * HIDN;  // slot-ordered
#pragma unroll
        for (int nf = 0; nf < 4; ++nf) {
          const int col = n0 + wn * 64 + nf * 16 + (lane & 15);
          orow[col] = f2bf(gelu_f(acc[mf][nf][rr] + b1[col]));
        }
      }
    }
}

// ---------------- MoE GEMM2: ring-3 (r11, passed); scatter epilogue ----------------
__global__ __launch_bounds__(256) void moe2_kernel(const u16* __restrict__ h1, const u16* __restrict__ w2t,
                            const float* __restrict__ e_b2, const int* __restrict__ off,
                            const int* __restrict__ cnts, const int* __restrict__ gidx,
                            const float* __restrict__ x2, float* __restrict__ outp) {
  const int g = blockIdx.z;
  const int cnt = cnts[g];
  const int m0 = blockIdx.y * 128;
  if (m0 >= cnt) return;
  const int base = off[g];
  const int n0 = blockIdx.x * 64;
  const int tid = threadIdx.x, lane = tid & 63, w = tid >> 6;
  const int wm = w >> 1, wn = w & 1;
  __shared__ u16 As[3][128 * 64];
  __shared__ u16 Bs[3][64 * 64];
  f32x4 acc[4][2];
#pragma unroll
  for (int i = 0; i < 4; ++i)
#pragma unroll
    for (int j = 0; j < 2; ++j) acc[i][j] = f32x4{0.f, 0.f, 0.f, 0.f};
  auto stage = [&](int t, int buf) {
    const int e = t >> 5;
    const int k0 = (t & 31) * 64;
#pragma unroll
    for (int q = 0; q < 4; ++q) {
      const int idx = w * 4 + q, r = idx * 8 + (lane >> 3), c = (lane & 7) ^ (r & 7);
      int rg = m0 + r; if (rg > cnt - 1) rg = cnt - 1;
      GLOAD16(h1 + ((size_t)e * NTOK + base + rg) * HIDN + k0 + c * 8, &As[buf][idx * 512]);
    }
#pragma unroll
    for (int q = 0; q < 2; ++q) {
      const int idx = w * 2 + q, r = idx * 8 + (lane >> 3), c = (lane & 7) ^ (r & 7);
      GLOAD16(w2t + ((size_t)(g * EE + e) * DD + n0 + r) * HIDN + k0 + c * 8, &Bs[buf][idx * 512]);
    }
  };
  stage(0, 0);
  stage(1, 1);
  const int T = 64;
  for (int t = 0; t < T; ++t) {
    if (t + 1 < T) asm volatile("s_waitcnt vmcnt(6)" ::: "memory");
    else           asm volatile("s_waitcnt vmcnt(0)" ::: "memory");
    __builtin_amdgcn_s_barrier();
    asm volatile("" ::: "memory");
    if (t + 2 < T) stage(t + 2, (t + 2) % 3);
    const u16* Ab = As[t % 3];
    const u16* Bb = Bs[t % 3];
    const int xb = (((lane >> 4) ^ (lane & 7)) * 16);
    s16x8 af[4][2], bfr[2][2];
#pragma unroll
    for (int mf = 0; mf < 4; ++mf) {
      const char* p = (const char*)Ab + (wm * 64 + mf * 16 + (lane & 15)) * 128;
      af[mf][0] = *(const s16x8*)(p + xb);
      af[mf][1] = *(const s16x8*)(p + (xb ^ 64));
    }
#pragma unroll
    for (int nf = 0; nf < 2; ++nf) {
      const char* p = (const char*)Bb + (wn * 32 + nf * 16 + (lane & 15)) * 128;
      bfr[nf][0] = *(const s16x8*)(p + xb);
      bfr[nf][1] = *(const s16x8*)(p + (xb ^ 64));
    }
    __builtin_amdgcn_s_setprio(1);
#pragma unroll
    for (int ks = 0; ks < 2; ++ks)
#pragma unroll
      for (int mf = 0; mf < 4; ++mf)
#pragma unroll
        for (int nf = 0; nf < 2; ++nf)
          acc[mf][nf] = MFMA16(af[mf][ks], bfr[nf][ks], acc[mf][nf]);
    __builtin_amdgcn_s_setprio(0);
  }
  const float* b20 = e_b2 + (size_t)(g * EE + 0) * DD;
  const float* b21 = e_b2 + (size_t)(g * EE + 1) * DD;
#pragma unroll
  for (int mf = 0; mf < 4; ++mf)
#pragma unroll
    for (int rr = 0; rr < 4; ++rr) {
      const int rowg = m0 + wm * 64 + mf * 16 + (lane >> 4) * 4 + rr;
      if (rowg < cnt) {
        const int tok = gidx[base + rowg];
#pragma unroll
        for (int nf = 0; nf < 2; ++nf) {
          const int col = n0 + wn * 32 + nf * 16 + (lane & 15);
          outp[(size_t)tok * DD + col] =
              0.5f * acc[mf][nf][rr] + 0.5f * (b20[col] + b21[col]) + x2[(size_t)tok * DD + col];
        }
      }
    }
}

extern "C" void kernel_launch(void* const* d_in, const int* in_sizes, int n_in,
                              void* d_out, int out_size, void* d_ws, size_t ws_size,
                              hipStream_t stream) {
  (void)in_sizes; (void)n_in; (void)out_size; (void)ws_size;
  const float* x      = (const float*)d_in[0];
  const int*   gid    = (const int*)d_in[1];
  const float* cn_g   = (const float*)d_in[2];
  const float* cn_b   = (const float*)d_in[3];
  const float* conv_w = (const float*)d_in[4];
  const float* conv_b = (const float*)d_in[5];
  const float* an_g   = (const float*)d_in[6];
  const float* an_b   = (const float*)d_in[7];
  const float* in_w   = (const float*)d_in[8];
  const float* in_b   = (const float*)d_in[9];
  const float* out_w  = (const float*)d_in[10];
  const float* out_b  = (const float*)d_in[11];
  const float* e_w1   = (const float*)d_in[12];
  const float* e_b1   = (const float*)d_in[13];
  const float* e_w2   = (const float*)d_in[14];
  const float* e_b2   = (const float*)d_in[15];
  float* outp = (float*)d_out;

  // ---- workspace map (high-water 74MB + ~41KB, identical to r5-r12 pass) ----
  char* wsp = (char*)d_ws;
  u16*   hb    = (u16*)(wsp);                         // 0..4M  (ln/combine out; ctxb reuse)
  u16*   Pc    = (u16*)(wsp + (4ull << 20));          // 4..12M (conv partials x2, conv phase)
  float* x1    = (float*)(wsp + (12ull << 20));       // 12..20M (combine out)
  u16*   Wb    = (u16*)(wsp + (12ull << 20));         // 12..74M (conv phase only)
  u16*   qkvb  = (u16*)(wsp + (24ull << 20));         // 24..36M (qkv->attn)
  u16*   inwb  = (u16*)(wsp + (40ull << 20));         // 40..46M (qkv phase)
  u16*   outwb = (u16*)(wsp + (40ull << 20));         // 40..42M (out phase, after qkv)
  u16*   Vt    = (u16*)(wsp + (46ull << 20));         // 46..50M (attn phase)
  u16*   ctxb  = hb;                                  // 0..4M  (after qkv)
  float* x2    = (float*)(wsp + (52ull << 20));       // 52..60M
  int*   inv   = (int*)(wsp + (60ull << 20));         // 60M.. 8KB (tok->slot; written post-conv)
  u16*   x2g   = (u16*)(wsp + (64ull << 20));         // 64..68M (slot-packed tokens)
  u16*   wgt   = (u16*)(wsp + (4ull << 20));          // 4..36M (w1t, then w2t; MoE phase)
  u16*   h1    = (u16*)(wsp + (36ull << 20));         // 36..52M (MoE phase, slot-ordered)
  int*   gat   = (int*)(wsp + (74ull << 20));         // 32KB (unused; kept for layout stability)
  int*   cnts  = gat + GG * NTOK;                     // 16B
  int*   offp  = cnts + GG;                           // 20B
  int*   gidx  = offp + (GG + 1);                     // 8KB

  // ---- conv block (v7, measured 179us) ----
  ln_kernel<<<NTOK, 256, 0, stream>>>(x, cn_g, cn_b, hb);
  prep_convw<<<1024, 256, 0, stream>>>(conv_w, Wb);
  conv_kernel<<<256, 512, 0, stream>>>(hb, Wb, Pc);
  // combine + attention-LN fused (writes x1 and hb)
  combine_kernel<<<NTOK, 256, 0, stream>>>(Pc, conv_b, x, an_g, an_b, x1, hb);
  // ---- routing, single launch (Wb dead; inv lives in its hole) ----
  routing_kernel<<<1, 1024, 0, stream>>>(gid, cnts, offp, gidx, inv);
  // ---- attention block ----
  cvt_kernel<<<3072, 256, 0, stream>>>(in_w, inwb, 3 * DD * DD / 4);
  qkv_kernel<<<dim3(D3 / 128, NTOK / 128), 256, 0, stream>>>(hb, inwb, in_b, qkvb);
  vtr_kernel<<<dim3(SS / 32, HDIM / 32, BB * HH), 256, 0, stream>>>(qkvb, Vt);
  attn_kernel<<<dim3(SS / 128, HH, BB), 512, 0, stream>>>(qkvb, Vt, ctxb);
  cvt_kernel<<<1024, 256, 0, stream>>>(out_w, outwb, DD * DD / 4);
  out_kernel<<<dim3(DD / 64, NTOK / 128), 256, 0, stream>>>(ctxb, outwb, out_b, x1, x2, x2g, inv);
  // ---- MoE (slot-packed + dense-fastest grids: all 8 XCDs active) ----
  tr_kernel<<<dim3(HIDN / 32, DD / 32, GG * EE), 256, 0, stream>>>(e_w1, wgt, DD, HIDN);
  moe1_kernel<<<dim3(HIDN / 128, NTOK / 128, GG * EE), 256, 0, stream>>>(x2g, wgt, e_b1, offp, cnts, h1);
  tr_kernel<<<dim3(DD / 32, HIDN / 32, GG * EE), 256, 0, stream>>>(e_w2, wgt, HIDN, DD);
  moe2_kernel<<<dim3(DD / 64, NTOK / 128, GG), 256, 0, stream>>>(h1, wgt, e_b2, offp, cnts, gidx, x2, outp);
}

// Round 14
// 466.079 us; speedup vs baseline: 1.1995x; 1.0127x over previous
//
#include <hip/hip_runtime.h>
#include <hip/hip_bf16.h>
#include <math.h>

#define BB 2
#define SS 1024
#define DD 1024
#define HH 16
#define HDIM 64
#define KK 31
#define GG 4
#define EE 2
#define HIDN 2048
#define NTOK (BB*SS)
#define D3 (3*DD)

typedef unsigned short u16;
typedef __attribute__((ext_vector_type(8))) short s16x8;
typedef __attribute__((ext_vector_type(8))) unsigned short u16x8;
typedef __attribute__((ext_vector_type(4))) unsigned short u16x4;
typedef __attribute__((ext_vector_type(2))) unsigned short u16x2;
typedef __attribute__((ext_vector_type(4))) float f32x4;
typedef __attribute__((ext_vector_type(2))) unsigned int u32x2;

__device__ __forceinline__ float gelu_f(float x) {
  return 0.5f * x * (1.0f + erff(x * 0.7071067811865475f));
}
__device__ __forceinline__ u16 f2bf(float f) {
  unsigned u = __builtin_bit_cast(unsigned, f);
  u = (u + 0x7fffu + ((u >> 16) & 1u)) >> 16;
  return (u16)u;
}
__device__ __forceinline__ float bf2f(u16 u) {
  return __builtin_bit_cast(float, ((unsigned)u) << 16);
}
__device__ __forceinline__ f32x4 MFMA16(s16x8 a, s16x8 b, f32x4 c) {
  return __builtin_amdgcn_mfma_f32_16x16x32_bf16(a, b, c, 0, 0, 0);
}
#define GLOAD16(gp, lp) __builtin_amdgcn_global_load_lds( \
    (const __attribute__((address_space(1))) void*)(gp),  \
    (__attribute__((address_space(3))) void*)(lp), 16, 0, 0)

// ---------------- LayerNorm: fp32 in -> bf16 out, one block per row ----------------
__global__ void ln_kernel(const float* __restrict__ x, const float* __restrict__ g,
                          const float* __restrict__ b, u16* __restrict__ out) {
  const int row = blockIdx.x;
  const int tid = threadIdx.x;
  __shared__ float red[4];
  const float4 v = reinterpret_cast<const float4*>(x + (size_t)row * DD)[tid];
  float s = v.x + v.y + v.z + v.w;
  s += __shfl_down(s, 32); s += __shfl_down(s, 16); s += __shfl_down(s, 8);
  s += __shfl_down(s, 4);  s += __shfl_down(s, 2);  s += __shfl_down(s, 1);
  if ((tid & 63) == 0) red[tid >> 6] = s;
  __syncthreads();
  const float mean = (red[0] + red[1] + red[2] + red[3]) * (1.0f / DD);
  __syncthreads();
  const float4 d = make_float4(v.x - mean, v.y - mean, v.z - mean, v.w - mean);
  float sq = d.x*d.x + d.y*d.y + d.z*d.z + d.w*d.w;
  sq += __shfl_down(sq, 32); sq += __shfl_down(sq, 16); sq += __shfl_down(sq, 8);
  sq += __shfl_down(sq, 4);  sq += __shfl_down(sq, 2);  sq += __shfl_down(sq, 1);
  if ((tid & 63) == 0) red[tid >> 6] = sq;
  __syncthreads();
  const float var = (red[0] + red[1] + red[2] + red[3]) * (1.0f / DD);
  const float rstd = rsqrtf(var + 1e-5f);
  const float4 gv = reinterpret_cast<const float4*>(g)[tid];
  const float4 bv = reinterpret_cast<const float4*>(b)[tid];
  u16x4 o;
  o[0] = f2bf(d.x * rstd * gv.x + bv.x);
  o[1] = f2bf(d.y * rstd * gv.y + bv.y);
  o[2] = f2bf(d.z * rstd * gv.z + bv.z);
  o[3] = f2bf(d.w * rstd * gv.w + bv.w);
  *reinterpret_cast<u16x4*>(out + (size_t)row * DD + tid * 4) = o;
}

// ---------------- conv weight reorder: conv_w[o][i][k] f32 -> Wb[k][o][i] bf16 ----------------
__global__ void prep_convw(const float* __restrict__ cw, u16* __restrict__ Wb) {
  const int o = blockIdx.x;
  const int i4 = threadIdx.x * 4;
  float wv[4][KK];
#pragma unroll
  for (int j = 0; j < 4; ++j) {
    const float* src = cw + ((size_t)o * DD + i4 + j) * KK;
#pragma unroll
    for (int k = 0; k < KK; ++k) wv[j][k] = src[k];
  }
#pragma unroll
  for (int k = 0; k < KK; ++k) {
    u16x4 o4;
    o4[0] = f2bf(wv[0][k]); o4[1] = f2bf(wv[1][k]);
    o4[2] = f2bf(wv[2][k]); o4[3] = f2bf(wv[3][k]);
    *(u16x4*)&Wb[((size_t)k * DD + o) * DD + i4] = o4;
  }
}

// ---------------- plain f32 -> bf16 convert ----------------
__global__ void cvt_kernel(const float* __restrict__ in, u16* __restrict__ outp, int n4) {
  const int i = blockIdx.x * 256 + threadIdx.x;
  if (i < n4) {
    const float4 v = reinterpret_cast<const float4*>(in)[i];
    u16x4 o; o[0] = f2bf(v.x); o[1] = f2bf(v.y); o[2] = f2bf(v.z); o[3] = f2bf(v.w);
    reinterpret_cast<u16x4*>(outp)[i] = o;
  }
}

// ---------------- transpose-convert: src[z][R][C] f32 -> dst[z][C][R] bf16, paired stores ----------------
__global__ void tr_kernel(const float* __restrict__ src, u16* __restrict__ dst, int R, int C) {
  __shared__ float tile[32][33];   // [r-local][c-local]
  const int c0 = blockIdx.x * 32, r0 = blockIdx.y * 32;
  const size_t base = (size_t)blockIdx.z * R * C;
  const int tx = threadIdx.x & 31, ty = threadIdx.x >> 5;  // ty 0..7
#pragma unroll
  for (int i = 0; i < 4; ++i)
    tile[ty + i * 8][tx] = src[base + (size_t)(r0 + ty + i * 8) * C + c0 + tx];
  __syncthreads();
  const int rx = threadIdx.x & 15, cy = threadIdx.x >> 4;  // cy 0..15
#pragma unroll
  for (int i = 0; i < 2; ++i) {
    const int c = cy + i * 16;
    u16x2 o2;
    o2[0] = f2bf(tile[2 * rx][c]);
    o2[1] = f2bf(tile[2 * rx + 1][c]);
    *(u16x2*)&dst[base + (size_t)(c0 + c) * R + r0 + 2 * rx] = o2;
  }
}

// ---------------- conv via MFMA v7 (measured 179us): barrier-free taps, private B ring-3 ----------------
__global__ __launch_bounds__(512) void conv_kernel(const u16* __restrict__ hb,
                                                   const u16* __restrict__ Wb,
                                                   u16* __restrict__ P) {
  const int L = blockIdx.x;            // 0..255
  const int o_t = L & 7;               // o-tile pinned per XCD (B L2 reuse)
  const int rest = L >> 3;
  const int s_t = rest >> 1;           // 0..15
  const int z = rest & 1;              // i-half
  const int b = s_t >> 3, sloc = s_t & 7;
  const int s0l = sloc * 128;
  const int o0 = o_t * 128;
  const int ibase = z * 512;
  const int tid = threadIdx.x, lane = tid & 63, w = tid >> 6;
  const int wm = (w >> 2) & 1, wn = (w >> 1) & 1, ksid = w & 1;
  const int q15 = lane & 15, g = lane >> 4;
  __shared__ __align__(16) u16 Ad[2][160 * 64];   // 40 KB, dbuf over i-slices
  __shared__ __align__(16) u16 Bp[8][3][2048];    // 96 KB, wave-private ring-3 (4KB slots)
  const int rlo = (sloc == 0) ? 15 : 0;
  const int rhi = (sloc == 7) ? 143 : 158;
  if (sloc == 0)
    for (int i = tid; i < 15 * 64; i += 512) { Ad[0][i] = 0; Ad[1][i] = 0; }
  if (sloc == 7)
    for (int i = tid; i < 17 * 64; i += 512) { Ad[0][143 * 64 + i] = 0; Ad[1][143 * 64 + i] = 0; }
  auto stageA = [&](int buf, int i0) {
    for (int q = w; q < 20; q += 8) {
      const int r = q * 8 + (lane >> 3);
      const int c = (lane & 7) ^ (r & 7);
      if (r >= rlo && r < rhi)
        GLOAD16(hb + (size_t)(b * SS + s0l - 15 + r) * DD + i0 + c * 8, &Ad[buf][q * 512]);
    }
  };
  auto stageBp = [&](int slot, int k, int i0w) {
#pragma unroll
    for (int q = 0; q < 4; ++q) {
      const int j = lane >> 2;                      // o-subrow 0..15
      const int r = q * 16 + j;                     // o-row local 0..63
      const int c16 = (lane & 3) ^ ((j >> 1) & 3);  // chunk 0..3, quad-permuted
      GLOAD16(Wb + ((size_t)k * DD + o0 + wn * 64 + r) * DD + i0w + c16 * 8,
              &Bp[w][slot][q * 512]);
    }
  };
  f32x4 acc[4][4];
#pragma unroll
  for (int i = 0; i < 4; ++i)
#pragma unroll
    for (int j = 0; j < 4; ++j) acc[i][j] = f32x4{0.f, 0.f, 0.f, 0.f};
  const int ib0 = ibase + ksid * 32;
  stageA(0, ibase);
  stageBp(0, 0, ib0);
  stageBp(1, 1, ib0);
  asm volatile("s_waitcnt vmcnt(0)" ::: "memory");
  __syncthreads();
  const int T = 8 * KK;  // 248 taps
  const int kx = ksid * 64;  // byte XOR selecting this wave's K=32 half in Ad rows
  const int bro = q15 * 64 + ((g ^ ((q15 >> 1) & 3)) << 4);  // per-lane B frag offset
  int t = 0;
  for (int i0i = 0; i0i < 8; ++i0i) {
    const u16* Ab = Ad[i0i & 1];
    for (int k = 0; k < KK; ++k, ++t) {
      {  // prefetch own B(t+2) into private ring
        const int tn = t + 2;
        if (tn < T) stageBp(tn % 3, tn % KK, ibase + (tn / KK) * 64 + ksid * 32);
      }
      // A frags from shared Ad (slice-stable)
      s16x8 af[4];
      const int rk0 = wm * 64 + q15 + k;
#pragma unroll
      for (int mf = 0; mf < 4; ++mf) {
        const int rr = rk0 + mf * 16;
        const char* p = (const char*)Ab + rr * 128;
        af[mf] = *(const s16x8*)(p + (((g ^ (rr & 7)) * 16) ^ kx));
      }
      // own B(t) landed when <= 2 taps' worth of own loads outstanding
      if (t + 2 < T)      asm volatile("s_waitcnt vmcnt(8)" ::: "memory");
      else if (t + 1 < T) asm volatile("s_waitcnt vmcnt(4)" ::: "memory");
      else                asm volatile("s_waitcnt vmcnt(0)" ::: "memory");
      // A prefetch AFTER the counted wait (issue-only; consumed after slice barrier)
      if (k == 5 && i0i < 7) stageA((i0i + 1) & 1, ibase + (i0i + 1) * 64);
      const char* Bb = (const char*)&Bp[w][t % 3][0];
      s16x8 bfr[4];
#pragma unroll
      for (int nf = 0; nf < 4; ++nf)
        bfr[nf] = *(const s16x8*)(Bb + nf * 1024 + bro);   // bank-quad bijective, 0-conflict
      __builtin_amdgcn_s_setprio(1);
#pragma unroll
      for (int mf = 0; mf < 4; ++mf)
#pragma unroll
        for (int nf = 0; nf < 4; ++nf)
          acc[mf][nf] = MFMA16(af[mf], bfr[nf], acc[mf][nf]);
      __builtin_amdgcn_s_setprio(0);
    }
    if (i0i < 7) {                       // slice boundary: Ad swap (cross-wave A visibility)
      asm volatile("s_waitcnt vmcnt(0)" ::: "memory");
      __syncthreads();
    }
  }
  // ---- ks-pair reduction: ks1 waves stash f32 acc in LDS (reuse Bp), ks0 sums+writes ----
  __syncthreads();
  float* scr = (float*)(&Bp[0][0][0]) + (wm * 2 + wn) * 4096;
  if (ksid == 1) {
#pragma unroll
    for (int mf = 0; mf < 4; ++mf)
#pragma unroll
      for (int nf = 0; nf < 4; ++nf) {
        const int col = nf * 16 + q15;
        *(f32x4*)&scr[col * 64 + ((mf * 16 + g * 4) ^ ((col & 7) << 3))] = acc[mf][nf];
      }
  }
  __syncthreads();
  if (ksid == 0) {
    u16* Pz = P + (size_t)z * NTOK * DD;
#pragma unroll
    for (int mf = 0; mf < 4; ++mf) {
      f32x4 sum[4];
#pragma unroll
      for (int nf = 0; nf < 4; ++nf) {
        const int col = nf * 16 + q15;
        const f32x4 o = *(const f32x4*)&scr[col * 64 + ((mf * 16 + g * 4) ^ ((col & 7) << 3))];
        sum[nf] = acc[mf][nf] + o;
      }
#pragma unroll
      for (int r = 0; r < 4; ++r) {
        const int srow = s0l + wm * 64 + mf * 16 + g * 4 + r;
        u16* orow = Pz + (size_t)(b * SS + srow) * DD + o0 + wn * 64;
#pragma unroll
        for (int nf = 0; nf < 4; ++nf)
          orow[nf * 16 + q15] = f2bf(sum[nf][r]);
      }
    }
  }
}

// ---------------- combine+LN fused: x1 = gelu(P0+P1+cb)+x ; hb = LN(x1)*an_g+an_b ----------------
__global__ void combine_kernel(const u16* __restrict__ P, const float* __restrict__ cb,
                               const float* __restrict__ x, const float* __restrict__ an_g,
                               const float* __restrict__ an_b, float* __restrict__ x1,
                               u16* __restrict__ hb) {
  const int row = blockIdx.x;
  const int tid = threadIdx.x;
  const size_t base = (size_t)row * DD + tid * 4;
  const int col = tid * 4;
  __shared__ float red[4];
  const u16x4 p0 = *(const u16x4*)(P + base);
  const u16x4 p1 = *(const u16x4*)(P + (size_t)NTOK * DD + base);
  const float4 xv = *(const float4*)(x + base);
  const float4 cbv = *(const float4*)(cb + col);
  float4 v;
  v.x = gelu_f(bf2f(p0[0]) + bf2f(p1[0]) + cbv.x) + xv.x;
  v.y = gelu_f(bf2f(p0[1]) + bf2f(p1[1]) + cbv.y) + xv.y;
  v.z = gelu_f(bf2f(p0[2]) + bf2f(p1[2]) + cbv.z) + xv.z;
  v.w = gelu_f(bf2f(p0[3]) + bf2f(p1[3]) + cbv.w) + xv.w;
  *(float4*)(x1 + base) = v;
  float s = v.x + v.y + v.z + v.w;
  s += __shfl_down(s, 32); s += __shfl_down(s, 16); s += __shfl_down(s, 8);
  s += __shfl_down(s, 4);  s += __shfl_down(s, 2);  s += __shfl_down(s, 1);
  if ((tid & 63) == 0) red[tid >> 6] = s;
  __syncthreads();
  const float mean = (red[0] + red[1] + red[2] + red[3]) * (1.0f / DD);
  __syncthreads();
  const float4 d = make_float4(v.x - mean, v.y - mean, v.z - mean, v.w - mean);
  float sq = d.x*d.x + d.y*d.y + d.z*d.z + d.w*d.w;
  sq += __shfl_down(sq, 32); sq += __shfl_down(sq, 16); sq += __shfl_down(sq, 8);
  sq += __shfl_down(sq, 4);  sq += __shfl_down(sq, 2);  sq += __shfl_down(sq, 1);
  if ((tid & 63) == 0) red[tid >> 6] = sq;
  __syncthreads();
  const float var = (red[0] + red[1] + red[2] + red[3]) * (1.0f / DD);
  const float rstd = rsqrtf(var + 1e-5f);
  const float4 gv = reinterpret_cast<const float4*>(an_g)[tid];
  const float4 bv = reinterpret_cast<const float4*>(an_b)[tid];
  u16x4 o;
  o[0] = f2bf(d.x * rstd * gv.x + bv.x);
  o[1] = f2bf(d.y * rstd * gv.y + bv.y);
  o[2] = f2bf(d.z * rstd * gv.z + bv.z);
  o[3] = f2bf(d.w * rstd * gv.w + bv.w);
  *reinterpret_cast<u16x4*>(hb + (size_t)row * DD + tid * 4) = o;
}

// ---------------- qkv GEMM v3: 128x128 tile, dbuf-2; V n-tiles transpose-write Vt directly ----------------
// For n0 >= 2D: bias-add -> bf16 -> LDS transpose (reuse dead As, 32KB) -> coalesced Vt rows.
// Kills the vtr kernel; qkvb V-part never written (attn reads V only via Vt).
__global__ __launch_bounds__(256) void qkv_kernel(const u16* __restrict__ A, const u16* __restrict__ B,
                           const float* __restrict__ bias, u16* __restrict__ C,
                           u16* __restrict__ Vt) {
  const int n0 = blockIdx.x * 128, m0 = blockIdx.y * 128;
  const int tid = threadIdx.x, lane = tid & 63, w = tid >> 6;
  const int wm = w >> 1, wn = w & 1;
  __shared__ __align__(16) u16 As[2][128 * 64];
  __shared__ __align__(16) u16 Bs[2][128 * 64];
  f32x4 acc[4][4];
#pragma unroll
  for (int i = 0; i < 4; ++i)
#pragma unroll
    for (int j = 0; j < 4; ++j) acc[i][j] = f32x4{0.f, 0.f, 0.f, 0.f};
  auto stage = [&](int t, int buf) {
    const int k0 = t * 64;
#pragma unroll
    for (int q = 0; q < 4; ++q) {
      const int idx = w * 4 + q, r = idx * 8 + (lane >> 3), c = (lane & 7) ^ (r & 7);
      GLOAD16(A + (size_t)(m0 + r) * DD + k0 + c * 8, &As[buf][idx * 512]);
    }
#pragma unroll
    for (int q = 0; q < 4; ++q) {
      const int idx = w * 4 + q, r = idx * 8 + (lane >> 3), c = (lane & 7) ^ (r & 7);
      GLOAD16(B + (size_t)(n0 + r) * DD + k0 + c * 8, &Bs[buf][idx * 512]);
    }
  };
  stage(0, 0);
  asm volatile("s_waitcnt vmcnt(0)" ::: "memory");
  __syncthreads();
  const int T = DD / 64;
  for (int t = 0; t < T; ++t) {
    if (t > 0) {
      asm volatile("s_waitcnt vmcnt(0)" ::: "memory");
      __builtin_amdgcn_s_barrier();
      asm volatile("" ::: "memory");
    }
    if (t + 1 < T) stage(t + 1, (t + 1) & 1);
    const u16* Ab = As[t & 1];
    const u16* Bb = Bs[t & 1];
    const int xb = (((lane >> 4) ^ (lane & 7)) * 16);
    s16x8 af[4][2], bfr[4][2];
#pragma unroll
    for (int mf = 0; mf < 4; ++mf) {
      const char* p = (const char*)Ab + (wm * 64 + mf * 16 + (lane & 15)) * 128;
      af[mf][0] = *(const s16x8*)(p + xb);
      af[mf][1] = *(const s16x8*)(p + (xb ^ 64));
    }
#pragma unroll
    for (int nf = 0; nf < 4; ++nf) {
      const char* p = (const char*)Bb + (wn * 64 + nf * 16 + (lane & 15)) * 128;
      bfr[nf][0] = *(const s16x8*)(p + xb);
      bfr[nf][1] = *(const s16x8*)(p + (xb ^ 64));
    }
    __builtin_amdgcn_s_setprio(1);
#pragma unroll
    for (int ks = 0; ks < 2; ++ks)
#pragma unroll
      for (int mf = 0; mf < 4; ++mf)
#pragma unroll
        for (int nf = 0; nf < 4; ++nf)
          acc[mf][nf] = MFMA16(af[mf][ks], bfr[nf][ks], acc[mf][nf]);
    __builtin_amdgcn_s_setprio(0);
  }
  if (n0 < 2 * DD) {
    // Q/K tiles: normal row-major qkvb write
#pragma unroll
    for (int mf = 0; mf < 4; ++mf)
#pragma unroll
      for (int rr = 0; rr < 4; ++rr) {
        const int row = m0 + wm * 64 + mf * 16 + (lane >> 4) * 4 + rr;
#pragma unroll
        for (int nf = 0; nf < 4; ++nf) {
          const int col = n0 + wn * 64 + nf * 16 + (lane & 15);
          C[(size_t)row * D3 + col] = f2bf(acc[mf][nf][rr] + bias[col]);
        }
      }
  } else {
    // V tiles: transpose through LDS and write Vt[b][h][d][token] coalesced
    u16* tbuf = (u16*)&As[0][0];     // 32 KB = 128x128 u16
    __syncthreads();                 // all K-loop LDS reads complete
#pragma unroll
    for (int mf = 0; mf < 4; ++mf)
#pragma unroll
      for (int rr = 0; rr < 4; ++rr) {
        const int row = wm * 64 + mf * 16 + (lane >> 4) * 4 + rr;   // token-local
#pragma unroll
        for (int nf = 0; nf < 4; ++nf) {
          const int col = wn * 64 + nf * 16 + (lane & 15);          // channel-local
          tbuf[col * 128 + row] = f2bf(acc[mf][nf][rr] + bias[n0 + col]);
        }
      }
    __syncthreads();
    const int b = m0 >> 10, s0 = m0 & 1023;
    const int cv0 = n0 - 2 * DD;
    const int rowl = tid >> 1, half = tid & 1;   // 128 channel-rows x 2 halves
    const int cv = cv0 + rowl;
    const int h = cv >> 6, dch = cv & 63;
    const u16* srcp = tbuf + rowl * 128 + half * 64;
    u16* dstp = Vt + ((size_t)(b * HH + h) * HDIM + dch) * SS + s0 + half * 64;
#pragma unroll
    for (int i = 0; i < 8; ++i)
      *(u16x8*)(dstp + i * 8) = *(const u16x8*)(srcp + i * 8);
  }
}

// ---------------- out proj: ring-3 (r11, passed); f32 out + bf16 scatter to x2g ----------------
__global__ __launch_bounds__(256) void out_kernel(const u16* __restrict__ A, const u16* __restrict__ B,
                           const float* __restrict__ bias, const float* __restrict__ resid,
                           float* __restrict__ C, u16* __restrict__ x2g,
                           const int* __restrict__ inv) {
  const int n0 = blockIdx.x * 64, m0 = blockIdx.y * 128;
  const int tid = threadIdx.x, lane = tid & 63, w = tid >> 6;
  const int wm = w >> 1, wn = w & 1;
  __shared__ u16 As[3][128 * 64];
  __shared__ u16 Bs[3][64 * 64];
  f32x4 acc[4][2];
#pragma unroll
  for (int i = 0; i < 4; ++i)
#pragma unroll
    for (int j = 0; j < 2; ++j) acc[i][j] = f32x4{0.f, 0.f, 0.f, 0.f};
  auto stage = [&](int t, int buf) {
    const int k0 = t * 64;
#pragma unroll
    for (int q = 0; q < 4; ++q) {
      const int idx = w * 4 + q, r = idx * 8 + (lane >> 3), c = (lane & 7) ^ (r & 7);
      GLOAD16(A + (size_t)(m0 + r) * DD + k0 + c * 8, &As[buf][idx * 512]);
    }
#pragma unroll
    for (int q = 0; q < 2; ++q) {
      const int idx = w * 2 + q, r = idx * 8 + (lane >> 3), c = (lane & 7) ^ (r & 7);
      GLOAD16(B + (size_t)(n0 + r) * DD + k0 + c * 8, &Bs[buf][idx * 512]);
    }
  };
  stage(0, 0);
  stage(1, 1);
  const int T = DD / 64;
  for (int t = 0; t < T; ++t) {
    if (t + 1 < T) asm volatile("s_waitcnt vmcnt(6)" ::: "memory");
    else           asm volatile("s_waitcnt vmcnt(0)" ::: "memory");
    __builtin_amdgcn_s_barrier();
    asm volatile("" ::: "memory");
    if (t + 2 < T) stage(t + 2, (t + 2) % 3);
    const u16* Ab = As[t % 3];
    const u16* Bb = Bs[t % 3];
    const int xb = (((lane >> 4) ^ (lane & 7)) * 16);
    s16x8 af[4][2], bfr[2][2];
#pragma unroll
    for (int mf = 0; mf < 4; ++mf) {
      const char* p = (const char*)Ab + (wm * 64 + mf * 16 + (lane & 15)) * 128;
      af[mf][0] = *(const s16x8*)(p + xb);
      af[mf][1] = *(const s16x8*)(p + (xb ^ 64));
    }
#pragma unroll
    for (int nf = 0; nf < 2; ++nf) {
      const char* p = (const char*)Bb + (wn * 32 + nf * 16 + (lane & 15)) * 128;
      bfr[nf][0] = *(const s16x8*)(p + xb);
      bfr[nf][1] = *(const s16x8*)(p + (xb ^ 64));
    }
    __builtin_amdgcn_s_setprio(1);
#pragma unroll
    for (int ks = 0; ks < 2; ++ks)
#pragma unroll
      for (int mf = 0; mf < 4; ++mf)
#pragma unroll
        for (int nf = 0; nf < 2; ++nf)
          acc[mf][nf] = MFMA16(af[mf][ks], bfr[nf][ks], acc[mf][nf]);
    __builtin_amdgcn_s_setprio(0);
  }
#pragma unroll
  for (int mf = 0; mf < 4; ++mf)
#pragma unroll
    for (int rr = 0; rr < 4; ++rr) {
      const int row = m0 + wm * 64 + mf * 16 + (lane >> 4) * 4 + rr;
      const int slot = inv[row];
#pragma unroll
      for (int nf = 0; nf < 2; ++nf) {
        const int col = n0 + wn * 32 + nf * 16 + (lane & 15);
        const float v = acc[mf][nf][rr] + bias[col] + resid[(size_t)row * DD + col];
        C[(size_t)row * DD + col] = v;
        x2g[(size_t)slot * DD + col] = f2bf(v);
      }
    }
}

// ---------------- MFMA flash attention: 128 q x (b,h) per block, 8 waves x 16 q ----------------
__global__ __launch_bounds__(512) void attn_kernel(const u16* __restrict__ qkv,
                                                   const u16* __restrict__ Vt,
                                                   u16* __restrict__ ctx) {
  const int q0 = blockIdx.x * 128, h = blockIdx.y, b = blockIdx.z;
  const int tid = threadIdx.x, lane = tid & 63, w = tid >> 6;
  const int q15 = lane & 15, g = lane >> 4, l7 = lane & 7;
  __shared__ u16 Q_lds[128 * 64];
  __shared__ u16 K_lds[2][64 * 64];
  __shared__ u16 V_lds[2][64 * 64];
  __shared__ u16 P_lds[8][16 * 72];
  __shared__ float s_lds[8][16];

#pragma unroll
  for (int q2 = 0; q2 < 2; ++q2) {
    const int idx = w * 2 + q2;
    const int r = idx * 8 + (lane >> 3);
    const int c = l7 ^ (r & 7);
    GLOAD16(qkv + (size_t)(b * SS + q0 + r) * D3 + h * HDIM + c * 8, &Q_lds[idx * 512]);
  }
  auto stageK = [&](int buf, int kt) {
    const int r = w * 8 + (lane >> 3);
    const int c = l7 ^ (r & 7);
    GLOAD16(qkv + (size_t)(b * SS + kt * 64 + r) * D3 + DD + h * HDIM + c * 8,
            &K_lds[buf][w * 512]);
  };
  auto stageV = [&](int buf, int kt) {
    const int r = w * 8 + (lane >> 3);
    const int c = l7 ^ (r & 7);
    GLOAD16(Vt + ((size_t)(b * HH + h) * HDIM + r) * SS + kt * 64 + c * 8,
            &V_lds[buf][w * 512]);
  };
  stageK(0, 0);
  stageV(0, 0);
  asm volatile("s_waitcnt vmcnt(0)" ::: "memory");
  __syncthreads();
  s16x8 bq[2];
#pragma unroll
  for (int ks = 0; ks < 2; ++ks)
    bq[ks] = *(const s16x8*)((const char*)Q_lds + (w * 16 + q15) * 128 + ((4 * ks + g) ^ l7) * 16);
  f32x4 oacc[4];
#pragma unroll
  for (int nf = 0; nf < 4; ++nf) oacc[nf] = f32x4{0.f, 0.f, 0.f, 0.f};
  float mrun = -3.0e38f, lrun = 0.0f;
  int buf = 0;
  for (int kt = 0; kt < 16; ++kt) {
    if (kt < 15) { stageK(buf ^ 1, kt + 1); stageV(buf ^ 1, kt + 1); }
    f32x4 st[4];
#pragma unroll
    for (int mf = 0; mf < 4; ++mf) st[mf] = f32x4{0.f, 0.f, 0.f, 0.f};
#pragma unroll
    for (int ks = 0; ks < 2; ++ks) {
#pragma unroll
      for (int mf = 0; mf < 4; ++mf) {
        const s16x8 ka = *(const s16x8*)((const char*)K_lds[buf] + (mf * 16 + q15) * 128 +
                                         ((4 * ks + g) ^ l7) * 16);
        st[mf] = MFMA16(ka, bq[ks], st[mf]);
      }
    }
    float t0[4][4];
    float cmax = -3.0e38f;
#pragma unroll
    for (int mf = 0; mf < 4; ++mf)
#pragma unroll
      for (int r = 0; r < 4; ++r) {
        const float v = st[mf][r] * 0.125f;
        t0[mf][r] = v;
        cmax = fmaxf(cmax, v);
      }
    cmax = fmaxf(cmax, __shfl_xor(cmax, 16));
    cmax = fmaxf(cmax, __shfl_xor(cmax, 32));
    const float mnew = fmaxf(mrun, cmax);
    const float scf = __expf(mrun - mnew);
    float psum = 0.f;
#pragma unroll
    for (int mf = 0; mf < 4; ++mf)
#pragma unroll
      for (int r = 0; r < 4; ++r) {
        const float p = __expf(t0[mf][r] - mnew);
        t0[mf][r] = p;
        psum += p;
      }
    psum += __shfl_xor(psum, 16);
    psum += __shfl_xor(psum, 32);
    lrun = lrun * scf + psum;
    mrun = mnew;
    s_lds[w][q15] = scf;
    u16* pw = &P_lds[w][0];
#pragma unroll
    for (int mf = 0; mf < 4; ++mf) {
      u32x2 pk;
      pk[0] = (unsigned)f2bf(t0[mf][0]) | ((unsigned)f2bf(t0[mf][1]) << 16);
      pk[1] = (unsigned)f2bf(t0[mf][2]) | ((unsigned)f2bf(t0[mf][3]) << 16);
      *(u32x2*)(pw + q15 * 72 + mf * 16 + g * 4) = pk;
    }
    asm volatile("s_waitcnt lgkmcnt(0)" ::: "memory");
    const f32x4 scv = *(const f32x4*)&s_lds[w][g * 4];
#pragma unroll
    for (int nf = 0; nf < 4; ++nf)
#pragma unroll
      for (int r = 0; r < 4; ++r) oacc[nf][r] *= scv[r];
#pragma unroll
    for (int ks = 0; ks < 2; ++ks) {
      const s16x8 pa = *(const s16x8*)(pw + q15 * 72 + ks * 32 + g * 8);
#pragma unroll
      for (int nf = 0; nf < 4; ++nf) {
        const s16x8 bv = *(const s16x8*)((const char*)V_lds[buf] + (nf * 16 + q15) * 128 +
                                         ((4 * ks + g) ^ l7) * 16);
        oacc[nf] = MFMA16(pa, bv, oacc[nf]);
      }
    }
    asm volatile("s_waitcnt vmcnt(0)" ::: "memory");
    __syncthreads();
    buf ^= 1;
  }
  const float linv = 1.0f / lrun;
  s_lds[w][q15] = linv;
  asm volatile("s_waitcnt lgkmcnt(0)" ::: "memory");
  const f32x4 lv = *(const f32x4*)&s_lds[w][g * 4];
#pragma unroll
  for (int nf = 0; nf < 4; ++nf)
#pragma unroll
    for (int r = 0; r < 4; ++r) {
      const int qg = q0 + w * 16 + g * 4 + r;
      ctx[(size_t)(b * SS + qg) * DD + h * HDIM + nf * 16 + q15] = f2bf(oacc[nf][r] * lv[r]);
    }
}

// ---------------- routing (single launch): counts, offsets, slot-pack, inverse ----------------
__global__ void routing_kernel(const int* __restrict__ gid, int* __restrict__ cnts_g,
                               int* __restrict__ off_g, int* __restrict__ gidx,
                               int* __restrict__ inv) {
  __shared__ int cnt[GG];
  __shared__ int off[GG + 1];
  const int tid = threadIdx.x;  // 1024 threads
  if (tid < GG) cnt[tid] = 0;
  __syncthreads();
  const int t0 = tid, t1 = tid + 1024;
  const int g0 = gid[t0], g1 = gid[t1];
  const int s0 = atomicAdd(&cnt[g0], 1);
  const int s1 = atomicAdd(&cnt[g1], 1);
  __syncthreads();
  if (tid == 0) {
    int s = 0;
#pragma unroll
    for (int g = 0; g < GG; ++g) { off[g] = s; s += cnt[g]; }
    off[GG] = s;
  }
  __syncthreads();
  const int sg0 = off[g0] + s0;
  gidx[sg0] = t0; inv[t0] = sg0;
  const int sg1 = off[g1] + s1;
  gidx[sg1] = t1; inv[t1] = sg1;
  if (tid < GG) cnts_g[tid] = cnt[tid];
  if (tid <= GG) off_g[tid] = off[tid];
}

// ---------------- MoE GEMM1 v2: 128x128 tile, dbuf-2 ----------------
__global__ __launch_bounds__(256) void moe1_kernel(const u16* __restrict__ x2g, const u16* __restrict__ w1t,
                            const float* __restrict__ e_b1, const int* __restrict__ off,
                            const int* __restrict__ cnts, u16* __restrict__ h1) {
  const int ge = blockIdx.z, g = ge >> 1, e = ge & 1;
  const int cnt = cnts[g];
  const int m0 = blockIdx.y * 128;
  if (m0 >= cnt) return;
  const int base = off[g];
  const int n0 = blockIdx.x * 128;
  const u16* A = x2g + (size_t)base * DD;       // contiguous rows of this group
  const u16* B = w1t + (size_t)ge * HIDN * DD;  // [HID][D]
  const int tid = threadIdx.x, lane = tid & 63, w = tid >> 6;
  const int wm = w >> 1, wn = w & 1;
  __shared__ u16 As[2][128 * 64];
  __shared__ u16 Bs[2][128 * 64];
  f32x4 acc[4][4];
#pragma unroll
  for (int i = 0; i < 4; ++i)
#pragma unroll
    for (int j = 0; j < 4; ++j) acc[i][j] = f32x4{0.f, 0.f, 0.f, 0.f};
  auto stage = [&](int t, int buf) {
    const int k0 = t * 64;
#pragma unroll
    for (int q = 0; q < 4; ++q) {
      const int idx = w * 4 + q, r = idx * 8 + (lane >> 3), c = (lane & 7) ^ (r & 7);
      int rg = m0 + r; if (rg > cnt - 1) rg = cnt - 1;
      GLOAD16(A + (size_t)rg * DD + k0 + c * 8, &As[buf][idx * 512]);
    }
#pragma unroll
    for (int q = 0; q < 4; ++q) {
      const int idx = w * 4 + q, r = idx * 8 + (lane >> 3), c = (lane & 7) ^ (r & 7);
      GLOAD16(B + (size_t)(n0 + r) * DD + k0 + c * 8, &Bs[buf][idx * 512]);
    }
  };
  stage(0, 0);
  asm volatile("s_waitcnt vmcnt(0)" ::: "memory");
  __syncthreads();
  const int T = DD / 64;
  for (int t = 0; t < T; ++t) {
    if (t > 0) {
      asm volatile("s_waitcnt vmcnt(0)" ::: "memory");
      __builtin_amdgcn_s_barrier();
      asm volatile("" ::: "memory");
    }
    if (t + 1 < T) stage(t + 1, (t + 1) & 1);
    const u16* Ab = As[t & 1];
    const u16* Bb = Bs[t & 1];
    const int xb = (((lane >> 4) ^ (lane & 7)) * 16);
    s16x8 af[4][2], bfr[4][2];
#pragma unroll
    for (int mf = 0; mf < 4; ++mf) {
      const char* p = (const char*)Ab + (wm * 64 + mf * 16 + (lane & 15)) * 128;
      af[mf][0] = *(const s16x8*)(p + xb);
      af[mf][1] = *(const s16x8*)(p + (xb ^ 64));
    }
#pragma unroll
    for (int nf = 0; nf < 4; ++nf) {
      const char* p = (const char*)Bb + (wn * 64 + nf * 16 + (lane & 15)) * 128;
      bfr[nf][0] = *(const s16x8*)(p + xb);
      bfr[nf][1] = *(const s16x8*)(p + (xb ^ 64));
    }
    __builtin_amdgcn_s_setprio(1);
#pragma unroll
    for (int ks = 0; ks < 2; ++ks)
#pragma unroll
      for (int mf = 0; mf < 4; ++mf)
#pragma unroll
        for (int nf = 0; nf < 4; ++nf)
          acc[mf][nf] = MFMA16(af[mf][ks], bfr[nf][ks], acc[mf][nf]);
    __builtin_amdgcn_s_setprio(0);
  }
  const float* b1 = e_b1 + (size_t)ge * HIDN;
#pragma unroll
  for (int mf = 0; mf < 4; ++mf)
#pragma unroll
    for (int rr = 0; rr < 4; ++rr) {
      const int rowg = m0 + wm * 64 + mf * 16 + (lane >> 4) * 4 + rr;
      if (rowg < cnt) {
        u16* orow = h1 + ((size_t)e * NTOK + base + rowg) * HIDN;  // slot-ordered
#pragma unroll
        for (int nf = 0; nf < 4; ++nf) {
          const int col = n0 + wn * 64 + nf * 16 + (lane & 15);
          orow[col] = f2bf(gelu_f(acc[mf][nf][rr] + b1[col]));
        }
      }
    }
}

// ---------------- MoE GEMM2 v2: 8 waves = 2m x 2n x 2ks (conv-style K-split), ring-3 ----------------
// 512 threads -> 2 waves/SIMD at 1 block/CU (was 1/SIMD). Each ks-wave takes one K=32 half of
// every staged 64-step (xb ^ ksid*64 on both operands); f32 pair-reduction through LDS (conv
// v7's proven swizzled-scr exchange), ks0 waves do the final write. 3 gloads/wave/stage.
__global__ __launch_bounds__(512) void moe2_kernel(const u16* __restrict__ h1, const u16* __restrict__ w2t,
                            const float* __restrict__ e_b2, const int* __restrict__ off,
                            const int* __restrict__ cnts, const int* __restrict__ gidx,
                            const float* __restrict__ x2, float* __restrict__ outp) {
  const int g = blockIdx.z;
  const int cnt = cnts[g];
  const int m0 = blockIdx.y * 128;
  if (m0 >= cnt) return;
  const int base = off[g];
  const int n0 = blockIdx.x * 64;
  const int tid = threadIdx.x, lane = tid & 63, w = tid >> 6;
  const int wm = (w >> 2) & 1, wn = (w >> 1) & 1, ksid = w & 1;
  const int q15 = lane & 15, gq = lane >> 4;
  __shared__ __align__(16) u16 As[3][128 * 64];
  __shared__ __align__(16) u16 Bs[3][64 * 64];
  f32x4 acc[4][2];
#pragma unroll
  for (int i = 0; i < 4; ++i)
#pragma unroll
    for (int j = 0; j < 2; ++j) acc[i][j] = f32x4{0.f, 0.f, 0.f, 0.f};
  auto stage = [&](int t, int buf) {
    const int e = t >> 5;
    const int k0 = (t & 31) * 64;
#pragma unroll
    for (int q = 0; q < 2; ++q) {
      const int idx = w * 2 + q, r = idx * 8 + (lane >> 3), c = (lane & 7) ^ (r & 7);
      int rg = m0 + r; if (rg > cnt - 1) rg = cnt - 1;
      GLOAD16(h1 + ((size_t)e * NTOK + base + rg) * HIDN + k0 + c * 8, &As[buf][idx * 512]);
    }
    {
      const int r = w * 8 + (lane >> 3), c = (lane & 7) ^ (r & 7);
      GLOAD16(w2t + ((size_t)(g * EE + e) * DD + n0 + r) * HIDN + k0 + c * 8, &Bs[buf][w * 512]);
    }
  };
  stage(0, 0);
  stage(1, 1);
  const int T = 64;
  const int kx = ksid * 64;
  for (int t = 0; t < T; ++t) {
    if (t + 1 < T) asm volatile("s_waitcnt vmcnt(3)" ::: "memory");
    else           asm volatile("s_waitcnt vmcnt(0)" ::: "memory");
    __builtin_amdgcn_s_barrier();
    asm volatile("" ::: "memory");
    if (t + 2 < T) stage(t + 2, (t + 2) % 3);
    const u16* Ab = As[t % 3];
    const u16* Bb = Bs[t % 3];
    const int xb = ((((lane >> 4) ^ (lane & 7)) * 16) ^ kx);
    s16x8 af[4], bfr[2];
#pragma unroll
    for (int mf = 0; mf < 4; ++mf) {
      const char* p = (const char*)Ab + (wm * 64 + mf * 16 + q15) * 128;
      af[mf] = *(const s16x8*)(p + xb);
    }
#pragma unroll
    for (int nf = 0; nf < 2; ++nf) {
      const char* p = (const char*)Bb + (wn * 32 + nf * 16 + q15) * 128;
      bfr[nf] = *(const s16x8*)(p + xb);
    }
    __builtin_amdgcn_s_setprio(1);
#pragma unroll
    for (int mf = 0; mf < 4; ++mf)
#pragma unroll
      for (int nf = 0; nf < 2; ++nf)
        acc[mf][nf] = MFMA16(af[mf], bfr[nf], acc[mf][nf]);
    __builtin_amdgcn_s_setprio(0);
  }
  // ---- ks-pair reduction (conv-pattern): ks1 stashes f32 acc, ks0 sums + writes ----
  __syncthreads();
  float* scr = (float*)&As[0][0] + (wm * 2 + wn) * 2048;   // 32col x 64row f32 per pair
  if (ksid == 1) {
#pragma unroll
    for (int mf = 0; mf < 4; ++mf)
#pragma unroll
      for (int nf = 0; nf < 2; ++nf) {
        const int col = nf * 16 + q15;
        *(f32x4*)&scr[col * 64 + ((mf * 16 + gq * 4) ^ ((col & 7) << 3))] = acc[mf][nf];
      }
  }
  __syncthreads();
  if (ksid == 0) {
    const float* b20 = e_b2 + (size_t)(g * EE + 0) * DD;
    const float* b21 = e_b2 + (size_t)(g * EE + 1) * DD;
#pragma unroll
    for (int mf = 0; mf < 4; ++mf) {
      f32x4 sum[2];
#pragma unroll
      for (int nf = 0; nf < 2; ++nf) {
        const int col = nf * 16 + q15;
        const f32x4 o = *(const f32x4*)&scr[col * 64 + ((mf * 16 + gq * 4) ^ ((col & 7) << 3))];
        sum[nf] = acc[mf][nf] + o;
      }
#pragma unroll
      for (int rr = 0; rr < 4; ++rr) {
        const int rowg = m0 + wm * 64 + mf * 16 + gq * 4 + rr;
        if (rowg < cnt) {
          const int tok = gidx[base + rowg];
#pragma unroll
          for (int nf = 0; nf < 2; ++nf) {
            const int col = n0 + wn * 32 + nf * 16 + q15;
            outp[(size_t)tok * DD + col] =
                0.5f * sum[nf][rr] + 0.5f * (b20[col] + b21[col]) + x2[(size_t)tok * DD + col];
          }
        }
      }
    }
  }
}

extern "C" void kernel_launch(void* const* d_in, const int* in_sizes, int n_in,
                              void* d_out, int out_size, void* d_ws, size_t ws_size,
                              hipStream_t stream) {
  (void)in_sizes; (void)n_in; (void)out_size; (void)ws_size;
  const float* x      = (const float*)d_in[0];
  const int*   gid    = (const int*)d_in[1];
  const float* cn_g   = (const float*)d_in[2];
  const float* cn_b   = (const float*)d_in[3];
  const float* conv_w = (const float*)d_in[4];
  const float* conv_b = (const float*)d_in[5];
  const float* an_g   = (const float*)d_in[6];
  const float* an_b   = (const float*)d_in[7];
  const float* in_w   = (const float*)d_in[8];
  const float* in_b   = (const float*)d_in[9];
  const float* out_w  = (const float*)d_in[10];
  const float* out_b  = (const float*)d_in[11];
  const float* e_w1   = (const float*)d_in[12];
  const float* e_b1   = (const float*)d_in[13];
  const float* e_w2   = (const float*)d_in[14];
  const float* e_b2   = (const float*)d_in[15];
  float* outp = (float*)d_out;

  // ---- workspace map (high-water 74MB + ~41KB, identical to r5-r13 pass) ----
  char* wsp = (char*)d_ws;
  u16*   hb    = (u16*)(wsp);                         // 0..4M  (ln/combine out; ctxb reuse)
  u16*   Pc    = (u16*)(wsp + (4ull << 20));          // 4..12M (conv partials x2, conv phase)
  float* x1    = (float*)(wsp + (12ull << 20));       // 12..20M (combine out)
  u16*   Wb    = (u16*)(wsp + (12ull << 20));         // 12..74M (conv phase only)
  u16*   qkvb  = (u16*)(wsp + (24ull << 20));         // 24..36M (qkv->attn; Q/K only)
  u16*   inwb  = (u16*)(wsp + (40ull << 20));         // 40..46M (qkv phase)
  u16*   outwb = (u16*)(wsp + (40ull << 20));         // 40..42M (out phase, after qkv)
  u16*   Vt    = (u16*)(wsp + (46ull << 20));         // 46..50M (attn phase; written by qkv)
  u16*   ctxb  = hb;                                  // 0..4M  (after qkv)
  float* x2    = (float*)(wsp + (52ull << 20));       // 52..60M
  int*   inv   = (int*)(wsp + (60ull << 20));         // 60M.. 8KB (tok->slot; written post-conv)
  u16*   x2g   = (u16*)(wsp + (64ull << 20));         // 64..68M (slot-packed tokens)
  u16*   wgt   = (u16*)(wsp + (4ull << 20));          // 4..36M (w1t, then w2t; MoE phase)
  u16*   h1    = (u16*)(wsp + (36ull << 20));         // 36..52M (MoE phase, slot-ordered)
  int*   gat   = (int*)(wsp + (74ull << 20));         // 32KB (unused; kept for layout stability)
  int*   cnts  = gat + GG * NTOK;                     // 16B
  int*   offp  = cnts + GG;                           // 20B
  int*   gidx  = offp + (GG + 1);                     // 8KB

  // ---- conv block (v7, measured 179us) ----
  ln_kernel<<<NTOK, 256, 0, stream>>>(x, cn_g, cn_b, hb);
  prep_convw<<<1024, 256, 0, stream>>>(conv_w, Wb);
  conv_kernel<<<256, 512, 0, stream>>>(hb, Wb, Pc);
  // combine + attention-LN fused (writes x1 and hb)
  combine_kernel<<<NTOK, 256, 0, stream>>>(Pc, conv_b, x, an_g, an_b, x1, hb);
  // ---- routing, single launch (Wb dead; inv lives in its hole) ----
  routing_kernel<<<1, 1024, 0, stream>>>(gid, cnts, offp, gidx, inv);
  // ---- attention block (qkv writes Vt directly for V n-tiles; no vtr) ----
  cvt_kernel<<<3072, 256, 0, stream>>>(in_w, inwb, 3 * DD * DD / 4);
  qkv_kernel<<<dim3(D3 / 128, NTOK / 128), 256, 0, stream>>>(hb, inwb, in_b, qkvb, Vt);
  attn_kernel<<<dim3(SS / 128, HH, BB), 512, 0, stream>>>(qkvb, Vt, ctxb);
  cvt_kernel<<<1024, 256, 0, stream>>>(out_w, outwb, DD * DD / 4);
  out_kernel<<<dim3(DD / 64, NTOK / 128), 256, 0, stream>>>(ctxb, outwb, out_b, x1, x2, x2g, inv);
  // ---- MoE (slot-packed + dense-fastest grids: all 8 XCDs active) ----
  tr_kernel<<<dim3(HIDN / 32, DD / 32, GG * EE), 256, 0, stream>>>(e_w1, wgt, DD, HIDN);
  moe1_kernel<<<dim3(HIDN / 128, NTOK / 128, GG * EE), 256, 0, stream>>>(x2g, wgt, e_b1, offp, cnts, h1);
  tr_kernel<<<dim3(DD / 32, HIDN / 32, GG * EE), 256, 0, stream>>>(e_w2, wgt, HIDN, DD);
  moe2_kernel<<<dim3(DD / 64, NTOK / 128, GG), 512, 0, stream>>>(h1, wgt, e_b2, offp, cnts, gidx, x2, outp);
}

// Round 15
// 410.115 us; speedup vs baseline: 1.3631x; 1.1365x over previous
//
#include <hip/hip_runtime.h>
#include <hip/hip_bf16.h>
#include <math.h>

#define BB 2
#define SS 1024
#define DD 1024
#define HH 16
#define HDIM 64
#define KK 31
#define GG 4
#define EE 2
#define HIDN 2048
#define NTOK (BB*SS)
#define D3 (3*DD)

typedef unsigned short u16;
typedef __attribute__((ext_vector_type(8))) short s16x8;
typedef __attribute__((ext_vector_type(8))) unsigned short u16x8;
typedef __attribute__((ext_vector_type(4))) unsigned short u16x4;
typedef __attribute__((ext_vector_type(2))) unsigned short u16x2;
typedef __attribute__((ext_vector_type(4))) float f32x4;
typedef __attribute__((ext_vector_type(2))) unsigned int u32x2;

__device__ __forceinline__ float gelu_f(float x) {
  return 0.5f * x * (1.0f + erff(x * 0.7071067811865475f));
}
__device__ __forceinline__ u16 f2bf(float f) {
  unsigned u = __builtin_bit_cast(unsigned, f);
  u = (u + 0x7fffu + ((u >> 16) & 1u)) >> 16;
  return (u16)u;
}
__device__ __forceinline__ float bf2f(u16 u) {
  return __builtin_bit_cast(float, ((unsigned)u) << 16);
}
__device__ __forceinline__ f32x4 MFMA16(s16x8 a, s16x8 b, f32x4 c) {
  return __builtin_amdgcn_mfma_f32_16x16x32_bf16(a, b, c, 0, 0, 0);
}
#define GLOAD16(gp, lp) __builtin_amdgcn_global_load_lds( \
    (const __attribute__((address_space(1))) void*)(gp),  \
    (__attribute__((address_space(3))) void*)(lp), 16, 0, 0)

// ---------------- LayerNorm: fp32 in -> bf16 out, one block per row ----------------
__global__ void ln_kernel(const float* __restrict__ x, const float* __restrict__ g,
                          const float* __restrict__ b, u16* __restrict__ out) {
  const int row = blockIdx.x;
  const int tid = threadIdx.x;
  __shared__ float red[4];
  const float4 v = reinterpret_cast<const float4*>(x + (size_t)row * DD)[tid];
  float s = v.x + v.y + v.z + v.w;
  s += __shfl_down(s, 32); s += __shfl_down(s, 16); s += __shfl_down(s, 8);
  s += __shfl_down(s, 4);  s += __shfl_down(s, 2);  s += __shfl_down(s, 1);
  if ((tid & 63) == 0) red[tid >> 6] = s;
  __syncthreads();
  const float mean = (red[0] + red[1] + red[2] + red[3]) * (1.0f / DD);
  __syncthreads();
  const float4 d = make_float4(v.x - mean, v.y - mean, v.z - mean, v.w - mean);
  float sq = d.x*d.x + d.y*d.y + d.z*d.z + d.w*d.w;
  sq += __shfl_down(sq, 32); sq += __shfl_down(sq, 16); sq += __shfl_down(sq, 8);
  sq += __shfl_down(sq, 4);  sq += __shfl_down(sq, 2);  sq += __shfl_down(sq, 1);
  if ((tid & 63) == 0) red[tid >> 6] = sq;
  __syncthreads();
  const float var = (red[0] + red[1] + red[2] + red[3]) * (1.0f / DD);
  const float rstd = rsqrtf(var + 1e-5f);
  const float4 gv = reinterpret_cast<const float4*>(g)[tid];
  const float4 bv = reinterpret_cast<const float4*>(b)[tid];
  u16x4 o;
  o[0] = f2bf(d.x * rstd * gv.x + bv.x);
  o[1] = f2bf(d.y * rstd * gv.y + bv.y);
  o[2] = f2bf(d.z * rstd * gv.z + bv.z);
  o[3] = f2bf(d.w * rstd * gv.w + bv.w);
  *reinterpret_cast<u16x4*>(out + (size_t)row * DD + tid * 4) = o;
}

// ---------------- conv weight reorder: conv_w[o][i][k] f32 -> Wb[k][o][i] bf16 ----------------
__global__ void prep_convw(const float* __restrict__ cw, u16* __restrict__ Wb) {
  const int o = blockIdx.x;
  const int i4 = threadIdx.x * 4;
  float wv[4][KK];
#pragma unroll
  for (int j = 0; j < 4; ++j) {
    const float* src = cw + ((size_t)o * DD + i4 + j) * KK;
#pragma unroll
    for (int k = 0; k < KK; ++k) wv[j][k] = src[k];
  }
#pragma unroll
  for (int k = 0; k < KK; ++k) {
    u16x4 o4;
    o4[0] = f2bf(wv[0][k]); o4[1] = f2bf(wv[1][k]);
    o4[2] = f2bf(wv[2][k]); o4[3] = f2bf(wv[3][k]);
    *(u16x4*)&Wb[((size_t)k * DD + o) * DD + i4] = o4;
  }
}

// ---------------- plain f32 -> bf16 convert ----------------
__global__ void cvt_kernel(const float* __restrict__ in, u16* __restrict__ outp, int n4) {
  const int i = blockIdx.x * 256 + threadIdx.x;
  if (i < n4) {
    const float4 v = reinterpret_cast<const float4*>(in)[i];
    u16x4 o; o[0] = f2bf(v.x); o[1] = f2bf(v.y); o[2] = f2bf(v.z); o[3] = f2bf(v.w);
    reinterpret_cast<u16x4*>(outp)[i] = o;
  }
}

// ---------------- transpose-convert: src[z][R][C] f32 -> dst[z][C][R] bf16, paired stores ----------------
__global__ void tr_kernel(const float* __restrict__ src, u16* __restrict__ dst, int R, int C) {
  __shared__ float tile[32][33];   // [r-local][c-local]
  const int c0 = blockIdx.x * 32, r0 = blockIdx.y * 32;
  const size_t base = (size_t)blockIdx.z * R * C;
  const int tx = threadIdx.x & 31, ty = threadIdx.x >> 5;  // ty 0..7
#pragma unroll
  for (int i = 0; i < 4; ++i)
    tile[ty + i * 8][tx] = src[base + (size_t)(r0 + ty + i * 8) * C + c0 + tx];
  __syncthreads();
  const int rx = threadIdx.x & 15, cy = threadIdx.x >> 4;  // cy 0..15
#pragma unroll
  for (int i = 0; i < 2; ++i) {
    const int c = cy + i * 16;
    u16x2 o2;
    o2[0] = f2bf(tile[2 * rx][c]);
    o2[1] = f2bf(tile[2 * rx + 1][c]);
    *(u16x2*)&dst[base + (size_t)(c0 + c) * R + r0 + 2 * rx] = o2;
  }
}

// ---------------- conv via MFMA v9: 2 blocks/CU (68KB LDS), 512 blocks, shared B ring-3 ----------------
// v7 plateau diagnosis: 1737 cyc/tap vs ~580 L2-feed floor at 1 block/CU -> DMA-latency bound,
// no co-resident work to hide it. v9: grid 512 (z = i-quarter x4, f32 partials), LDS 68KB
// (Ad single 20KB reloaded per slice behind dbl-barrier; Bs SHARED dedup ring-3 48KB) ->
// 2 blocks/CU, 4 waves/SIMD. Sync = r11-proven counted vmcnt(2) -> barrier -> stage(t+2).
__global__ __launch_bounds__(512, 4) void conv_kernel(const u16* __restrict__ hb,
                                                      const u16* __restrict__ Wb,
                                                      float* __restrict__ P) {
  const int L = blockIdx.x;            // 0..511
  const int o_t = L & 7;               // o-tile pinned per XCD (B L2 reuse)
  const int rest = L >> 3;             // 0..63
  const int s_t = rest >> 2;           // 0..15
  const int z = rest & 3;              // i-quarter
  const int b = s_t >> 3, sloc = s_t & 7;
  const int s0l = sloc * 128;
  const int o0 = o_t * 128;
  const int ibase = z * 256;
  const int tid = threadIdx.x, lane = tid & 63, w = tid >> 6;
  const int wm = (w >> 2) & 1, wn = (w >> 1) & 1, ksid = w & 1;
  const int q15 = lane & 15, g = lane >> 4;
  __shared__ __align__(16) u16 Ad[160 * 64];     // 20 KB single buffer (reload per slice)
  __shared__ __align__(16) u16 Bs[3][128 * 64];  // 48 KB shared ring-3 (16KB slots)
  const int rlo = (sloc == 0) ? 15 : 0;
  const int rhi = (sloc == 7) ? 143 : 158;
  if (sloc == 0)
    for (int i = tid; i < 15 * 64; i += 512) Ad[i] = 0;
  if (sloc == 7)
    for (int i = tid; i < 17 * 64; i += 512) Ad[143 * 64 + i] = 0;
  auto stageA = [&](int i0) {
    for (int q = w; q < 20; q += 8) {
      const int r = q * 8 + (lane >> 3);
      const int c = (lane & 7) ^ (r & 7);
      if (r >= rlo && r < rhi)
        GLOAD16(hb + (size_t)(b * SS + s0l - 15 + r) * DD + i0 + c * 8, &Ad[q * 512]);
    }
  };
  auto stageB = [&](int slot, int k, int i0) {   // shared 128o x 64i, 2 gloads/wave
#pragma unroll
    for (int qq = 0; qq < 2; ++qq) {
      const int q = w * 2 + qq;
      const int r = q * 8 + (lane >> 3);
      const int c = (lane & 7) ^ (r & 7);
      GLOAD16(Wb + ((size_t)k * DD + o0 + r) * DD + i0 + c * 8, &Bs[slot][q * 512]);
    }
  };
  f32x4 acc[4][4];
#pragma unroll
  for (int i = 0; i < 4; ++i)
#pragma unroll
    for (int j = 0; j < 4; ++j) acc[i][j] = f32x4{0.f, 0.f, 0.f, 0.f};
  stageA(ibase);
  stageB(0, 0, ibase);
  stageB(1, 1, ibase);
  asm volatile("s_waitcnt vmcnt(0)" ::: "memory");
  __syncthreads();
  const int NSL = 4;
  const int T = NSL * KK;    // 124 taps
  const int kx = ksid * 64;  // byte XOR selecting this wave's K=32 half
  int t = 0;
  for (int i0i = 0; i0i < NSL; ++i0i) {
    for (int k = 0; k < KK; ++k, ++t) {
      // stage(t) drained when only the newest stage (2 loads) remains in flight
      if (t + 1 < T) asm volatile("s_waitcnt vmcnt(2)" ::: "memory");
      else           asm volatile("s_waitcnt vmcnt(0)" ::: "memory");
      __builtin_amdgcn_s_barrier();
      asm volatile("" ::: "memory");
      {  // AFTER barrier: slot (t+2)%3's previous readers (iter t-1) all done
        const int tn = t + 2;
        if (tn < T) stageB(tn % 3, tn % KK, ibase + (tn / KK) * 64);
      }
      s16x8 af[4];
      const int rk0 = wm * 64 + q15 + k;
#pragma unroll
      for (int mf = 0; mf < 4; ++mf) {
        const int rr = rk0 + mf * 16;
        const char* p = (const char*)Ad + rr * 128;
        af[mf] = *(const s16x8*)(p + (((g ^ (rr & 7)) * 16) ^ kx));
      }
      const u16* Bb = Bs[t % 3];
      s16x8 bfr[4];
#pragma unroll
      for (int nf = 0; nf < 4; ++nf) {
        const int rr = wn * 64 + nf * 16 + q15;
        const char* p = (const char*)Bb + rr * 128;
        bfr[nf] = *(const s16x8*)(p + (((g ^ (rr & 7)) * 16) ^ kx));
      }
      __builtin_amdgcn_s_setprio(1);
#pragma unroll
      for (int mf = 0; mf < 4; ++mf)
#pragma unroll
        for (int nf = 0; nf < 4; ++nf)
          acc[mf][nf] = MFMA16(af[mf], bfr[nf], acc[mf][nf]);
      __builtin_amdgcn_s_setprio(0);
    }
    if (i0i < NSL - 1) {   // slice boundary: single-Ad reload behind double barrier
      asm volatile("s_waitcnt vmcnt(0)" ::: "memory");
      __syncthreads();                       // all waves done reading Ad
      stageA(ibase + (i0i + 1) * 64);
      asm volatile("s_waitcnt vmcnt(0)" ::: "memory");
      __syncthreads();                       // new Ad visible to all
    }
  }
  // ---- ks-pair reduction: ks1 stashes f32 acc, ks0 sums + writes f32 partials ----
  __syncthreads();
  const int pair = wm * 2 + wn;
  float* scr = (pair < 3) ? ((float*)&Bs[pair][0]) : (float*)&Ad[0];  // 16KB each
  if (ksid == 1) {
#pragma unroll
    for (int mf = 0; mf < 4; ++mf)
#pragma unroll
      for (int nf = 0; nf < 4; ++nf) {
        const int col = nf * 16 + q15;
        *(f32x4*)&scr[col * 64 + ((mf * 16 + g * 4) ^ ((col & 7) << 3))] = acc[mf][nf];
      }
  }
  __syncthreads();
  if (ksid == 0) {
    float* Pz = P + (size_t)z * NTOK * DD;
#pragma unroll
    for (int mf = 0; mf < 4; ++mf) {
      f32x4 sum[4];
#pragma unroll
      for (int nf = 0; nf < 4; ++nf) {
        const int col = nf * 16 + q15;
        const f32x4 o = *(const f32x4*)&scr[col * 64 + ((mf * 16 + g * 4) ^ ((col & 7) << 3))];
        sum[nf] = acc[mf][nf] + o;
      }
#pragma unroll
      for (int r = 0; r < 4; ++r) {
        const int srow = s0l + wm * 64 + mf * 16 + g * 4 + r;
        float* orow = Pz + (size_t)(b * SS + srow) * DD + o0 + wn * 64;
#pragma unroll
        for (int nf = 0; nf < 4; ++nf)
          orow[nf * 16 + q15] = sum[nf][r];
      }
    }
  }
}

// ---------------- combine+LN fused: x1 = gelu(P0+P1+P2+P3+cb)+x ; hb = LN(x1)*an_g+an_b ----------------
__global__ void combine_kernel(const float* __restrict__ P, const float* __restrict__ cb,
                               const float* __restrict__ x, const float* __restrict__ an_g,
                               const float* __restrict__ an_b, float* __restrict__ x1,
                               u16* __restrict__ hb) {
  const int row = blockIdx.x;
  const int tid = threadIdx.x;
  const size_t base = (size_t)row * DD + tid * 4;
  const int col = tid * 4;
  __shared__ float red[4];
  float4 p = *(const float4*)(P + base);
#pragma unroll
  for (int zz = 1; zz < 4; ++zz) {
    const float4 q = *(const float4*)(P + (size_t)zz * NTOK * DD + base);
    p.x += q.x; p.y += q.y; p.z += q.z; p.w += q.w;
  }
  const float4 xv = *(const float4*)(x + base);
  const float4 cbv = *(const float4*)(cb + col);
  float4 v;
  v.x = gelu_f(p.x + cbv.x) + xv.x;
  v.y = gelu_f(p.y + cbv.y) + xv.y;
  v.z = gelu_f(p.z + cbv.z) + xv.z;
  v.w = gelu_f(p.w + cbv.w) + xv.w;
  *(float4*)(x1 + base) = v;
  float s = v.x + v.y + v.z + v.w;
  s += __shfl_down(s, 32); s += __shfl_down(s, 16); s += __shfl_down(s, 8);
  s += __shfl_down(s, 4);  s += __shfl_down(s, 2);  s += __shfl_down(s, 1);
  if ((tid & 63) == 0) red[tid >> 6] = s;
  __syncthreads();
  const float mean = (red[0] + red[1] + red[2] + red[3]) * (1.0f / DD);
  __syncthreads();
  const float4 d = make_float4(v.x - mean, v.y - mean, v.z - mean, v.w - mean);
  float sq = d.x*d.x + d.y*d.y + d.z*d.z + d.w*d.w;
  sq += __shfl_down(sq, 32); sq += __shfl_down(sq, 16); sq += __shfl_down(sq, 8);
  sq += __shfl_down(sq, 4);  sq += __shfl_down(sq, 2);  sq += __shfl_down(sq, 1);
  if ((tid & 63) == 0) red[tid >> 6] = sq;
  __syncthreads();
  const float var = (red[0] + red[1] + red[2] + red[3]) * (1.0f / DD);
  const float rstd = rsqrtf(var + 1e-5f);
  const float4 gv = reinterpret_cast<const float4*>(an_g)[tid];
  const float4 bv = reinterpret_cast<const float4*>(an_b)[tid];
  u16x4 o;
  o[0] = f2bf(d.x * rstd * gv.x + bv.x);
  o[1] = f2bf(d.y * rstd * gv.y + bv.y);
  o[2] = f2bf(d.z * rstd * gv.z + bv.z);
  o[3] = f2bf(d.w * rstd * gv.w + bv.w);
  *reinterpret_cast<u16x4*>(hb + (size_t)row * DD + tid * 4) = o;
}

// ---------------- qkv GEMM v3: 128x128 tile, dbuf-2; V n-tiles transpose-write Vt directly ----------------
__global__ __launch_bounds__(256) void qkv_kernel(const u16* __restrict__ A, const u16* __restrict__ B,
                           const float* __restrict__ bias, u16* __restrict__ C,
                           u16* __restrict__ Vt) {
  const int n0 = blockIdx.x * 128, m0 = blockIdx.y * 128;
  const int tid = threadIdx.x, lane = tid & 63, w = tid >> 6;
  const int wm = w >> 1, wn = w & 1;
  __shared__ __align__(16) u16 As[2][128 * 64];
  __shared__ __align__(16) u16 Bs[2][128 * 64];
  f32x4 acc[4][4];
#pragma unroll
  for (int i = 0; i < 4; ++i)
#pragma unroll
    for (int j = 0; j < 4; ++j) acc[i][j] = f32x4{0.f, 0.f, 0.f, 0.f};
  auto stage = [&](int t, int buf) {
    const int k0 = t * 64;
#pragma unroll
    for (int q = 0; q < 4; ++q) {
      const int idx = w * 4 + q, r = idx * 8 + (lane >> 3), c = (lane & 7) ^ (r & 7);
      GLOAD16(A + (size_t)(m0 + r) * DD + k0 + c * 8, &As[buf][idx * 512]);
    }
#pragma unroll
    for (int q = 0; q < 4; ++q) {
      const int idx = w * 4 + q, r = idx * 8 + (lane >> 3), c = (lane & 7) ^ (r & 7);
      GLOAD16(B + (size_t)(n0 + r) * DD + k0 + c * 8, &Bs[buf][idx * 512]);
    }
  };
  stage(0, 0);
  asm volatile("s_waitcnt vmcnt(0)" ::: "memory");
  __syncthreads();
  const int T = DD / 64;
  for (int t = 0; t < T; ++t) {
    if (t > 0) {
      asm volatile("s_waitcnt vmcnt(0)" ::: "memory");
      __builtin_amdgcn_s_barrier();
      asm volatile("" ::: "memory");
    }
    if (t + 1 < T) stage(t + 1, (t + 1) & 1);
    const u16* Ab = As[t & 1];
    const u16* Bb = Bs[t & 1];
    const int xb = (((lane >> 4) ^ (lane & 7)) * 16);
    s16x8 af[4][2], bfr[4][2];
#pragma unroll
    for (int mf = 0; mf < 4; ++mf) {
      const char* p = (const char*)Ab + (wm * 64 + mf * 16 + (lane & 15)) * 128;
      af[mf][0] = *(const s16x8*)(p + xb);
      af[mf][1] = *(const s16x8*)(p + (xb ^ 64));
    }
#pragma unroll
    for (int nf = 0; nf < 4; ++nf) {
      const char* p = (const char*)Bb + (wn * 64 + nf * 16 + (lane & 15)) * 128;
      bfr[nf][0] = *(const s16x8*)(p + xb);
      bfr[nf][1] = *(const s16x8*)(p + (xb ^ 64));
    }
    __builtin_amdgcn_s_setprio(1);
#pragma unroll
    for (int ks = 0; ks < 2; ++ks)
#pragma unroll
      for (int mf = 0; mf < 4; ++mf)
#pragma unroll
        for (int nf = 0; nf < 4; ++nf)
          acc[mf][nf] = MFMA16(af[mf][ks], bfr[nf][ks], acc[mf][nf]);
    __builtin_amdgcn_s_setprio(0);
  }
  if (n0 < 2 * DD) {
#pragma unroll
    for (int mf = 0; mf < 4; ++mf)
#pragma unroll
      for (int rr = 0; rr < 4; ++rr) {
        const int row = m0 + wm * 64 + mf * 16 + (lane >> 4) * 4 + rr;
#pragma unroll
        for (int nf = 0; nf < 4; ++nf) {
          const int col = n0 + wn * 64 + nf * 16 + (lane & 15);
          C[(size_t)row * D3 + col] = f2bf(acc[mf][nf][rr] + bias[col]);
        }
      }
  } else {
    u16* tbuf = (u16*)&As[0][0];     // 32 KB = 128x128 u16
    __syncthreads();                 // all K-loop LDS reads complete
#pragma unroll
    for (int mf = 0; mf < 4; ++mf)
#pragma unroll
      for (int rr = 0; rr < 4; ++rr) {
        const int row = wm * 64 + mf * 16 + (lane >> 4) * 4 + rr;   // token-local
#pragma unroll
        for (int nf = 0; nf < 4; ++nf) {
          const int col = wn * 64 + nf * 16 + (lane & 15);          // channel-local
          tbuf[col * 128 + row] = f2bf(acc[mf][nf][rr] + bias[n0 + col]);
        }
      }
    __syncthreads();
    const int b = m0 >> 10, s0 = m0 & 1023;
    const int cv0 = n0 - 2 * DD;
    const int rowl = tid >> 1, half = tid & 1;
    const int cv = cv0 + rowl;
    const int h = cv >> 6, dch = cv & 63;
    const u16* srcp = tbuf + rowl * 128 + half * 64;
    u16* dstp = Vt + ((size_t)(b * HH + h) * HDIM + dch) * SS + s0 + half * 64;
#pragma unroll
    for (int i = 0; i < 8; ++i)
      *(u16x8*)(dstp + i * 8) = *(const u16x8*)(srcp + i * 8);
  }
}

// ---------------- out proj: ring-3; f32 out + bf16 scatter to x2g ----------------
__global__ __launch_bounds__(256) void out_kernel(const u16* __restrict__ A, const u16* __restrict__ B,
                           const float* __restrict__ bias, const float* __restrict__ resid,
                           float* __restrict__ C, u16* __restrict__ x2g,
                           const int* __restrict__ inv) {
  const int n0 = blockIdx.x * 64, m0 = blockIdx.y * 128;
  const int tid = threadIdx.x, lane = tid & 63, w = tid >> 6;
  const int wm = w >> 1, wn = w & 1;
  __shared__ u16 As[3][128 * 64];
  __shared__ u16 Bs[3][64 * 64];
  f32x4 acc[4][2];
#pragma unroll
  for (int i = 0; i < 4; ++i)
#pragma unroll
    for (int j = 0; j < 2; ++j) acc[i][j] = f32x4{0.f, 0.f, 0.f, 0.f};
  auto stage = [&](int t, int buf) {
    const int k0 = t * 64;
#pragma unroll
    for (int q = 0; q < 4; ++q) {
      const int idx = w * 4 + q, r = idx * 8 + (lane >> 3), c = (lane & 7) ^ (r & 7);
      GLOAD16(A + (size_t)(m0 + r) * DD + k0 + c * 8, &As[buf][idx * 512]);
    }
#pragma unroll
    for (int q = 0; q < 2; ++q) {
      const int idx = w * 2 + q, r = idx * 8 + (lane >> 3), c = (lane & 7) ^ (r & 7);
      GLOAD16(B + (size_t)(n0 + r) * DD + k0 + c * 8, &Bs[buf][idx * 512]);
    }
  };
  stage(0, 0);
  stage(1, 1);
  const int T = DD / 64;
  for (int t = 0; t < T; ++t) {
    if (t + 1 < T) asm volatile("s_waitcnt vmcnt(6)" ::: "memory");
    else           asm volatile("s_waitcnt vmcnt(0)" ::: "memory");
    __builtin_amdgcn_s_barrier();
    asm volatile("" ::: "memory");
    if (t + 2 < T) stage(t + 2, (t + 2) % 3);
    const u16* Ab = As[t % 3];
    const u16* Bb = Bs[t % 3];
    const int xb = (((lane >> 4) ^ (lane & 7)) * 16);
    s16x8 af[4][2], bfr[2][2];
#pragma unroll
    for (int mf = 0; mf < 4; ++mf) {
      const char* p = (const char*)Ab + (wm * 64 + mf * 16 + (lane & 15)) * 128;
      af[mf][0] = *(const s16x8*)(p + xb);
      af[mf][1] = *(const s16x8*)(p + (xb ^ 64));
    }
#pragma unroll
    for (int nf = 0; nf < 2; ++nf) {
      const char* p = (const char*)Bb + (wn * 32 + nf * 16 + (lane & 15)) * 128;
      bfr[nf][0] = *(const s16x8*)(p + xb);
      bfr[nf][1] = *(const s16x8*)(p + (xb ^ 64));
    }
    __builtin_amdgcn_s_setprio(1);
#pragma unroll
    for (int ks = 0; ks < 2; ++ks)
#pragma unroll
      for (int mf = 0; mf < 4; ++mf)
#pragma unroll
        for (int nf = 0; nf < 2; ++nf)
          acc[mf][nf] = MFMA16(af[mf][ks], bfr[nf][ks], acc[mf][nf]);
    __builtin_amdgcn_s_setprio(0);
  }
#pragma unroll
  for (int mf = 0; mf < 4; ++mf)
#pragma unroll
    for (int rr = 0; rr < 4; ++rr) {
      const int row = m0 + wm * 64 + mf * 16 + (lane >> 4) * 4 + rr;
      const int slot = inv[row];
#pragma unroll
      for (int nf = 0; nf < 2; ++nf) {
        const int col = n0 + wn * 32 + nf * 16 + (lane & 15);
        const float v = acc[mf][nf][rr] + bias[col] + resid[(size_t)row * DD + col];
        C[(size_t)row * DD + col] = v;
        x2g[(size_t)slot * DD + col] = f2bf(v);
      }
    }
}

// ---------------- MFMA flash attention: 128 q x (b,h) per block, 8 waves x 16 q ----------------
__global__ __launch_bounds__(512) void attn_kernel(const u16* __restrict__ qkv,
                                                   const u16* __restrict__ Vt,
                                                   u16* __restrict__ ctx) {
  const int q0 = blockIdx.x * 128, h = blockIdx.y, b = blockIdx.z;
  const int tid = threadIdx.x, lane = tid & 63, w = tid >> 6;
  const int q15 = lane & 15, g = lane >> 4, l7 = lane & 7;
  __shared__ u16 Q_lds[128 * 64];
  __shared__ u16 K_lds[2][64 * 64];
  __shared__ u16 V_lds[2][64 * 64];
  __shared__ u16 P_lds[8][16 * 72];
  __shared__ float s_lds[8][16];

#pragma unroll
  for (int q2 = 0; q2 < 2; ++q2) {
    const int idx = w * 2 + q2;
    const int r = idx * 8 + (lane >> 3);
    const int c = l7 ^ (r & 7);
    GLOAD16(qkv + (size_t)(b * SS + q0 + r) * D3 + h * HDIM + c * 8, &Q_lds[idx * 512]);
  }
  auto stageK = [&](int buf, int kt) {
    const int r = w * 8 + (lane >> 3);
    const int c = l7 ^ (r & 7);
    GLOAD16(qkv + (size_t)(b * SS + kt * 64 + r) * D3 + DD + h * HDIM + c * 8,
            &K_lds[buf][w * 512]);
  };
  auto stageV = [&](int buf, int kt) {
    const int r = w * 8 + (lane >> 3);
    const int c = l7 ^ (r & 7);
    GLOAD16(Vt + ((size_t)(b * HH + h) * HDIM + r) * SS + kt * 64 + c * 8,
            &V_lds[buf][w * 512]);
  };
  stageK(0, 0);
  stageV(0, 0);
  asm volatile("s_waitcnt vmcnt(0)" ::: "memory");
  __syncthreads();
  s16x8 bq[2];
#pragma unroll
  for (int ks = 0; ks < 2; ++ks)
    bq[ks] = *(const s16x8*)((const char*)Q_lds + (w * 16 + q15) * 128 + ((4 * ks + g) ^ l7) * 16);
  f32x4 oacc[4];
#pragma unroll
  for (int nf = 0; nf < 4; ++nf) oacc[nf] = f32x4{0.f, 0.f, 0.f, 0.f};
  float mrun = -3.0e38f, lrun = 0.0f;
  int buf = 0;
  for (int kt = 0; kt < 16; ++kt) {
    if (kt < 15) { stageK(buf ^ 1, kt + 1); stageV(buf ^ 1, kt + 1); }
    f32x4 st[4];
#pragma unroll
    for (int mf = 0; mf < 4; ++mf) st[mf] = f32x4{0.f, 0.f, 0.f, 0.f};
#pragma unroll
    for (int ks = 0; ks < 2; ++ks) {
#pragma unroll
      for (int mf = 0; mf < 4; ++mf) {
        const s16x8 ka = *(const s16x8*)((const char*)K_lds[buf] + (mf * 16 + q15) * 128 +
                                         ((4 * ks + g) ^ l7) * 16);
        st[mf] = MFMA16(ka, bq[ks], st[mf]);
      }
    }
    float t0[4][4];
    float cmax = -3.0e38f;
#pragma unroll
    for (int mf = 0; mf < 4; ++mf)
#pragma unroll
      for (int r = 0; r < 4; ++r) {
        const float v = st[mf][r] * 0.125f;
        t0[mf][r] = v;
        cmax = fmaxf(cmax, v);
      }
    cmax = fmaxf(cmax, __shfl_xor(cmax, 16));
    cmax = fmaxf(cmax, __shfl_xor(cmax, 32));
    const float mnew = fmaxf(mrun, cmax);
    const float scf = __expf(mrun - mnew);
    float psum = 0.f;
#pragma unroll
    for (int mf = 0; mf < 4; ++mf)
#pragma unroll
      for (int r = 0; r < 4; ++r) {
        const float p = __expf(t0[mf][r] - mnew);
        t0[mf][r] = p;
        psum += p;
      }
    psum += __shfl_xor(psum, 16);
    psum += __shfl_xor(psum, 32);
    lrun = lrun * scf + psum;
    mrun = mnew;
    s_lds[w][q15] = scf;
    u16* pw = &P_lds[w][0];
#pragma unroll
    for (int mf = 0; mf < 4; ++mf) {
      u32x2 pk;
      pk[0] = (unsigned)f2bf(t0[mf][0]) | ((unsigned)f2bf(t0[mf][1]) << 16);
      pk[1] = (unsigned)f2bf(t0[mf][2]) | ((unsigned)f2bf(t0[mf][3]) << 16);
      *(u32x2*)(pw + q15 * 72 + mf * 16 + g * 4) = pk;
    }
    asm volatile("s_waitcnt lgkmcnt(0)" ::: "memory");
    const f32x4 scv = *(const f32x4*)&s_lds[w][g * 4];
#pragma unroll
    for (int nf = 0; nf < 4; ++nf)
#pragma unroll
      for (int r = 0; r < 4; ++r) oacc[nf][r] *= scv[r];
#pragma unroll
    for (int ks = 0; ks < 2; ++ks) {
      const s16x8 pa = *(const s16x8*)(pw + q15 * 72 + ks * 32 + g * 8);
#pragma unroll
      for (int nf = 0; nf < 4; ++nf) {
        const s16x8 bv = *(const s16x8*)((const char*)V_lds[buf] + (nf * 16 + q15) * 128 +
                                         ((4 * ks + g) ^ l7) * 16);
        oacc[nf] = MFMA16(pa, bv, oacc[nf]);
      }
    }
    asm volatile("s_waitcnt vmcnt(0)" ::: "memory");
    __syncthreads();
    buf ^= 1;
  }
  const float linv = 1.0f / lrun;
  s_lds[w][q15] = linv;
  asm volatile("s_waitcnt lgkmcnt(0)" ::: "memory");
  const f32x4 lv = *(const f32x4*)&s_lds[w][g * 4];
#pragma unroll
  for (int nf = 0; nf < 4; ++nf)
#pragma unroll
    for (int r = 0; r < 4; ++r) {
      const int qg = q0 + w * 16 + g * 4 + r;
      ctx[(size_t)(b * SS + qg) * DD + h * HDIM + nf * 16 + q15] = f2bf(oacc[nf][r] * lv[r]);
    }
}

// ---------------- routing (single launch): counts, offsets, slot-pack, inverse ----------------
__global__ void routing_kernel(const int* __restrict__ gid, int* __restrict__ cnts_g,
                               int* __restrict__ off_g, int* __restrict__ gidx,
                               int* __restrict__ inv) {
  __shared__ int cnt[GG];
  __shared__ int off[GG + 1];
  const int tid = threadIdx.x;  // 1024 threads
  if (tid < GG) cnt[tid] = 0;
  __syncthreads();
  const int t0 = tid, t1 = tid + 1024;
  const int g0 = gid[t0], g1 = gid[t1];
  const int s0 = atomicAdd(&cnt[g0], 1);
  const int s1 = atomicAdd(&cnt[g1], 1);
  __syncthreads();
  if (tid == 0) {
    int s = 0;
#pragma unroll
    for (int g = 0; g < GG; ++g) { off[g] = s; s += cnt[g]; }
    off[GG] = s;
  }
  __syncthreads();
  const int sg0 = off[g0] + s0;
  gidx[sg0] = t0; inv[t0] = sg0;
  const int sg1 = off[g1] + s1;
  gidx[sg1] = t1; inv[t1] = sg1;
  if (tid < GG) cnts_g[tid] = cnt[tid];
  if (tid <= GG) off_g[tid] = off[tid];
}

// ---------------- MoE GEMM1 v2: 128x128 tile, dbuf-2 ----------------
__global__ __launch_bounds__(256) void moe1_kernel(const u16* __restrict__ x2g, const u16* __restrict__ w1t,
                            const float* __restrict__ e_b1, const int* __restrict__ off,
                            const int* __restrict__ cnts, u16* __restrict__ h1) {
  const int ge = blockIdx.z, g = ge >> 1, e = ge & 1;
  const int cnt = cnts[g];
  const int m0 = blockIdx.y * 128;
  if (m0 >= cnt) return;
  const int base = off[g];
  const int n0 = blockIdx.x * 128;
  const u16* A = x2g + (size_t)base * DD;       // contiguous rows of this group
  const u16* B = w1t + (size_t)ge * HIDN * DD;  // [HID][D]
  const int tid = threadIdx.x, lane = tid & 63, w = tid >> 6;
  const int wm = w >> 1, wn = w & 1;
  __shared__ u16 As[2][128 * 64];
  __shared__ u16 Bs[2][128 * 64];
  f32x4 acc[4][4];
#pragma unroll
  for (int i = 0; i < 4; ++i)
#pragma unroll
    for (int j = 0; j < 4; ++j) acc[i][j] = f32x4{0.f, 0.f, 0.f, 0.f};
  auto stage = [&](int t, int buf) {
    const int k0 = t * 64;
#pragma unroll
    for (int q = 0; q < 4; ++q) {
      const int idx = w * 4 + q, r = idx * 8 + (lane >> 3), c = (lane & 7) ^ (r & 7);
      int rg = m0 + r; if (rg > cnt - 1) rg = cnt - 1;
      GLOAD16(A + (size_t)rg * DD + k0 + c * 8, &As[buf][idx * 512]);
    }
#pragma unroll
    for (int q = 0; q < 4; ++q) {
      const int idx = w * 4 + q, r = idx * 8 + (lane >> 3), c = (lane & 7) ^ (r & 7);
      GLOAD16(B + (size_t)(n0 + r) * DD + k0 + c * 8, &Bs[buf][idx * 512]);
    }
  };
  stage(0, 0);
  asm volatile("s_waitcnt vmcnt(0)" ::: "memory");
  __syncthreads();
  const int T = DD / 64;
  for (int t = 0; t < T; ++t) {
    if (t > 0) {
      asm volatile("s_waitcnt vmcnt(0)" ::: "memory");
      __builtin_amdgcn_s_barrier();
      asm volatile("" ::: "memory");
    }
    if (t + 1 < T) stage(t + 1, (t + 1) & 1);
    const u16* Ab = As[t & 1];
    const u16* Bb = Bs[t & 1];
    const int xb = (((lane >> 4) ^ (lane & 7)) * 16);
    s16x8 af[4][2], bfr[4][2];
#pragma unroll
    for (int mf = 0; mf < 4; ++mf) {
      const char* p = (const char*)Ab + (wm * 64 + mf * 16 + (lane & 15)) * 128;
      af[mf][0] = *(const s16x8*)(p + xb);
      af[mf][1] = *(const s16x8*)(p + (xb ^ 64));
    }
#pragma unroll
    for (int nf = 0; nf < 4; ++nf) {
      const char* p = (const char*)Bb + (wn * 64 + nf * 16 + (lane & 15)) * 128;
      bfr[nf][0] = *(const s16x8*)(p + xb);
      bfr[nf][1] = *(const s16x8*)(p + (xb ^ 64));
    }
    __builtin_amdgcn_s_setprio(1);
#pragma unroll
    for (int ks = 0; ks < 2; ++ks)
#pragma unroll
      for (int mf = 0; mf < 4; ++mf)
#pragma unroll
        for (int nf = 0; nf < 4; ++nf)
          acc[mf][nf] = MFMA16(af[mf][ks], bfr[nf][ks], acc[mf][nf]);
    __builtin_amdgcn_s_setprio(0);
  }
  const float* b1 = e_b1 + (size_t)ge * HIDN;
#pragma unroll
  for (int mf = 0; mf < 4; ++mf)
#pragma unroll
    for (int rr = 0; rr < 4; ++rr) {
      const int rowg = m0 + wm * 64 + mf * 16 + (lane >> 4) * 4 + rr;
      if (rowg < cnt) {
        u16* orow = h1 + ((size_t)e * NTOK + base + rowg) * HIDN;  // slot-ordered
#pragma unroll
        for (int nf = 0; nf < 4; ++nf) {
          const int col = n0 + wn * 64 + nf * 16 + (lane & 15);
          orow[col] = f2bf(gelu_f(acc[mf][nf][rr] + b1[col]));
        }
      }
    }
}

// ---------------- MoE GEMM2 v2: 8 waves = 2m x 2n x 2ks (conv-style K-split), ring-3 ----------------
__global__ __launch_bounds__(512) void moe2_kernel(const u16* __restrict__ h1, const u16* __restrict__ w2t,
                            const float* __restrict__ e_b2, const int* __restrict__ off,
                            const int* __restrict__ cnts, const int* __restrict__ gidx,
                            const float* __restrict__ x2, float* __restrict__ outp) {
  const int g = blockIdx.z;
  const int cnt = cnts[g];
  const int m0 = blockIdx.y * 128;
  if (m0 >= cnt) return;
  const int base = off[g];
  const int n0 = blockIdx.x * 64;
  const int tid = threadIdx.x, lane = tid & 63, w = tid >> 6;
  const int wm = (w >> 2) & 1, wn = (w >> 1) & 1, ksid = w & 1;
  const int q15 = lane & 15, gq = lane >> 4;
  __shared__ __align__(16) u16 As[3][128 * 64];
  __shared__ __align__(16) u16 Bs[3][64 * 64];
  f32x4 acc[4][2];
#pragma unroll
  for (int i = 0; i < 4; ++i)
#pragma unroll
    for (int j = 0; j < 2; ++j) acc[i][j] = f32x4{0.f, 0.f, 0.f, 0.f};
  auto stage = [&](int t, int buf) {
    const int e = t >> 5;
    const int k0 = (t & 31) * 64;
#pragma unroll
    for (int q = 0; q < 2; ++q) {
      const int idx = w * 2 + q, r = idx * 8 + (lane >> 3), c = (lane & 7) ^ (r & 7);
      int rg = m0 + r; if (rg > cnt - 1) rg = cnt - 1;
      GLOAD16(h1 + ((size_t)e * NTOK + base + rg) * HIDN + k0 + c * 8, &As[buf][idx * 512]);
    }
    {
      const int r = w * 8 + (lane >> 3), c = (lane & 7) ^ (r & 7);
      GLOAD16(w2t + ((size_t)(g * EE + e) * DD + n0 + r) * HIDN + k0 + c * 8, &Bs[buf][w * 512]);
    }
  };
  stage(0, 0);
  stage(1, 1);
  const int T = 64;
  const int kx = ksid * 64;
  for (int t = 0; t < T; ++t) {
    if (t + 1 < T) asm volatile("s_waitcnt vmcnt(3)" ::: "memory");
    else           asm volatile("s_waitcnt vmcnt(0)" ::: "memory");
    __builtin_amdgcn_s_barrier();
    asm volatile("" ::: "memory");
    if (t + 2 < T) stage(t + 2, (t + 2) % 3);
    const u16* Ab = As[t % 3];
    const u16* Bb = Bs[t % 3];
    const int xb = ((((lane >> 4) ^ (lane & 7)) * 16) ^ kx);
    s16x8 af[4], bfr[2];
#pragma unroll
    for (int mf = 0; mf < 4; ++mf) {
      const char* p = (const char*)Ab + (wm * 64 + mf * 16 + q15) * 128;
      af[mf] = *(const s16x8*)(p + xb);
    }
#pragma unroll
    for (int nf = 0; nf < 2; ++nf) {
      const char* p = (const char*)Bb + (wn * 32 + nf * 16 + q15) * 128;
      bfr[nf] = *(const s16x8*)(p + xb);
    }
    __builtin_amdgcn_s_setprio(1);
#pragma unroll
    for (int mf = 0; mf < 4; ++mf)
#pragma unroll
      for (int nf = 0; nf < 2; ++nf)
        acc[mf][nf] = MFMA16(af[mf], bfr[nf], acc[mf][nf]);
    __builtin_amdgcn_s_setprio(0);
  }
  __syncthreads();
  float* scr = (float*)&As[0][0] + (wm * 2 + wn) * 2048;
  if (ksid == 1) {
#pragma unroll
    for (int mf = 0; mf < 4; ++mf)
#pragma unroll
      for (int nf = 0; nf < 2; ++nf) {
        const int col = nf * 16 + q15;
        *(f32x4*)&scr[col * 64 + ((mf * 16 + gq * 4) ^ ((col & 7) << 3))] = acc[mf][nf];
      }
  }
  __syncthreads();
  if (ksid == 0) {
    const float* b20 = e_b2 + (size_t)(g * EE + 0) * DD;
    const float* b21 = e_b2 + (size_t)(g * EE + 1) * DD;
#pragma unroll
    for (int mf = 0; mf < 4; ++mf) {
      f32x4 sum[2];
#pragma unroll
      for (int nf = 0; nf < 2; ++nf) {
        const int col = nf * 16 + q15;
        const f32x4 o = *(const f32x4*)&scr[col * 64 + ((mf * 16 + gq * 4) ^ ((col & 7) << 3))];
        sum[nf] = acc[mf][nf] + o;
      }
#pragma unroll
      for (int rr = 0; rr < 4; ++rr) {
        const int rowg = m0 + wm * 64 + mf * 16 + gq * 4 + rr;
        if (rowg < cnt) {
          const int tok = gidx[base + rowg];
#pragma unroll
          for (int nf = 0; nf < 2; ++nf) {
            const int col = n0 + wn * 32 + nf * 16 + q15;
            outp[(size_t)tok * DD + col] =
                0.5f * sum[nf][rr] + 0.5f * (b20[col] + b21[col]) + x2[(size_t)tok * DD + col];
          }
        }
      }
    }
  }
}

extern "C" void kernel_launch(void* const* d_in, const int* in_sizes, int n_in,
                              void* d_out, int out_size, void* d_ws, size_t ws_size,
                              hipStream_t stream) {
  (void)in_sizes; (void)n_in; (void)out_size; (void)ws_size;
  const float* x      = (const float*)d_in[0];
  const int*   gid    = (const int*)d_in[1];
  const float* cn_g   = (const float*)d_in[2];
  const float* cn_b   = (const float*)d_in[3];
  const float* conv_w = (const float*)d_in[4];
  const float* conv_b = (const float*)d_in[5];
  const float* an_g   = (const float*)d_in[6];
  const float* an_b   = (const float*)d_in[7];
  const float* in_w   = (const float*)d_in[8];
  const float* in_b   = (const float*)d_in[9];
  const float* out_w  = (const float*)d_in[10];
  const float* out_b  = (const float*)d_in[11];
  const float* e_w1   = (const float*)d_in[12];
  const float* e_b1   = (const float*)d_in[13];
  const float* e_w2   = (const float*)d_in[14];
  const float* e_b2   = (const float*)d_in[15];
  float* outp = (float*)d_out;

  // ---- workspace map (high-water 74MB + ~41KB; r2-proven conv-phase layout) ----
  // conv phase: hb 0..4 | Pc f32 x4 4..36 | Wb 36..68 (dead after conv_kernel)
  // post-conv:  x1 36..44 (dead Wb) | qkvb 24..36 (dead Pc) | inwb 44..50 | outwb 44..46
  //             Vt 50..54 | x2 54..62 | inv 62..62.008 | x2g 64..68 (all in dead Wb)
  // MoE phase:  wgt 4..36 | h1 36..52 (x1/outwb/inwb/Vt dead) | tail 74M: cnts/offp/gidx
  char* wsp = (char*)d_ws;
  u16*   hb    = (u16*)(wsp);                         // 0..4M  (ln/combine out; ctxb reuse)
  float* Pc    = (float*)(wsp + (4ull << 20));        // 4..36M (conv f32 partials x4)
  u16*   Wb    = (u16*)(wsp + (36ull << 20));         // 36..68M (conv phase only)
  float* x1    = (float*)(wsp + (36ull << 20));       // 36..44M (combine out, dead-Wb)
  u16*   qkvb  = (u16*)(wsp + (24ull << 20));         // 24..36M (qkv->attn, dead-Pc)
  u16*   inwb  = (u16*)(wsp + (44ull << 20));         // 44..50M (qkv phase)
  u16*   outwb = (u16*)(wsp + (44ull << 20));         // 44..46M (out phase, after qkv)
  u16*   Vt    = (u16*)(wsp + (50ull << 20));         // 50..54M (attn phase; written by qkv)
  u16*   ctxb  = hb;                                  // 0..4M  (after qkv)
  float* x2    = (float*)(wsp + (54ull << 20));       // 54..62M
  int*   inv   = (int*)(wsp + (62ull << 20));         // 62M.. 8KB (tok->slot; post-combine)
  u16*   x2g   = (u16*)(wsp + (64ull << 20));         // 64..68M (slot-packed tokens)
  u16*   wgt   = (u16*)(wsp + (4ull << 20));          // 4..36M (w1t, then w2t; MoE phase)
  u16*   h1    = (u16*)(wsp + (36ull << 20));         // 36..52M (MoE phase, slot-ordered)
  int*   gat   = (int*)(wsp + (74ull << 20));         // kept for layout stability
  int*   cnts  = gat + GG * NTOK;
  int*   offp  = cnts + GG;
  int*   gidx  = offp + (GG + 1);

  // ---- conv block (v9: 512 blocks, 2 blocks/CU, shared B ring-3) ----
  ln_kernel<<<NTOK, 256, 0, stream>>>(x, cn_g, cn_b, hb);
  prep_convw<<<1024, 256, 0, stream>>>(conv_w, Wb);
  conv_kernel<<<512, 512, 0, stream>>>(hb, Wb, Pc);
  combine_kernel<<<NTOK, 256, 0, stream>>>(Pc, conv_b, x, an_g, an_b, x1, hb);
  // ---- routing, single launch (Wb dead; inv lives in its hole) ----
  routing_kernel<<<1, 1024, 0, stream>>>(gid, cnts, offp, gidx, inv);
  // ---- attention block (qkv writes Vt directly for V n-tiles) ----
  cvt_kernel<<<3072, 256, 0, stream>>>(in_w, inwb, 3 * DD * DD / 4);
  qkv_kernel<<<dim3(D3 / 128, NTOK / 128), 256, 0, stream>>>(hb, inwb, in_b, qkvb, Vt);
  attn_kernel<<<dim3(SS / 128, HH, BB), 512, 0, stream>>>(qkvb, Vt, ctxb);
  cvt_kernel<<<1024, 256, 0, stream>>>(out_w, outwb, DD * DD / 4);
  out_kernel<<<dim3(DD / 64, NTOK / 128), 256, 0, stream>>>(ctxb, outwb, out_b, x1, x2, x2g, inv);
  // ---- MoE (slot-packed + dense-fastest grids: all 8 XCDs active) ----
  tr_kernel<<<dim3(HIDN / 32, DD / 32, GG * EE), 256, 0, stream>>>(e_w1, wgt, DD, HIDN);
  moe1_kernel<<<dim3(HIDN / 128, NTOK / 128, GG * EE), 256, 0, stream>>>(x2g, wgt, e_b1, offp, cnts, h1);
  tr_kernel<<<dim3(DD / 32, HIDN / 32, GG * EE), 256, 0, stream>>>(e_w2, wgt, HIDN, DD);
  moe2_kernel<<<dim3(DD / 64, NTOK / 128, GG), 512, 0, stream>>>(h1, wgt, e_b2, offp, cnts, gidx, x2, outp);
}